// Round 1
// baseline (12791.441 us; speedup 1.0000x reference)
//
#include <hip/hip_runtime.h>
#include <hip/hip_bf16.h>

// Problem constants (from reference)
#define LCNT 2
#define HCNT 12
#define CDIM 768
#define HSD  64
#define ECNT 8
#define VOC  32000
#define BB   2
#define TT   1024
#define NTOK 2048   // B*T
#define FF   3072   // 4*C

// ---------------- wave reduction helpers ----------------
__device__ __forceinline__ float wave_sum(float v) {
    #pragma unroll
    for (int off = 32; off; off >>= 1) v += __shfl_xor(v, off);
    return v;
}
__device__ __forceinline__ float wave_max(float v) {
    #pragma unroll
    for (int off = 32; off; off >>= 1) v = fmaxf(v, __shfl_xor(v, off));
    return v;
}

// ---------------- embedding ----------------
__global__ __launch_bounds__(256)
void embed_kernel(const int* __restrict__ idx, const float* __restrict__ tok,
                  const float* __restrict__ pos, float* __restrict__ x)
{
    int i = blockIdx.x * 256 + threadIdx.x;      // N*C total
    int c = i % CDIM;
    int n = i / CDIM;
    int t = n % TT;
    x[i] = tok[(size_t)idx[n] * CDIM + c] + pos[(size_t)t * CDIM + c];
}

// ---------------- repack wq/wk/wv [L,H,C,HS] -> [3,L,C,H*HS] ----------------
__global__ __launch_bounds__(256)
void repack_kernel(const float* __restrict__ wq, const float* __restrict__ wk,
                   const float* __restrict__ wv, float* __restrict__ wp)
{
    int i = blockIdx.x * 256 + threadIdx.x;      // 3*L*C*C
    int n  = i % CDIM;
    int c  = (i / CDIM) % CDIM;
    int l  = (i / (CDIM * CDIM)) % LCNT;
    int w3 = i / (CDIM * CDIM * LCNT);
    const float* src = (w3 == 0) ? wq : (w3 == 1) ? wk : wv;
    int h = n / HSD, d = n % HSD;
    wp[i] = src[((((size_t)l * HCNT + h) * CDIM) + c) * HSD + d];
}

// ---------------- layernorm ----------------
__global__ __launch_bounds__(256)
void ln_kernel(const float* __restrict__ x, const float* __restrict__ sc,
               const float* __restrict__ bs, float* __restrict__ out)
{
    int row = blockIdx.x;
    const float* xr = x + (size_t)row * CDIM;
    float* orow = out + (size_t)row * CDIM;
    int tid = threadIdx.x;
    float v0 = xr[tid], v1 = xr[tid + 256], v2 = xr[tid + 512];
    float s1 = v0 + v1 + v2;
    float s2 = v0 * v0 + v1 * v1 + v2 * v2;
    s1 = wave_sum(s1);
    s2 = wave_sum(s2);
    __shared__ float r1[4], r2[4];
    int w = tid >> 6, lane = tid & 63;
    if (lane == 0) { r1[w] = s1; r2[w] = s2; }
    __syncthreads();
    float t1 = r1[0] + r1[1] + r1[2] + r1[3];
    float t2 = r2[0] + r2[1] + r2[2] + r2[3];
    float mu = t1 * (1.0f / CDIM);
    float var = t2 * (1.0f / CDIM) - mu * mu;
    float rstd = rsqrtf(var + 1e-5f);
    orow[tid]       = (v0 - mu) * rstd * sc[tid]       + bs[tid];
    orow[tid + 256] = (v1 - mu) * rstd * sc[tid + 256] + bs[tid + 256];
    orow[tid + 512] = (v2 - mu) * rstd * sc[tid + 512] + bs[tid + 512];
}

// ---------------- generic fp32 tiled GEMM ----------------
// out[m,n] (epilogue per MODE) with acc = sum_k A[m,k]*B(k,n), B(k,n) = TB ? B[n*ldb+k] : B[k*ldb+n]
// MODE 0: out = acc + bias
// MODE 1: out += acc + bias
// MODE 2: out = relu(acc + bias)
// MODE 3: out += scale[m*E+e] * (acc + bias)
#define BM 128
#define BN 128
#define BKK 8

template<bool TB, int MODE>
__global__ __launch_bounds__(256)
void gemm_kernel(int M, int Nn, int Kd,
                 const float* __restrict__ A, int lda,
                 const float* __restrict__ Bp, int ldb,
                 const float* __restrict__ bias,
                 float* __restrict__ out, int ldo,
                 const float* __restrict__ scale, int e)
{
    __shared__ float As[BKK * BM];
    __shared__ float Bs[BKK * BN];
    const int tid = threadIdx.x;
    const int m0 = blockIdx.y * BM;
    const int n0 = blockIdx.x * BN;
    const int tx = tid & 15, ty = tid >> 4;
    float acc[8][8] = {};

    for (int k0 = 0; k0 < Kd; k0 += BKK) {
        {   // A tile: 128 rows x 8 k, stored transposed As[k][m]
            int row = tid >> 1, cg = (tid & 1) * 4;
            float4 a = *reinterpret_cast<const float4*>(A + (size_t)(m0 + row) * lda + k0 + cg);
            As[(cg + 0) * BM + row] = a.x;
            As[(cg + 1) * BM + row] = a.y;
            As[(cg + 2) * BM + row] = a.z;
            As[(cg + 3) * BM + row] = a.w;
        }
        if (TB) {
            int col = tid >> 1, kg = (tid & 1) * 4;
            float4 b = *reinterpret_cast<const float4*>(Bp + (size_t)(n0 + col) * ldb + k0 + kg);
            Bs[(kg + 0) * BN + col] = b.x;
            Bs[(kg + 1) * BN + col] = b.y;
            Bs[(kg + 2) * BN + col] = b.z;
            Bs[(kg + 3) * BN + col] = b.w;
        } else {
            int kk = tid >> 5, ng = (tid & 31) * 4;
            float4 b = *reinterpret_cast<const float4*>(Bp + (size_t)(k0 + kk) * ldb + n0 + ng);
            *reinterpret_cast<float4*>(&Bs[kk * BN + ng]) = b;
        }
        __syncthreads();
        #pragma unroll
        for (int kk = 0; kk < BKK; ++kk) {
            const float4 a0 = *reinterpret_cast<const float4*>(&As[kk * BM + ty * 8]);
            const float4 a1 = *reinterpret_cast<const float4*>(&As[kk * BM + ty * 8 + 4]);
            const float4 b0 = *reinterpret_cast<const float4*>(&Bs[kk * BN + tx * 8]);
            const float4 b1 = *reinterpret_cast<const float4*>(&Bs[kk * BN + tx * 8 + 4]);
            const float av[8] = {a0.x, a0.y, a0.z, a0.w, a1.x, a1.y, a1.z, a1.w};
            const float bv[8] = {b0.x, b0.y, b0.z, b0.w, b1.x, b1.y, b1.z, b1.w};
            #pragma unroll
            for (int i = 0; i < 8; ++i)
                #pragma unroll
                for (int j = 0; j < 8; ++j)
                    acc[i][j] = fmaf(av[i], bv[j], acc[i][j]);
        }
        __syncthreads();
    }

    #pragma unroll
    for (int i = 0; i < 8; ++i) {
        int m = m0 + ty * 8 + i;
        float sm = (MODE == 3) ? scale[(size_t)m * ECNT + e] : 0.0f;
        #pragma unroll
        for (int j = 0; j < 8; ++j) {
            int n = n0 + tx * 8 + j;
            float bj = bias ? bias[n] : 0.0f;
            float r = acc[i][j] + bj;
            float* op = out + (size_t)m * ldo + n;
            if (MODE == 0) *op = r;
            else if (MODE == 1) *op = *op + r;
            else if (MODE == 2) *op = fmaxf(r, 0.0f);
            else *op = *op + sm * r;
        }
    }
}

// ---------------- flash-style causal attention (fp32) ----------------
// q,k,v in [B,T,C] layout with head slice at column h*HS; out same layout (= concat heads)
__global__ __launch_bounds__(256)
void attn_kernel(const float* __restrict__ q, const float* __restrict__ k,
                 const float* __restrict__ v, float* __restrict__ o)
{
    __shared__ float Ks[64 * 65];
    __shared__ float Vs[64 * 65];
    __shared__ float Qs[16 * 65];
    __shared__ float Ps[4 * 65];

    const int t0 = blockIdx.x * 16;
    const int bh = blockIdx.y;
    const int b = bh / HCNT, hh = bh % HCNT;
    const size_t base = (size_t)b * TT * CDIM + (size_t)hh * HSD;
    const int tid = threadIdx.x;
    const int w = tid >> 6, lane = tid & 63;

    {   // load 16 q rows
        int row = tid >> 4, d0 = (tid & 15) * 4;
        float4 qa = *reinterpret_cast<const float4*>(q + base + (size_t)(t0 + row) * CDIM + d0);
        Qs[row * 65 + d0 + 0] = qa.x;
        Qs[row * 65 + d0 + 1] = qa.y;
        Qs[row * 65 + d0 + 2] = qa.z;
        Qs[row * 65 + d0 + 3] = qa.w;
    }

    float m_[4], l_[4], o_[4];
    #pragma unroll
    for (int rr = 0; rr < 4; ++rr) { m_[rr] = -1e30f; l_[rr] = 0.0f; o_[rr] = 0.0f; }
    const float sscale = rsqrtf((float)CDIM);   // C^-0.5 (as in reference)

    for (int s0 = 0; s0 <= t0 + 15; s0 += 64) {
        __syncthreads();   // previous tile fully consumed (also publishes Qs on iter 0)
        {   // load K,V tile: 64 rows x 64
            int row = tid >> 2, g = (tid & 3) * 16;
            const float* ksrc = k + base + (size_t)(s0 + row) * CDIM + g;
            const float* vsrc = v + base + (size_t)(s0 + row) * CDIM + g;
            #pragma unroll
            for (int i = 0; i < 16; i += 4) {
                float4 ka = *reinterpret_cast<const float4*>(ksrc + i);
                Ks[row * 65 + g + i + 0] = ka.x;
                Ks[row * 65 + g + i + 1] = ka.y;
                Ks[row * 65 + g + i + 2] = ka.z;
                Ks[row * 65 + g + i + 3] = ka.w;
                float4 va = *reinterpret_cast<const float4*>(vsrc + i);
                Vs[row * 65 + g + i + 0] = va.x;
                Vs[row * 65 + g + i + 1] = va.y;
                Vs[row * 65 + g + i + 2] = va.z;
                Vs[row * 65 + g + i + 3] = va.w;
            }
        }
        __syncthreads();

        #pragma unroll
        for (int rr = 0; rr < 4; ++rr) {
            const int t = t0 + w * 4 + rr;
            const float* qr = &Qs[(w * 4 + rr) * 65];
            const float* kr = &Ks[lane * 65];
            float s = 0.0f;
            #pragma unroll 8
            for (int d = 0; d < 64; ++d) s = fmaf(qr[d], kr[d], s);
            s *= sscale;
            if (s0 + lane > t) s = -1e30f;

            float mx = wave_max(s);
            float mnew = fmaxf(m_[rr], mx);
            float p = __expf(s - mnew);
            float ps = wave_sum(p);
            float corr = __expf(m_[rr] - mnew);
            l_[rr] = l_[rr] * corr + ps;
            m_[rr] = mnew;
            Ps[w * 65 + lane] = p;
            // intra-wave write->read; compiler orders LDS accesses
            float po = 0.0f;
            const float* pr = &Ps[w * 65];
            #pragma unroll 8
            for (int j = 0; j < 64; ++j) po = fmaf(pr[j], Vs[j * 65 + lane], po);
            o_[rr] = o_[rr] * corr + po;
        }
    }

    #pragma unroll
    for (int rr = 0; rr < 4; ++rr) {
        const int t = t0 + w * 4 + rr;
        o[base + (size_t)t * CDIM + lane] = o_[rr] / l_[rr];
    }
}

// ---------------- gate + top-2 + softmax -> comb[N,E] ----------------
__global__ __launch_bounds__(256)
void gate_kernel(const float* __restrict__ h2, const float* __restrict__ gw,
                 float* __restrict__ comb)
{
    __shared__ float gws[ECNT * CDIM];
    int tid = threadIdx.x;
    for (int i = tid; i < ECNT * CDIM; i += 256) gws[i] = gw[i];
    __syncthreads();
    int t = blockIdx.x * 256 + tid;
    const float* hr = h2 + (size_t)t * CDIM;
    float g[ECNT] = {};
    for (int c = 0; c < CDIM; ++c) {
        float hv = hr[c];
        #pragma unroll
        for (int e = 0; e < ECNT; ++e) g[e] = fmaf(hv, gws[e * CDIM + c], g[e]);
    }
    int e0 = 0; float g0 = g[0];
    #pragma unroll
    for (int e = 1; e < ECNT; ++e) if (g[e] > g0) { g0 = g[e]; e0 = e; }
    int e1 = -1; float g1 = -1e30f;
    #pragma unroll
    for (int e = 0; e < ECNT; ++e) if (e != e0 && g[e] > g1) { g1 = g[e]; e1 = e; }
    float z = __expf(g1 - g0);          // <= 1
    float w0 = 1.0f / (1.0f + z);
    float w1 = z / (1.0f + z);
    #pragma unroll
    for (int e = 0; e < ECNT; ++e)
        comb[(size_t)t * ECNT + e] = (e == e0) ? w0 : ((e == e1) ? w1 : 0.0f);
}

// ---------------- per-row cross-entropy ----------------
__global__ __launch_bounds__(256)
void loss_row_kernel(const float* __restrict__ logits, const int* __restrict__ tgt,
                     float* __restrict__ lrow)
{
    int row = blockIdx.x;
    const float* lr = logits + (size_t)row * VOC;
    int tid = threadIdx.x, w = tid >> 6, lane = tid & 63;
    __shared__ float red[4];
    float mx = -1e30f;
    for (int i = tid; i < VOC; i += 256) mx = fmaxf(mx, lr[i]);
    mx = wave_max(mx);
    if (lane == 0) red[w] = mx;
    __syncthreads();
    mx = fmaxf(fmaxf(red[0], red[1]), fmaxf(red[2], red[3]));
    __syncthreads();
    float se = 0.0f;
    for (int i = tid; i < VOC; i += 256) se += expf(lr[i] - mx);
    se = wave_sum(se);
    if (lane == 0) red[w] = se;
    __syncthreads();
    if (tid == 0) {
        float lse = mx + logf(red[0] + red[1] + red[2] + red[3]);
        lrow[row] = lse - lr[tgt[row]];
    }
}

__global__ __launch_bounds__(256)
void loss_reduce_kernel(const float* __restrict__ lrow, float* __restrict__ out)
{
    int tid = threadIdx.x, w = tid >> 6, lane = tid & 63;
    float s = 0.0f;
    for (int i = tid; i < NTOK; i += 256) s += lrow[i];
    s = wave_sum(s);
    __shared__ float red[4];
    if (lane == 0) red[w] = s;
    __syncthreads();
    if (tid == 0) out[0] = (red[0] + red[1] + red[2] + red[3]) * (1.0f / NTOK);
}

// ---------------- launch ----------------
extern "C" void kernel_launch(void* const* d_in, const int* in_sizes, int n_in,
                              void* d_out, int out_size, void* d_ws, size_t ws_size,
                              hipStream_t stream)
{
    const int*   idx     = (const int*)d_in[0];
    const int*   targets = (const int*)d_in[1];
    const float* tok_emb = (const float*)d_in[2];
    const float* pos_emb = (const float*)d_in[3];
    const float* ln1_s   = (const float*)d_in[4];
    const float* ln1_b   = (const float*)d_in[5];
    const float* wq      = (const float*)d_in[6];
    const float* wk      = (const float*)d_in[7];
    const float* wv      = (const float*)d_in[8];
    const float* wo      = (const float*)d_in[9];
    const float* bo      = (const float*)d_in[10];
    const float* ln2_s   = (const float*)d_in[11];
    const float* ln2_b   = (const float*)d_in[12];
    const float* gate_w  = (const float*)d_in[13];
    const float* w1      = (const float*)d_in[14];
    const float* b1      = (const float*)d_in[15];
    const float* w2      = (const float*)d_in[16];
    const float* b2      = (const float*)d_in[17];
    const float* lm_w    = (const float*)d_in[18];
    const float* lm_b    = (const float*)d_in[19];
    float* out = (float*)d_out;

    float* ws   = (float*)d_ws;
    float* wp   = ws;                                // 3*L*C*C
    float* x    = wp + (size_t)3 * LCNT * CDIM * CDIM;
    float* hbuf = x    + (size_t)NTOK * CDIM;        // LN1 out, later attn out
    float* qbuf = hbuf + (size_t)NTOK * CDIM;        // q, later h2
    float* kbuf = qbuf + (size_t)NTOK * CDIM;
    float* vbuf = kbuf + (size_t)NTOK * CDIM;
    float* hid  = vbuf + (size_t)NTOK * CDIM;        // N*FF
    float* comb = hid  + (size_t)NTOK * FF;          // N*E
    float* lrow = comb + (size_t)NTOK * ECNT;        // N

    dim3 blk(256);

    repack_kernel<<<(3 * LCNT * CDIM * CDIM) / 256, blk, 0, stream>>>(wq, wk, wv, wp);
    embed_kernel<<<(NTOK * CDIM) / 256, blk, 0, stream>>>(idx, tok_emb, pos_emb, x);

    for (int l = 0; l < LCNT; ++l) {
        ln_kernel<<<NTOK, blk, 0, stream>>>(x, ln1_s + (size_t)l * CDIM, ln1_b + (size_t)l * CDIM, hbuf);

        const size_t mw = (size_t)CDIM * CDIM;
        gemm_kernel<false, 0><<<dim3(CDIM / BN, NTOK / BM), blk, 0, stream>>>(
            NTOK, CDIM, CDIM, hbuf, CDIM, wp + (0 * LCNT + l) * mw, CDIM, nullptr, qbuf, CDIM, nullptr, 0);
        gemm_kernel<false, 0><<<dim3(CDIM / BN, NTOK / BM), blk, 0, stream>>>(
            NTOK, CDIM, CDIM, hbuf, CDIM, wp + (1 * LCNT + l) * mw, CDIM, nullptr, kbuf, CDIM, nullptr, 0);
        gemm_kernel<false, 0><<<dim3(CDIM / BN, NTOK / BM), blk, 0, stream>>>(
            NTOK, CDIM, CDIM, hbuf, CDIM, wp + (2 * LCNT + l) * mw, CDIM, nullptr, vbuf, CDIM, nullptr, 0);

        attn_kernel<<<dim3(TT / 16, BB * HCNT), blk, 0, stream>>>(qbuf, kbuf, vbuf, hbuf);

        gemm_kernel<true, 1><<<dim3(CDIM / BN, NTOK / BM), blk, 0, stream>>>(
            NTOK, CDIM, CDIM, hbuf, CDIM, wo + (size_t)l * CDIM * CDIM, CDIM,
            bo + (size_t)l * CDIM, x, CDIM, nullptr, 0);

        ln_kernel<<<NTOK, blk, 0, stream>>>(x, ln2_s + (size_t)l * CDIM, ln2_b + (size_t)l * CDIM, qbuf);
        gate_kernel<<<NTOK / 256, blk, 0, stream>>>(qbuf, gate_w + (size_t)l * ECNT * CDIM, comb);

        for (int e = 0; e < ECNT; ++e) {
            const float* w1e = w1 + ((size_t)l * ECNT + e) * FF * CDIM;
            const float* b1e = b1 + ((size_t)l * ECNT + e) * FF;
            const float* w2e = w2 + ((size_t)l * ECNT + e) * CDIM * FF;
            const float* b2e = b2 + ((size_t)l * ECNT + e) * CDIM;
            gemm_kernel<true, 2><<<dim3(FF / BN, NTOK / BM), blk, 0, stream>>>(
                NTOK, FF, CDIM, qbuf, CDIM, w1e, CDIM, b1e, hid, FF, nullptr, 0);
            gemm_kernel<true, 3><<<dim3(CDIM / BN, NTOK / BM), blk, 0, stream>>>(
                NTOK, CDIM, FF, hid, FF, w2e, FF, b2e, x, CDIM, comb, e);
        }
    }

    gemm_kernel<true, 0><<<dim3(VOC / BN, NTOK / BM), blk, 0, stream>>>(
        NTOK, VOC, CDIM, x, CDIM, lm_w, CDIM, lm_b, out, VOC, nullptr, 0);

    loss_row_kernel<<<NTOK, blk, 0, stream>>>(out, targets, lrow);
    loss_reduce_kernel<<<1, blk, 0, stream>>>(lrow, out + (size_t)NTOK * VOC);
}

// Round 4
// 5359.090 us; speedup vs baseline: 2.3869x; 2.3869x over previous
//
#include <hip/hip_runtime.h>
#include <hip/hip_bf16.h>

// Problem constants (from reference)
#define LCNT 2
#define HCNT 12
#define CDIM 768
#define HSD  64
#define ECNT 8
#define VOC  32000
#define BB   2
#define TT   1024
#define NTOK 2048   // B*T
#define FF   3072   // 4*C

typedef __attribute__((ext_vector_type(8))) short bf16x8;
typedef __attribute__((ext_vector_type(4))) float f32x4;

// ---------------- helpers ----------------
__device__ __forceinline__ float wave_sum(float v) {
    #pragma unroll
    for (int off = 32; off; off >>= 1) v += __shfl_xor(v, off);
    return v;
}
__device__ __forceinline__ float wave_max(float v) {
    #pragma unroll
    for (int off = 32; off; off >>= 1) v = fmaxf(v, __shfl_xor(v, off));
    return v;
}
__device__ __forceinline__ unsigned short f2bf(float f) {
    unsigned int u = __float_as_uint(f);
    unsigned int r = (u + 0x7FFFu + ((u >> 16) & 1u)) >> 16;
    return (unsigned short)r;
}
__device__ __forceinline__ float bf2f(unsigned short h) {
    return __uint_as_float((unsigned int)h << 16);
}
// split fp32 -> hi bf16 + lo bf16 (a ~= hi + lo, residual ~2^-17 relative)
__device__ __forceinline__ void split2(float a, unsigned short& h, unsigned short& l) {
    h = f2bf(a);
    l = f2bf(a - bf2f(h));
}

// ---------------- embedding ----------------
__global__ __launch_bounds__(256)
void embed_kernel(const int* __restrict__ idx, const float* __restrict__ tok,
                  const float* __restrict__ pos, float* __restrict__ x)
{
    int i = blockIdx.x * 256 + threadIdx.x;      // N*C total
    int c = i % CDIM;
    int n = i / CDIM;
    int t = n % TT;
    x[i] = tok[(size_t)idx[n] * CDIM + c] + pos[(size_t)t * CDIM + c];
}

// ---------------- repack wq/wk/wv [L,H,C,HS] -> wp[w3][l][n=h*HS+d][k=c]  (B^T layout) ----------------
__global__ __launch_bounds__(256)
void repack_kernel(const float* __restrict__ wq, const float* __restrict__ wk,
                   const float* __restrict__ wv, float* __restrict__ wp)
{
    int i = blockIdx.x * 256 + threadIdx.x;      // 3*L*C*C
    int n  = i % CDIM;
    int c  = (i / CDIM) % CDIM;
    int l  = (i / (CDIM * CDIM)) % LCNT;
    int w3 = i / (CDIM * CDIM * LCNT);
    const float* src = (w3 == 0) ? wq : (w3 == 1) ? wk : wv;
    int h = n / HSD, d = n % HSD;
    wp[((((size_t)w3 * LCNT + l) * CDIM) + n) * CDIM + c] =
        src[((((size_t)l * HCNT + h) * CDIM) + c) * HSD + d];
}

// ---------------- layernorm ----------------
__global__ __launch_bounds__(256)
void ln_kernel(const float* __restrict__ x, const float* __restrict__ sc,
               const float* __restrict__ bs, float* __restrict__ out)
{
    int row = blockIdx.x;
    const float* xr = x + (size_t)row * CDIM;
    float* orow = out + (size_t)row * CDIM;
    int tid = threadIdx.x;
    float v0 = xr[tid], v1 = xr[tid + 256], v2 = xr[tid + 512];
    float s1 = v0 + v1 + v2;
    float s2 = v0 * v0 + v1 * v1 + v2 * v2;
    s1 = wave_sum(s1);
    s2 = wave_sum(s2);
    __shared__ float r1[4], r2[4];
    int w = tid >> 6, lane = tid & 63;
    if (lane == 0) { r1[w] = s1; r2[w] = s2; }
    __syncthreads();
    float t1 = r1[0] + r1[1] + r1[2] + r1[3];
    float t2 = r2[0] + r2[1] + r2[2] + r2[3];
    float mu = t1 * (1.0f / CDIM);
    float var = t2 * (1.0f / CDIM) - mu * mu;
    float rstd = rsqrtf(var + 1e-5f);
    orow[tid]       = (v0 - mu) * rstd * sc[tid]       + bs[tid];
    orow[tid + 256] = (v1 - mu) * rstd * sc[tid + 256] + bs[tid + 256];
    orow[tid + 512] = (v2 - mu) * rstd * sc[tid + 512] + bs[tid + 512];
}

// ---------------- split-precision bf16 MFMA GEMM (fp32-grade accuracy) ----------------
// C[m,n] = sum_k A[m,k] * B[n,k]   (B given row-major [N][K], i.e. B^T)
// Each fp32 operand split into hi+lo bf16; acc += ah*bh + ah*bl + al*bh  (3 MFMAs)
// MODE 0: out = acc + bias
// MODE 1: out += acc + bias
// MODE 2: out = relu(acc + bias)
// MODE 3: out += scale[m*E+e] * (acc + bias)
#define BM 128
#define BN 128
#define BK 32
#define PADK 40   // bf16 stride per row (80 B)

template<int MODE>
__global__ __launch_bounds__(256)
void gemm_bf16_kernel(int M, int Nn, int Kd,
                      const float* __restrict__ A, int lda,
                      const float* __restrict__ B, int ldb,
                      const float* __restrict__ bias,
                      float* __restrict__ out, int ldo,
                      const float* __restrict__ scale, int e)
{
    __shared__ short Ah[BM * PADK];
    __shared__ short Al[BM * PADK];
    __shared__ short Bh[BN * PADK];
    __shared__ short Bl[BN * PADK];
    const int tid = threadIdx.x;
    const int m0 = blockIdx.y * BM;
    const int n0 = blockIdx.x * BN;
    const int w = tid >> 6, lane = tid & 63;
    const int wr = w >> 1, wc = w & 1;          // wave tile (64x64)
    const int lrow = lane & 15, lkg = lane >> 4;
    const int srow = tid >> 3, skg = (tid & 7) * 4;

    const float* Ablk = A + (size_t)m0 * lda;
    const float* Bblk = B + (size_t)n0 * ldb;

    float4 pa[4], pb[4];
    #pragma unroll
    for (int p = 0; p < 4; ++p) {
        pa[p] = *(const float4*)(Ablk + (size_t)(p * 32 + srow) * lda + skg);
        pb[p] = *(const float4*)(Bblk + (size_t)(p * 32 + srow) * ldb + skg);
    }

    f32x4 acc[4][4] = {};
    const int nk = Kd / BK;

    for (int t = 0; t < nk; ++t) {
        __syncthreads();   // previous compute done; LDS free
        #pragma unroll
        for (int p = 0; p < 4; ++p) {
            ushort4 h, l;
            split2(pa[p].x, h.x, l.x); split2(pa[p].y, h.y, l.y);
            split2(pa[p].z, h.z, l.z); split2(pa[p].w, h.w, l.w);
            *(ushort4*)(&Ah[(p * 32 + srow) * PADK + skg]) = h;
            *(ushort4*)(&Al[(p * 32 + srow) * PADK + skg]) = l;
            split2(pb[p].x, h.x, l.x); split2(pb[p].y, h.y, l.y);
            split2(pb[p].z, h.z, l.z); split2(pb[p].w, h.w, l.w);
            *(ushort4*)(&Bh[(p * 32 + srow) * PADK + skg]) = h;
            *(ushort4*)(&Bl[(p * 32 + srow) * PADK + skg]) = l;
        }
        __syncthreads();   // writes visible
        if (t + 1 < nk) {
            const int kb = (t + 1) * BK + skg;
            #pragma unroll
            for (int p = 0; p < 4; ++p) {
                pa[p] = *(const float4*)(Ablk + (size_t)(p * 32 + srow) * lda + kb);
                pb[p] = *(const float4*)(Bblk + (size_t)(p * 32 + srow) * ldb + kb);
            }
        }
        bf16x8 afh[4], afl[4];
        #pragma unroll
        for (int i = 0; i < 4; ++i) {
            afh[i] = *(const bf16x8*)(&Ah[(wr * 64 + i * 16 + lrow) * PADK + lkg * 8]);
            afl[i] = *(const bf16x8*)(&Al[(wr * 64 + i * 16 + lrow) * PADK + lkg * 8]);
        }
        #pragma unroll
        for (int j = 0; j < 4; ++j) {
            const bf16x8 bh = *(const bf16x8*)(&Bh[(wc * 64 + j * 16 + lrow) * PADK + lkg * 8]);
            const bf16x8 bl = *(const bf16x8*)(&Bl[(wc * 64 + j * 16 + lrow) * PADK + lkg * 8]);
            #pragma unroll
            for (int i = 0; i < 4; ++i) {
                acc[i][j] = __builtin_amdgcn_mfma_f32_16x16x32_bf16(afh[i], bh, acc[i][j], 0, 0, 0);
                acc[i][j] = __builtin_amdgcn_mfma_f32_16x16x32_bf16(afl[i], bh, acc[i][j], 0, 0, 0);
                acc[i][j] = __builtin_amdgcn_mfma_f32_16x16x32_bf16(afh[i], bl, acc[i][j], 0, 0, 0);
            }
        }
    }

    #pragma unroll
    for (int i = 0; i < 4; ++i) {
        #pragma unroll
        for (int r = 0; r < 4; ++r) {
            const int row = m0 + wr * 64 + i * 16 + lkg * 4 + r;
            const float sm = (MODE == 3) ? scale[(size_t)row * ECNT + e] : 0.0f;
            #pragma unroll
            for (int j = 0; j < 4; ++j) {
                const int col = n0 + wc * 64 + j * 16 + lrow;
                const float bj = bias ? bias[col] : 0.0f;
                const float vres = acc[i][j][r] + bj;
                float* op = out + (size_t)row * ldo + col;
                if (MODE == 0) *op = vres;
                else if (MODE == 1) *op = *op + vres;
                else if (MODE == 2) *op = fmaxf(vres, 0.0f);
                else *op = *op + sm * vres;
            }
        }
    }
}

// ---------------- flash-style causal attention (fp32) — exact round-1 version ----------------
__global__ __launch_bounds__(256)
void attn_kernel(const float* __restrict__ q, const float* __restrict__ k,
                 const float* __restrict__ v, float* __restrict__ o)
{
    __shared__ float Ks[64 * 65];
    __shared__ float Vs[64 * 65];
    __shared__ float Qs[16 * 65];
    __shared__ float Ps[4 * 65];

    const int t0 = blockIdx.x * 16;
    const int bh = blockIdx.y;
    const int b = bh / HCNT, hh = bh % HCNT;
    const size_t base = (size_t)b * TT * CDIM + (size_t)hh * HSD;
    const int tid = threadIdx.x;
    const int w = tid >> 6, lane = tid & 63;

    {   // load 16 q rows
        int row = tid >> 4, d0 = (tid & 15) * 4;
        float4 qa = *reinterpret_cast<const float4*>(q + base + (size_t)(t0 + row) * CDIM + d0);
        Qs[row * 65 + d0 + 0] = qa.x;
        Qs[row * 65 + d0 + 1] = qa.y;
        Qs[row * 65 + d0 + 2] = qa.z;
        Qs[row * 65 + d0 + 3] = qa.w;
    }

    float m_[4], l_[4], o_[4];
    #pragma unroll
    for (int rr = 0; rr < 4; ++rr) { m_[rr] = -1e30f; l_[rr] = 0.0f; o_[rr] = 0.0f; }
    const float sscale = rsqrtf((float)CDIM);   // C^-0.5 (as in reference)

    for (int s0 = 0; s0 <= t0 + 15; s0 += 64) {
        __syncthreads();   // previous tile fully consumed (also publishes Qs on iter 0)
        {   // load K,V tile: 64 rows x 64
            int row = tid >> 2, g = (tid & 3) * 16;
            const float* ksrc = k + base + (size_t)(s0 + row) * CDIM + g;
            const float* vsrc = v + base + (size_t)(s0 + row) * CDIM + g;
            #pragma unroll
            for (int i = 0; i < 16; i += 4) {
                float4 ka = *reinterpret_cast<const float4*>(ksrc + i);
                Ks[row * 65 + g + i + 0] = ka.x;
                Ks[row * 65 + g + i + 1] = ka.y;
                Ks[row * 65 + g + i + 2] = ka.z;
                Ks[row * 65 + g + i + 3] = ka.w;
                float4 va = *reinterpret_cast<const float4*>(vsrc + i);
                Vs[row * 65 + g + i + 0] = va.x;
                Vs[row * 65 + g + i + 1] = va.y;
                Vs[row * 65 + g + i + 2] = va.z;
                Vs[row * 65 + g + i + 3] = va.w;
            }
        }
        __syncthreads();

        #pragma unroll
        for (int rr = 0; rr < 4; ++rr) {
            const int t = t0 + w * 4 + rr;
            const float* qr = &Qs[(w * 4 + rr) * 65];
            const float* kr = &Ks[lane * 65];
            float s = 0.0f;
            #pragma unroll 8
            for (int d = 0; d < 64; ++d) s = fmaf(qr[d], kr[d], s);
            s *= sscale;
            if (s0 + lane > t) s = -1e30f;

            float mx = wave_max(s);
            float mnew = fmaxf(m_[rr], mx);
            float p = __expf(s - mnew);
            float ps = wave_sum(p);
            float corr = __expf(m_[rr] - mnew);
            l_[rr] = l_[rr] * corr + ps;
            m_[rr] = mnew;
            Ps[w * 65 + lane] = p;
            float po = 0.0f;
            const float* pr = &Ps[w * 65];
            #pragma unroll 8
            for (int j = 0; j < 64; ++j) po = fmaf(pr[j], Vs[j * 65 + lane], po);
            o_[rr] = o_[rr] * corr + po;
        }
    }

    #pragma unroll
    for (int rr = 0; rr < 4; ++rr) {
        const int t = t0 + w * 4 + rr;
        o[base + (size_t)t * CDIM + lane] = o_[rr] / l_[rr];
    }
}

// ---------------- gate + top-2 + softmax -> comb[N,E] ----------------
__global__ __launch_bounds__(256)
void gate_kernel(const float* __restrict__ h2, const float* __restrict__ gw,
                 float* __restrict__ comb)
{
    __shared__ float gws[ECNT * CDIM];
    int tid = threadIdx.x;
    for (int i = tid; i < ECNT * CDIM; i += 256) gws[i] = gw[i];
    __syncthreads();
    int t = blockIdx.x * 256 + tid;
    const float* hr = h2 + (size_t)t * CDIM;
    float g[ECNT] = {};
    for (int c = 0; c < CDIM; ++c) {
        float hv = hr[c];
        #pragma unroll
        for (int e = 0; e < ECNT; ++e) g[e] = fmaf(hv, gws[e * CDIM + c], g[e]);
    }
    int e0 = 0; float g0 = g[0];
    #pragma unroll
    for (int e = 1; e < ECNT; ++e) if (g[e] > g0) { g0 = g[e]; e0 = e; }
    int e1 = -1; float g1 = -1e30f;
    #pragma unroll
    for (int e = 0; e < ECNT; ++e) if (e != e0 && g[e] > g1) { g1 = g[e]; e1 = e; }
    float z = __expf(g1 - g0);          // <= 1
    float w0 = 1.0f / (1.0f + z);
    float w1 = z / (1.0f + z);
    #pragma unroll
    for (int e = 0; e < ECNT; ++e)
        comb[(size_t)t * ECNT + e] = (e == e0) ? w0 : ((e == e1) ? w1 : 0.0f);
}

// ---------------- per-row cross-entropy ----------------
__global__ __launch_bounds__(256)
void loss_row_kernel(const float* __restrict__ logits, const int* __restrict__ tgt,
                     float* __restrict__ lrow)
{
    int row = blockIdx.x;
    const float* lr = logits + (size_t)row * VOC;
    int tid = threadIdx.x, w = tid >> 6, lane = tid & 63;
    __shared__ float red[4];
    float mx = -1e30f;
    for (int i = tid; i < VOC; i += 256) mx = fmaxf(mx, lr[i]);
    mx = wave_max(mx);
    if (lane == 0) red[w] = mx;
    __syncthreads();
    mx = fmaxf(fmaxf(red[0], red[1]), fmaxf(red[2], red[3]));
    __syncthreads();
    float se = 0.0f;
    for (int i = tid; i < VOC; i += 256) se += expf(lr[i] - mx);
    se = wave_sum(se);
    if (lane == 0) red[w] = se;
    __syncthreads();
    if (tid == 0) {
        float lse = mx + logf(red[0] + red[1] + red[2] + red[3]);
        lrow[row] = lse - lr[tgt[row]];
    }
}

__global__ __launch_bounds__(256)
void loss_reduce_kernel(const float* __restrict__ lrow, float* __restrict__ out)
{
    int tid = threadIdx.x, w = tid >> 6, lane = tid & 63;
    float s = 0.0f;
    for (int i = tid; i < NTOK; i += 256) s += lrow[i];
    s = wave_sum(s);
    __shared__ float red[4];
    if (lane == 0) red[w] = s;
    __syncthreads();
    if (tid == 0) out[0] = (red[0] + red[1] + red[2] + red[3]) * (1.0f / NTOK);
}

// ---------------- launch (round-1 structure) ----------------
extern "C" void kernel_launch(void* const* d_in, const int* in_sizes, int n_in,
                              void* d_out, int out_size, void* d_ws, size_t ws_size,
                              hipStream_t stream)
{
    const int*   idx     = (const int*)d_in[0];
    const int*   targets = (const int*)d_in[1];
    const float* tok_emb = (const float*)d_in[2];
    const float* pos_emb = (const float*)d_in[3];
    const float* ln1_s   = (const float*)d_in[4];
    const float* ln1_b   = (const float*)d_in[5];
    const float* wq      = (const float*)d_in[6];
    const float* wk      = (const float*)d_in[7];
    const float* wv      = (const float*)d_in[8];
    const float* wo      = (const float*)d_in[9];
    const float* bo      = (const float*)d_in[10];
    const float* ln2_s   = (const float*)d_in[11];
    const float* ln2_b   = (const float*)d_in[12];
    const float* gate_w  = (const float*)d_in[13];
    const float* w1      = (const float*)d_in[14];
    const float* b1      = (const float*)d_in[15];
    const float* w2      = (const float*)d_in[16];
    const float* b2      = (const float*)d_in[17];
    const float* lm_w    = (const float*)d_in[18];
    const float* lm_b    = (const float*)d_in[19];
    float* out = (float*)d_out;

    float* ws   = (float*)d_ws;
    float* wp   = ws;                                // 3*L*C*C  ([w3][l][n][k] B^T)
    float* x    = wp + (size_t)3 * LCNT * CDIM * CDIM;
    float* hbuf = x    + (size_t)NTOK * CDIM;        // LN1 out, later attn out
    float* qbuf = hbuf + (size_t)NTOK * CDIM;        // q, later h2
    float* kbuf = qbuf + (size_t)NTOK * CDIM;
    float* vbuf = kbuf + (size_t)NTOK * CDIM;
    float* hid  = vbuf + (size_t)NTOK * CDIM;        // N*FF
    float* comb = hid  + (size_t)NTOK * FF;          // N*E
    float* lrow = comb + (size_t)NTOK * ECNT;        // N

    dim3 blk(256);

    repack_kernel<<<(3 * LCNT * CDIM * CDIM) / 256, blk, 0, stream>>>(wq, wk, wv, wp);
    embed_kernel<<<(NTOK * CDIM) / 256, blk, 0, stream>>>(idx, tok_emb, pos_emb, x);

    for (int l = 0; l < LCNT; ++l) {
        ln_kernel<<<NTOK, blk, 0, stream>>>(x, ln1_s + (size_t)l * CDIM, ln1_b + (size_t)l * CDIM, hbuf);

        const size_t mw = (size_t)CDIM * CDIM;
        gemm_bf16_kernel<0><<<dim3(CDIM / BN, NTOK / BM), blk, 0, stream>>>(
            NTOK, CDIM, CDIM, hbuf, CDIM, wp + (0 * LCNT + l) * mw, CDIM, nullptr, qbuf, CDIM, nullptr, 0);
        gemm_bf16_kernel<0><<<dim3(CDIM / BN, NTOK / BM), blk, 0, stream>>>(
            NTOK, CDIM, CDIM, hbuf, CDIM, wp + (1 * LCNT + l) * mw, CDIM, nullptr, kbuf, CDIM, nullptr, 0);
        gemm_bf16_kernel<0><<<dim3(CDIM / BN, NTOK / BM), blk, 0, stream>>>(
            NTOK, CDIM, CDIM, hbuf, CDIM, wp + (2 * LCNT + l) * mw, CDIM, nullptr, vbuf, CDIM, nullptr, 0);

        attn_kernel<<<dim3(TT / 16, BB * HCNT), blk, 0, stream>>>(qbuf, kbuf, vbuf, hbuf);

        gemm_bf16_kernel<1><<<dim3(CDIM / BN, NTOK / BM), blk, 0, stream>>>(
            NTOK, CDIM, CDIM, hbuf, CDIM, wo + (size_t)l * CDIM * CDIM, CDIM,
            bo + (size_t)l * CDIM, x, CDIM, nullptr, 0);

        ln_kernel<<<NTOK, blk, 0, stream>>>(x, ln2_s + (size_t)l * CDIM, ln2_b + (size_t)l * CDIM, qbuf);
        gate_kernel<<<NTOK / 256, blk, 0, stream>>>(qbuf, gate_w + (size_t)l * ECNT * CDIM, comb);

        for (int e = 0; e < ECNT; ++e) {
            const float* w1e = w1 + ((size_t)l * ECNT + e) * FF * CDIM;
            const float* b1e = b1 + ((size_t)l * ECNT + e) * FF;
            const float* w2e = w2 + ((size_t)l * ECNT + e) * CDIM * FF;
            const float* b2e = b2 + ((size_t)l * ECNT + e) * CDIM;
            gemm_bf16_kernel<2><<<dim3(FF / BN, NTOK / BM), blk, 0, stream>>>(
                NTOK, FF, CDIM, qbuf, CDIM, w1e, CDIM, b1e, hid, FF, nullptr, 0);
            gemm_bf16_kernel<3><<<dim3(CDIM / BN, NTOK / BM), blk, 0, stream>>>(
                NTOK, CDIM, FF, hid, FF, w2e, FF, b2e, x, CDIM, comb, e);
        }
    }

    gemm_bf16_kernel<0><<<dim3(VOC / BN, NTOK / BM), blk, 0, stream>>>(
        NTOK, VOC, CDIM, x, CDIM, lm_w, CDIM, lm_b, out, VOC, nullptr, 0);

    loss_row_kernel<<<NTOK, blk, 0, stream>>>(out, targets, lrow);
    loss_reduce_kernel<<<1, blk, 0, stream>>>(lrow, out + (size_t)NTOK * VOC);
}

// Round 5
// 2360.638 us; speedup vs baseline: 5.4186x; 2.2702x over previous
//
#include <hip/hip_runtime.h>
#include <hip/hip_bf16.h>

// Problem constants (from reference)
#define LCNT 2
#define HCNT 12
#define CDIM 768
#define HSD  64
#define ECNT 8
#define VOC  32000
#define BB   2
#define TT   1024
#define NTOK 2048   // B*T
#define FF   3072   // 4*C
#define TOTCAP 5120 // 2*NTOK + 8*128 padding capacity

typedef __attribute__((ext_vector_type(8))) short bf16x8;
typedef __attribute__((ext_vector_type(4))) float f32x4;

// ---------------- helpers ----------------
__device__ __forceinline__ float wave_sum(float v) {
    #pragma unroll
    for (int off = 32; off; off >>= 1) v += __shfl_xor(v, off);
    return v;
}
__device__ __forceinline__ float wave_max(float v) {
    #pragma unroll
    for (int off = 32; off; off >>= 1) v = fmaxf(v, __shfl_xor(v, off));
    return v;
}
__device__ __forceinline__ unsigned short f2bf(float f) {
    unsigned int u = __float_as_uint(f);
    unsigned int r = (u + 0x7FFFu + ((u >> 16) & 1u)) >> 16;
    return (unsigned short)r;
}
__device__ __forceinline__ float bf2f(unsigned short h) {
    return __uint_as_float((unsigned int)h << 16);
}
__device__ __forceinline__ void split2(float a, unsigned short& h, unsigned short& l) {
    h = f2bf(a);
    l = f2bf(a - bf2f(h));
}
__device__ __forceinline__ ushort4 cvt4(float4 v) {
    ushort4 r;
    r.x = f2bf(v.x); r.y = f2bf(v.y); r.z = f2bf(v.z); r.w = f2bf(v.w);
    return r;
}

// ---------------- embedding ----------------
__global__ __launch_bounds__(256)
void embed_kernel(const int* __restrict__ idx, const float* __restrict__ tok,
                  const float* __restrict__ pos, float* __restrict__ x)
{
    int i = blockIdx.x * 256 + threadIdx.x;      // N*C total
    int c = i % CDIM;
    int n = i / CDIM;
    int t = n % TT;
    x[i] = tok[(size_t)idx[n] * CDIM + c] + pos[(size_t)t * CDIM + c];
}

// ---------------- repack wq/wk/wv [L,H,C,HS] -> wp[w3][l][n=h*HS+d][k=c]  (B^T layout) ----------------
__global__ __launch_bounds__(256)
void repack_kernel(const float* __restrict__ wq, const float* __restrict__ wk,
                   const float* __restrict__ wv, float* __restrict__ wp)
{
    int i = blockIdx.x * 256 + threadIdx.x;      // 3*L*C*C
    int n  = i % CDIM;
    int c  = (i / CDIM) % CDIM;
    int l  = (i / (CDIM * CDIM)) % LCNT;
    int w3 = i / (CDIM * CDIM * LCNT);
    const float* src = (w3 == 0) ? wq : (w3 == 1) ? wk : wv;
    int h = n / HSD, d = n % HSD;
    wp[((((size_t)w3 * LCNT + l) * CDIM) + n) * CDIM + c] =
        src[((((size_t)l * HCNT + h) * CDIM) + c) * HSD + d];
}

// ---------------- layernorm ----------------
__global__ __launch_bounds__(256)
void ln_kernel(const float* __restrict__ x, const float* __restrict__ sc,
               const float* __restrict__ bs, float* __restrict__ out)
{
    int row = blockIdx.x;
    const float* xr = x + (size_t)row * CDIM;
    float* orow = out + (size_t)row * CDIM;
    int tid = threadIdx.x;
    float v0 = xr[tid], v1 = xr[tid + 256], v2 = xr[tid + 512];
    float s1 = v0 + v1 + v2;
    float s2 = v0 * v0 + v1 * v1 + v2 * v2;
    s1 = wave_sum(s1);
    s2 = wave_sum(s2);
    __shared__ float r1[4], r2[4];
    int w = tid >> 6, lane = tid & 63;
    if (lane == 0) { r1[w] = s1; r2[w] = s2; }
    __syncthreads();
    float t1 = r1[0] + r1[1] + r1[2] + r1[3];
    float t2 = r2[0] + r2[1] + r2[2] + r2[3];
    float mu = t1 * (1.0f / CDIM);
    float var = t2 * (1.0f / CDIM) - mu * mu;
    float rstd = rsqrtf(var + 1e-5f);
    orow[tid]       = (v0 - mu) * rstd * sc[tid]       + bs[tid];
    orow[tid + 256] = (v1 - mu) * rstd * sc[tid + 256] + bs[tid + 256];
    orow[tid + 512] = (v2 - mu) * rstd * sc[tid + 512] + bs[tid + 512];
}

// ---------------- bf16 MFMA GEMM (SPLIT: fp32-grade via hi/lo 3-MFMA; FAST: 1 MFMA) ----------------
// C[m,n] = sum_k A[m,k] * B[n,k]   (B row-major [N][K], i.e. B^T)
// MODE 0: out = acc + bias ; MODE 1: out += acc + bias ; MODE 2: out = relu(acc + bias)
// rowmeta != null: expert mode; blockIdx.z = expert; rowmeta[2e]=row offset, rowmeta[2e+1]=padded count
#define BM 128
#define BN 128
#define BK 32
#define PADK 40   // bf16 stride per row (80 B)

template<int MODE, bool SPLIT>
__global__ __launch_bounds__(256)
void gemm_bf16_kernel(int Kd,
                      const float* __restrict__ A, int lda,
                      const float* __restrict__ B, int ldb,
                      const float* __restrict__ bias,
                      float* __restrict__ out, int ldo,
                      const int* __restrict__ rowmeta,
                      size_t bstride, int biasstride)
{
    __shared__ short Ah[BM * PADK];
    __shared__ short Bh[BN * PADK];
    __shared__ short Al[SPLIT ? BM * PADK : 2];
    __shared__ short Bl[SPLIT ? BN * PADK : 2];

    int roff = 0;
    if (rowmeta) {
        const int ee = blockIdx.z;
        const int rcnt = rowmeta[2 * ee + 1];
        if ((int)(blockIdx.y * BM) >= rcnt) return;
        roff = rowmeta[2 * ee];
        B += (size_t)ee * bstride;
        if (bias) bias += (size_t)ee * biasstride;
    }

    const int tid = threadIdx.x;
    const int m0 = roff + blockIdx.y * BM;
    const int n0 = blockIdx.x * BN;
    const int w = tid >> 6, lane = tid & 63;
    const int wr = w >> 1, wc = w & 1;          // wave tile (64x64)
    const int lrow = lane & 15, lkg = lane >> 4;
    const int srow = tid >> 3, skg = (tid & 7) * 4;

    const float* Ablk = A + (size_t)m0 * lda;
    const float* Bblk = B + (size_t)n0 * ldb;

    float4 pa[4], pb[4];
    #pragma unroll
    for (int p = 0; p < 4; ++p) {
        pa[p] = *(const float4*)(Ablk + (size_t)(p * 32 + srow) * lda + skg);
        pb[p] = *(const float4*)(Bblk + (size_t)(p * 32 + srow) * ldb + skg);
    }

    f32x4 acc[4][4] = {};
    const int nk = Kd / BK;

    for (int t = 0; t < nk; ++t) {
        __syncthreads();   // previous compute done; LDS free
        #pragma unroll
        for (int p = 0; p < 4; ++p) {
            if constexpr (SPLIT) {
                ushort4 h, l;
                split2(pa[p].x, h.x, l.x); split2(pa[p].y, h.y, l.y);
                split2(pa[p].z, h.z, l.z); split2(pa[p].w, h.w, l.w);
                *(ushort4*)(&Ah[(p * 32 + srow) * PADK + skg]) = h;
                *(ushort4*)(&Al[(p * 32 + srow) * PADK + skg]) = l;
                split2(pb[p].x, h.x, l.x); split2(pb[p].y, h.y, l.y);
                split2(pb[p].z, h.z, l.z); split2(pb[p].w, h.w, l.w);
                *(ushort4*)(&Bh[(p * 32 + srow) * PADK + skg]) = h;
                *(ushort4*)(&Bl[(p * 32 + srow) * PADK + skg]) = l;
            } else {
                *(ushort4*)(&Ah[(p * 32 + srow) * PADK + skg]) = cvt4(pa[p]);
                *(ushort4*)(&Bh[(p * 32 + srow) * PADK + skg]) = cvt4(pb[p]);
            }
        }
        __syncthreads();   // writes visible
        if (t + 1 < nk) {
            const int kb = (t + 1) * BK + skg;
            #pragma unroll
            for (int p = 0; p < 4; ++p) {
                pa[p] = *(const float4*)(Ablk + (size_t)(p * 32 + srow) * lda + kb);
                pb[p] = *(const float4*)(Bblk + (size_t)(p * 32 + srow) * ldb + kb);
            }
        }
        bf16x8 afh[4], afl[4];
        #pragma unroll
        for (int i = 0; i < 4; ++i) {
            afh[i] = *(const bf16x8*)(&Ah[(wr * 64 + i * 16 + lrow) * PADK + lkg * 8]);
            if constexpr (SPLIT)
                afl[i] = *(const bf16x8*)(&Al[(wr * 64 + i * 16 + lrow) * PADK + lkg * 8]);
        }
        #pragma unroll
        for (int j = 0; j < 4; ++j) {
            const bf16x8 bh = *(const bf16x8*)(&Bh[(wc * 64 + j * 16 + lrow) * PADK + lkg * 8]);
            if constexpr (SPLIT) {
                const bf16x8 bl = *(const bf16x8*)(&Bl[(wc * 64 + j * 16 + lrow) * PADK + lkg * 8]);
                #pragma unroll
                for (int i = 0; i < 4; ++i) {
                    acc[i][j] = __builtin_amdgcn_mfma_f32_16x16x32_bf16(afh[i], bh, acc[i][j], 0, 0, 0);
                    acc[i][j] = __builtin_amdgcn_mfma_f32_16x16x32_bf16(afl[i], bh, acc[i][j], 0, 0, 0);
                    acc[i][j] = __builtin_amdgcn_mfma_f32_16x16x32_bf16(afh[i], bl, acc[i][j], 0, 0, 0);
                }
            } else {
                #pragma unroll
                for (int i = 0; i < 4; ++i)
                    acc[i][j] = __builtin_amdgcn_mfma_f32_16x16x32_bf16(afh[i], bh, acc[i][j], 0, 0, 0);
            }
        }
    }

    #pragma unroll
    for (int i = 0; i < 4; ++i) {
        #pragma unroll
        for (int r = 0; r < 4; ++r) {
            const int row = m0 + wr * 64 + i * 16 + lkg * 4 + r;
            #pragma unroll
            for (int j = 0; j < 4; ++j) {
                const int col = n0 + wc * 64 + j * 16 + lrow;
                const float bj = bias ? bias[col] : 0.0f;
                const float vres = acc[i][j][r] + bj;
                float* op = out + (size_t)row * ldo + col;
                if (MODE == 0) *op = vres;
                else if (MODE == 1) *op = *op + vres;
                else *op = fmaxf(vres, 0.0f);
            }
        }
    }
}

// ---------------- flash-style causal attention (fp32) ----------------
__global__ __launch_bounds__(256)
void attn_kernel(const float* __restrict__ q, const float* __restrict__ k,
                 const float* __restrict__ v, float* __restrict__ o)
{
    __shared__ float Ks[64 * 65];
    __shared__ float Vs[64 * 65];
    __shared__ float Qs[16 * 65];
    __shared__ float Ps[4 * 65];

    const int t0 = blockIdx.x * 16;
    const int bh = blockIdx.y;
    const int b = bh / HCNT, hh = bh % HCNT;
    const size_t base = (size_t)b * TT * CDIM + (size_t)hh * HSD;
    const int tid = threadIdx.x;
    const int w = tid >> 6, lane = tid & 63;

    {   // load 16 q rows
        int row = tid >> 4, d0 = (tid & 15) * 4;
        float4 qa = *reinterpret_cast<const float4*>(q + base + (size_t)(t0 + row) * CDIM + d0);
        Qs[row * 65 + d0 + 0] = qa.x;
        Qs[row * 65 + d0 + 1] = qa.y;
        Qs[row * 65 + d0 + 2] = qa.z;
        Qs[row * 65 + d0 + 3] = qa.w;
    }

    float m_[4], l_[4], o_[4];
    #pragma unroll
    for (int rr = 0; rr < 4; ++rr) { m_[rr] = -1e30f; l_[rr] = 0.0f; o_[rr] = 0.0f; }
    const float sscale = rsqrtf((float)CDIM);   // C^-0.5 (as in reference)

    for (int s0 = 0; s0 <= t0 + 15; s0 += 64) {
        __syncthreads();
        {   // load K,V tile: 64 rows x 64
            int row = tid >> 2, g = (tid & 3) * 16;
            const float* ksrc = k + base + (size_t)(s0 + row) * CDIM + g;
            const float* vsrc = v + base + (size_t)(s0 + row) * CDIM + g;
            #pragma unroll
            for (int i = 0; i < 16; i += 4) {
                float4 ka = *reinterpret_cast<const float4*>(ksrc + i);
                Ks[row * 65 + g + i + 0] = ka.x;
                Ks[row * 65 + g + i + 1] = ka.y;
                Ks[row * 65 + g + i + 2] = ka.z;
                Ks[row * 65 + g + i + 3] = ka.w;
                float4 va = *reinterpret_cast<const float4*>(vsrc + i);
                Vs[row * 65 + g + i + 0] = va.x;
                Vs[row * 65 + g + i + 1] = va.y;
                Vs[row * 65 + g + i + 2] = va.z;
                Vs[row * 65 + g + i + 3] = va.w;
            }
        }
        __syncthreads();

        #pragma unroll
        for (int rr = 0; rr < 4; ++rr) {
            const int t = t0 + w * 4 + rr;
            const float* qr = &Qs[(w * 4 + rr) * 65];
            const float* kr = &Ks[lane * 65];
            float s = 0.0f;
            #pragma unroll 8
            for (int d = 0; d < 64; ++d) s = fmaf(qr[d], kr[d], s);
            s *= sscale;
            if (s0 + lane > t) s = -1e30f;

            float mx = wave_max(s);
            float mnew = fmaxf(m_[rr], mx);
            float p = __expf(s - mnew);
            float ps = wave_sum(p);
            float corr = __expf(m_[rr] - mnew);
            l_[rr] = l_[rr] * corr + ps;
            m_[rr] = mnew;
            Ps[w * 65 + lane] = p;
            float po = 0.0f;
            const float* pr = &Ps[w * 65];
            #pragma unroll 8
            for (int j = 0; j < 64; ++j) po = fmaf(pr[j], Vs[j * 65 + lane], po);
            o_[rr] = o_[rr] * corr + po;
        }
    }

    #pragma unroll
    for (int rr = 0; rr < 4; ++rr) {
        const int t = t0 + w * 4 + rr;
        o[base + (size_t)t * CDIM + lane] = o_[rr] / l_[rr];
    }
}

// ---------------- gate: logits + top-2 + softmax -> sel[N], wts[N] ----------------
__global__ __launch_bounds__(256)
void gate_kernel(const float* __restrict__ h2, const float* __restrict__ gw,
                 int2* __restrict__ sel, float2* __restrict__ wts)
{
    __shared__ float gws[ECNT * CDIM];
    int tid = threadIdx.x;
    for (int i = tid; i < ECNT * CDIM; i += 256) gws[i] = gw[i];
    __syncthreads();
    int t = blockIdx.x * 256 + tid;
    const float* hr = h2 + (size_t)t * CDIM;
    float g[ECNT] = {};
    for (int c = 0; c < CDIM; ++c) {
        float hv = hr[c];
        #pragma unroll
        for (int e = 0; e < ECNT; ++e) g[e] = fmaf(hv, gws[e * CDIM + c], g[e]);
    }
    int e0 = 0; float g0 = g[0];
    #pragma unroll
    for (int e = 1; e < ECNT; ++e) if (g[e] > g0) { g0 = g[e]; e0 = e; }
    int e1 = -1; float g1 = -1e30f;
    #pragma unroll
    for (int e = 0; e < ECNT; ++e) if (e != e0 && g[e] > g1) { g1 = g[e]; e1 = e; }
    float z = __expf(g1 - g0);          // <= 1
    float w0 = 1.0f / (1.0f + z);
    sel[t] = make_int2(e0, e1);
    wts[t] = make_float2(w0, 1.0f - w0);
}

// ---------------- routing: build expert-grouped permutation (single block) ----------------
__global__ __launch_bounds__(256)
void route_kernel(const int2* __restrict__ sel, int* __restrict__ perm,
                  int* __restrict__ tokpos, int* __restrict__ meta)
{
    __shared__ int cnt[ECNT], off[ECNT], cur[ECNT];
    const int tid = threadIdx.x;
    if (tid < ECNT) cnt[tid] = 0;
    __syncthreads();
    for (int t = tid; t < NTOK; t += 256) {
        atomicAdd(&cnt[sel[t].x], 1);
        atomicAdd(&cnt[sel[t].y], 1);
    }
    __syncthreads();
    if (tid == 0) {
        int run = 0;
        for (int e = 0; e < ECNT; ++e) {
            off[e] = run; cur[e] = 0;
            int pc = (cnt[e] + BM - 1) / BM * BM;
            meta[2 * e] = run; meta[2 * e + 1] = pc;
            run += pc;
        }
    }
    __syncthreads();
    for (int p = tid; p < TOTCAP; p += 256) perm[p] = 0;   // pad slots -> token 0
    __syncthreads();
    for (int t = tid; t < NTOK; t += 256) {
        int2 s = sel[t];
        int p0 = atomicAdd(&cur[s.x], 1); perm[off[s.x] + p0] = t; tokpos[2 * t]     = off[s.x] + p0;
        int p1 = atomicAdd(&cur[s.y], 1); perm[off[s.y] + p1] = t; tokpos[2 * t + 1] = off[s.y] + p1;
    }
}

// ---------------- gather h2 rows into expert order ----------------
__global__ __launch_bounds__(256)
void gather_kernel(const float* __restrict__ h2, const int* __restrict__ perm,
                   float* __restrict__ xg)
{
    int i = blockIdx.x * 256 + threadIdx.x;   // TOTCAP*CDIM
    int c = i % CDIM, p = i / CDIM;
    xg[i] = h2[(size_t)perm[p] * CDIM + c];
}

// ---------------- combine: x += w0*y[pos0] + w1*y[pos1] ----------------
__global__ __launch_bounds__(256)
void combine_kernel(const float* __restrict__ y, const int* __restrict__ tokpos,
                    const float2* __restrict__ wts, float* __restrict__ x)
{
    int i = blockIdx.x * 256 + threadIdx.x;   // NTOK*CDIM
    int c = i % CDIM, t = i / CDIM;
    float2 wv = wts[t];
    x[i] += wv.x * y[(size_t)tokpos[2 * t] * CDIM + c]
          + wv.y * y[(size_t)tokpos[2 * t + 1] * CDIM + c];
}

// ---------------- per-row cross-entropy ----------------
__global__ __launch_bounds__(256)
void loss_row_kernel(const float* __restrict__ logits, const int* __restrict__ tgt,
                     float* __restrict__ lrow)
{
    int row = blockIdx.x;
    const float* lr = logits + (size_t)row * VOC;
    int tid = threadIdx.x, w = tid >> 6, lane = tid & 63;
    __shared__ float red[4];
    float mx = -1e30f;
    for (int i = tid; i < VOC; i += 256) mx = fmaxf(mx, lr[i]);
    mx = wave_max(mx);
    if (lane == 0) red[w] = mx;
    __syncthreads();
    mx = fmaxf(fmaxf(red[0], red[1]), fmaxf(red[2], red[3]));
    __syncthreads();
    float se = 0.0f;
    for (int i = tid; i < VOC; i += 256) se += expf(lr[i] - mx);
    se = wave_sum(se);
    if (lane == 0) red[w] = se;
    __syncthreads();
    if (tid == 0) {
        float lse = mx + logf(red[0] + red[1] + red[2] + red[3]);
        lrow[row] = lse - lr[tgt[row]];
    }
}

__global__ __launch_bounds__(256)
void loss_reduce_kernel(const float* __restrict__ lrow, float* __restrict__ out)
{
    int tid = threadIdx.x, w = tid >> 6, lane = tid & 63;
    float s = 0.0f;
    for (int i = tid; i < NTOK; i += 256) s += lrow[i];
    s = wave_sum(s);
    __shared__ float red[4];
    if (lane == 0) red[w] = s;
    __syncthreads();
    if (tid == 0) out[0] = (red[0] + red[1] + red[2] + red[3]) * (1.0f / NTOK);
}

// ---------------- launch ----------------
extern "C" void kernel_launch(void* const* d_in, const int* in_sizes, int n_in,
                              void* d_out, int out_size, void* d_ws, size_t ws_size,
                              hipStream_t stream)
{
    const int*   idx     = (const int*)d_in[0];
    const int*   targets = (const int*)d_in[1];
    const float* tok_emb = (const float*)d_in[2];
    const float* pos_emb = (const float*)d_in[3];
    const float* ln1_s   = (const float*)d_in[4];
    const float* ln1_b   = (const float*)d_in[5];
    const float* wq      = (const float*)d_in[6];
    const float* wk      = (const float*)d_in[7];
    const float* wv      = (const float*)d_in[8];
    const float* wo      = (const float*)d_in[9];
    const float* bo      = (const float*)d_in[10];
    const float* ln2_s   = (const float*)d_in[11];
    const float* ln2_b   = (const float*)d_in[12];
    const float* gate_w  = (const float*)d_in[13];
    const float* w1      = (const float*)d_in[14];
    const float* b1      = (const float*)d_in[15];
    const float* w2      = (const float*)d_in[16];
    const float* b2      = (const float*)d_in[17];
    const float* lm_w    = (const float*)d_in[18];
    const float* lm_b    = (const float*)d_in[19];
    float* out = (float*)d_out;

    float* ws   = (float*)d_ws;
    float* wp   = ws;                                // 3*L*C*C  ([w3][l][n][k] B^T)
    float* x    = wp   + (size_t)3 * LCNT * CDIM * CDIM;
    float* hbuf = x    + (size_t)NTOK * CDIM;        // LN1 out, attn out
    float* qbuf = hbuf + (size_t)NTOK * CDIM;        // q / h2 ; y overlays qbuf..vbuf during MoE tail
    float* kbuf = qbuf + (size_t)NTOK * CDIM;
    float* vbuf = kbuf + (size_t)NTOK * CDIM;
    float* xg   = vbuf + (size_t)NTOK * CDIM;        // TOTCAP*C gathered h2
    float* hid  = xg   + (size_t)TOTCAP * CDIM;      // TOTCAP*FF
    float* lrow = hid  + (size_t)TOTCAP * FF;        // NTOK
    float2* wts = (float2*)(lrow + NTOK);            // NTOK float2
    int2*  sel  = (int2*)(wts + NTOK);               // NTOK int2
    int*   perm = (int*)(sel + NTOK);                // TOTCAP
    int*  tokpos= perm + TOTCAP;                     // 2*NTOK
    int*   meta = tokpos + 2 * NTOK;                 // 16
    float* ybuf = qbuf;                              // TOTCAP*C (fits in qbuf+kbuf+vbuf)

    dim3 blk(256);

    repack_kernel<<<(3 * LCNT * CDIM * CDIM) / 256, blk, 0, stream>>>(wq, wk, wv, wp);
    embed_kernel<<<(NTOK * CDIM) / 256, blk, 0, stream>>>(idx, tok_emb, pos_emb, x);

    for (int l = 0; l < LCNT; ++l) {
        ln_kernel<<<NTOK, blk, 0, stream>>>(x, ln1_s + (size_t)l * CDIM, ln1_b + (size_t)l * CDIM, hbuf);

        const size_t mw = (size_t)CDIM * CDIM;
        gemm_bf16_kernel<0, true><<<dim3(CDIM / BN, NTOK / BM), blk, 0, stream>>>(
            CDIM, hbuf, CDIM, wp + (0 * LCNT + l) * mw, CDIM, nullptr, qbuf, CDIM, nullptr, 0, 0);
        gemm_bf16_kernel<0, true><<<dim3(CDIM / BN, NTOK / BM), blk, 0, stream>>>(
            CDIM, hbuf, CDIM, wp + (1 * LCNT + l) * mw, CDIM, nullptr, kbuf, CDIM, nullptr, 0, 0);
        gemm_bf16_kernel<0, true><<<dim3(CDIM / BN, NTOK / BM), blk, 0, stream>>>(
            CDIM, hbuf, CDIM, wp + (2 * LCNT + l) * mw, CDIM, nullptr, vbuf, CDIM, nullptr, 0, 0);

        attn_kernel<<<dim3(TT / 16, BB * HCNT), blk, 0, stream>>>(qbuf, kbuf, vbuf, hbuf);

        gemm_bf16_kernel<1, true><<<dim3(CDIM / BN, NTOK / BM), blk, 0, stream>>>(
            CDIM, hbuf, CDIM, wo + (size_t)l * CDIM * CDIM, CDIM,
            bo + (size_t)l * CDIM, x, CDIM, nullptr, 0, 0);

        // --- MoE: gate -> route -> gather -> expert GEMMs -> combine ---
        float* h2 = qbuf;
        ln_kernel<<<NTOK, blk, 0, stream>>>(x, ln2_s + (size_t)l * CDIM, ln2_b + (size_t)l * CDIM, h2);
        gate_kernel<<<NTOK / 256, blk, 0, stream>>>(h2, gate_w + (size_t)l * ECNT * CDIM, sel, wts);
        route_kernel<<<1, blk, 0, stream>>>(sel, perm, tokpos, meta);
        gather_kernel<<<(TOTCAP * CDIM) / 256, blk, 0, stream>>>(h2, perm, xg);

        const float* w1l = w1 + (size_t)l * ECNT * FF * CDIM;
        const float* b1l = b1 + (size_t)l * ECNT * FF;
        const float* w2l = w2 + (size_t)l * ECNT * CDIM * FF;
        const float* b2l = b2 + (size_t)l * ECNT * CDIM;
        if (l == 0) {   // feeds next layer's router -> keep fp32-grade
            gemm_bf16_kernel<2, true><<<dim3(FF / BN, NTOK / BM, ECNT), blk, 0, stream>>>(
                CDIM, xg, CDIM, w1l, CDIM, b1l, hid, FF, meta, (size_t)FF * CDIM, FF);
            gemm_bf16_kernel<0, true><<<dim3(CDIM / BN, NTOK / BM, ECNT), blk, 0, stream>>>(
                FF, hid, FF, w2l, FF, b2l, ybuf, CDIM, meta, (size_t)CDIM * FF, CDIM);
        } else {        // feeds only logits -> fast single-bf16
            gemm_bf16_kernel<2, false><<<dim3(FF / BN, NTOK / BM, ECNT), blk, 0, stream>>>(
                CDIM, xg, CDIM, w1l, CDIM, b1l, hid, FF, meta, (size_t)FF * CDIM, FF);
            gemm_bf16_kernel<0, false><<<dim3(CDIM / BN, NTOK / BM, ECNT), blk, 0, stream>>>(
                FF, hid, FF, w2l, FF, b2l, ybuf, CDIM, meta, (size_t)CDIM * FF, CDIM);
        }
        combine_kernel<<<(NTOK * CDIM) / 256, blk, 0, stream>>>(ybuf, tokpos, wts, x);
    }

    gemm_bf16_kernel<0, false><<<dim3(VOC / BN, NTOK / BM), blk, 0, stream>>>(
        CDIM, x, CDIM, lm_w, CDIM, lm_b, out, VOC, nullptr, 0, 0);

    loss_row_kernel<<<NTOK, blk, 0, stream>>>(out, targets, lrow);
    loss_reduce_kernel<<<1, blk, 0, stream>>>(lrow, out + (size_t)NTOK * VOC);
}

// Round 6
// 1676.751 us; speedup vs baseline: 7.6287x; 1.4079x over previous
//
#include <hip/hip_runtime.h>
#include <hip/hip_bf16.h>

// Problem constants (from reference)
#define LCNT 2
#define HCNT 12
#define CDIM 768
#define HSD  64
#define ECNT 8
#define VOC  32000
#define BB   2
#define TT   1024
#define NTOK 2048   // B*T
#define FF   3072   // 4*C
#define TOTCAP 5120 // 2*NTOK + 8*128 padding capacity

typedef __attribute__((ext_vector_type(8))) short bf16x8;
typedef __attribute__((ext_vector_type(4))) float f32x4;

// ---------------- helpers ----------------
__device__ __forceinline__ float wave_sum(float v) {
    #pragma unroll
    for (int off = 32; off; off >>= 1) v += __shfl_xor(v, off);
    return v;
}
__device__ __forceinline__ float wave_max(float v) {
    #pragma unroll
    for (int off = 32; off; off >>= 1) v = fmaxf(v, __shfl_xor(v, off));
    return v;
}
__device__ __forceinline__ unsigned short f2bf(float f) {
    unsigned int u = __float_as_uint(f);
    unsigned int r = (u + 0x7FFFu + ((u >> 16) & 1u)) >> 16;
    return (unsigned short)r;
}
__device__ __forceinline__ float bf2f(unsigned short h) {
    return __uint_as_float((unsigned int)h << 16);
}
__device__ __forceinline__ void split2(float a, unsigned short& h, unsigned short& l) {
    h = f2bf(a);
    l = f2bf(a - bf2f(h));
}
__device__ __forceinline__ ushort4 cvt4(float4 v) {
    ushort4 r;
    r.x = f2bf(v.x); r.y = f2bf(v.y); r.z = f2bf(v.z); r.w = f2bf(v.w);
    return r;
}

// ---------------- embedding ----------------
__global__ __launch_bounds__(256)
void embed_kernel(const int* __restrict__ idx, const float* __restrict__ tok,
                  const float* __restrict__ pos, float* __restrict__ x)
{
    int i = blockIdx.x * 256 + threadIdx.x;      // N*C total
    int c = i % CDIM;
    int n = i / CDIM;
    int t = n % TT;
    x[i] = tok[(size_t)idx[n] * CDIM + c] + pos[(size_t)t * CDIM + c];
}

// ---------------- repack wq/wk/wv [L,H,C,HS] -> wp[w3][l][n=h*HS+d][k=c]  (B^T layout) ----------------
__global__ __launch_bounds__(256)
void repack_kernel(const float* __restrict__ wq, const float* __restrict__ wk,
                   const float* __restrict__ wv, float* __restrict__ wp)
{
    int i = blockIdx.x * 256 + threadIdx.x;      // 3*L*C*C
    int n  = i % CDIM;
    int c  = (i / CDIM) % CDIM;
    int l  = (i / (CDIM * CDIM)) % LCNT;
    int w3 = i / (CDIM * CDIM * LCNT);
    const float* src = (w3 == 0) ? wq : (w3 == 1) ? wk : wv;
    int h = n / HSD, d = n % HSD;
    wp[((((size_t)w3 * LCNT + l) * CDIM) + n) * CDIM + c] =
        src[((((size_t)l * HCNT + h) * CDIM) + c) * HSD + d];
}

// ---------------- layernorm ----------------
__global__ __launch_bounds__(256)
void ln_kernel(const float* __restrict__ x, const float* __restrict__ sc,
               const float* __restrict__ bs, float* __restrict__ out)
{
    int row = blockIdx.x;
    const float* xr = x + (size_t)row * CDIM;
    float* orow = out + (size_t)row * CDIM;
    int tid = threadIdx.x;
    float v0 = xr[tid], v1 = xr[tid + 256], v2 = xr[tid + 512];
    float s1 = v0 + v1 + v2;
    float s2 = v0 * v0 + v1 * v1 + v2 * v2;
    s1 = wave_sum(s1);
    s2 = wave_sum(s2);
    __shared__ float r1[4], r2[4];
    int w = tid >> 6, lane = tid & 63;
    if (lane == 0) { r1[w] = s1; r2[w] = s2; }
    __syncthreads();
    float t1 = r1[0] + r1[1] + r1[2] + r1[3];
    float t2 = r2[0] + r2[1] + r2[2] + r2[3];
    float mu = t1 * (1.0f / CDIM);
    float var = t2 * (1.0f / CDIM) - mu * mu;
    float rstd = rsqrtf(var + 1e-5f);
    orow[tid]       = (v0 - mu) * rstd * sc[tid]       + bs[tid];
    orow[tid + 256] = (v1 - mu) * rstd * sc[tid + 256] + bs[tid + 256];
    orow[tid + 512] = (v2 - mu) * rstd * sc[tid + 512] + bs[tid + 512];
}

// ---------------- bf16 MFMA GEMM (SPLIT: fp32-grade via hi/lo 3-MFMA; FAST: 1 MFMA) ----------------
// C[m,n] = sum_k A[m,k] * B[n,k]   (B row-major [N][K], i.e. B^T)
// MODE 0: out = acc + bias ; MODE 1: out += acc + bias ; MODE 2: out = relu(acc + bias)
// rowmeta != null: expert mode; blockIdx.z = expert; rowmeta[2e]=row offset, rowmeta[2e+1]=padded count
#define BM 128
#define BN 128
#define BK 32
#define PADK 40   // bf16 stride per row (80 B)

template<int MODE, bool SPLIT>
__global__ __launch_bounds__(256)
void gemm_bf16_kernel(int Kd,
                      const float* __restrict__ A, int lda,
                      const float* __restrict__ B, int ldb,
                      const float* __restrict__ bias,
                      float* __restrict__ out, int ldo,
                      const int* __restrict__ rowmeta,
                      size_t bstride, int biasstride)
{
    __shared__ short Ah[BM * PADK];
    __shared__ short Bh[BN * PADK];
    __shared__ short Al[SPLIT ? BM * PADK : 2];
    __shared__ short Bl[SPLIT ? BN * PADK : 2];

    int roff = 0;
    if (rowmeta) {
        const int ee = blockIdx.z;
        const int rcnt = rowmeta[2 * ee + 1];
        if ((int)(blockIdx.y * BM) >= rcnt) return;
        roff = rowmeta[2 * ee];
        B += (size_t)ee * bstride;
        if (bias) bias += (size_t)ee * biasstride;
    }

    const int tid = threadIdx.x;
    const int m0 = roff + blockIdx.y * BM;
    const int n0 = blockIdx.x * BN;
    const int w = tid >> 6, lane = tid & 63;
    const int wr = w >> 1, wc = w & 1;          // wave tile (64x64)
    const int lrow = lane & 15, lkg = lane >> 4;
    const int srow = tid >> 3, skg = (tid & 7) * 4;

    const float* Ablk = A + (size_t)m0 * lda;
    const float* Bblk = B + (size_t)n0 * ldb;

    float4 pa[4], pb[4];
    #pragma unroll
    for (int p = 0; p < 4; ++p) {
        pa[p] = *(const float4*)(Ablk + (size_t)(p * 32 + srow) * lda + skg);
        pb[p] = *(const float4*)(Bblk + (size_t)(p * 32 + srow) * ldb + skg);
    }

    f32x4 acc[4][4] = {};
    const int nk = Kd / BK;

    for (int t = 0; t < nk; ++t) {
        __syncthreads();   // previous compute done; LDS free
        #pragma unroll
        for (int p = 0; p < 4; ++p) {
            if constexpr (SPLIT) {
                ushort4 h, l;
                split2(pa[p].x, h.x, l.x); split2(pa[p].y, h.y, l.y);
                split2(pa[p].z, h.z, l.z); split2(pa[p].w, h.w, l.w);
                *(ushort4*)(&Ah[(p * 32 + srow) * PADK + skg]) = h;
                *(ushort4*)(&Al[(p * 32 + srow) * PADK + skg]) = l;
                split2(pb[p].x, h.x, l.x); split2(pb[p].y, h.y, l.y);
                split2(pb[p].z, h.z, l.z); split2(pb[p].w, h.w, l.w);
                *(ushort4*)(&Bh[(p * 32 + srow) * PADK + skg]) = h;
                *(ushort4*)(&Bl[(p * 32 + srow) * PADK + skg]) = l;
            } else {
                *(ushort4*)(&Ah[(p * 32 + srow) * PADK + skg]) = cvt4(pa[p]);
                *(ushort4*)(&Bh[(p * 32 + srow) * PADK + skg]) = cvt4(pb[p]);
            }
        }
        __syncthreads();   // writes visible
        if (t + 1 < nk) {
            const int kb = (t + 1) * BK + skg;
            #pragma unroll
            for (int p = 0; p < 4; ++p) {
                pa[p] = *(const float4*)(Ablk + (size_t)(p * 32 + srow) * lda + kb);
                pb[p] = *(const float4*)(Bblk + (size_t)(p * 32 + srow) * ldb + kb);
            }
        }
        bf16x8 afh[4], afl[4];
        #pragma unroll
        for (int i = 0; i < 4; ++i) {
            afh[i] = *(const bf16x8*)(&Ah[(wr * 64 + i * 16 + lrow) * PADK + lkg * 8]);
            if constexpr (SPLIT)
                afl[i] = *(const bf16x8*)(&Al[(wr * 64 + i * 16 + lrow) * PADK + lkg * 8]);
        }
        #pragma unroll
        for (int j = 0; j < 4; ++j) {
            const bf16x8 bh = *(const bf16x8*)(&Bh[(wc * 64 + j * 16 + lrow) * PADK + lkg * 8]);
            if constexpr (SPLIT) {
                const bf16x8 bl = *(const bf16x8*)(&Bl[(wc * 64 + j * 16 + lrow) * PADK + lkg * 8]);
                #pragma unroll
                for (int i = 0; i < 4; ++i) {
                    acc[i][j] = __builtin_amdgcn_mfma_f32_16x16x32_bf16(afh[i], bh, acc[i][j], 0, 0, 0);
                    acc[i][j] = __builtin_amdgcn_mfma_f32_16x16x32_bf16(afl[i], bh, acc[i][j], 0, 0, 0);
                    acc[i][j] = __builtin_amdgcn_mfma_f32_16x16x32_bf16(afh[i], bl, acc[i][j], 0, 0, 0);
                }
            } else {
                #pragma unroll
                for (int i = 0; i < 4; ++i)
                    acc[i][j] = __builtin_amdgcn_mfma_f32_16x16x32_bf16(afh[i], bh, acc[i][j], 0, 0, 0);
            }
        }
    }

    #pragma unroll
    for (int i = 0; i < 4; ++i) {
        #pragma unroll
        for (int r = 0; r < 4; ++r) {
            const int row = m0 + wr * 64 + i * 16 + lkg * 4 + r;
            #pragma unroll
            for (int j = 0; j < 4; ++j) {
                const int col = n0 + wc * 64 + j * 16 + lrow;
                const float bj = bias ? bias[col] : 0.0f;
                const float vres = acc[i][j][r] + bj;
                float* op = out + (size_t)row * ldo + col;
                if (MODE == 0) *op = vres;
                else if (MODE == 1) *op = *op + vres;
                else *op = fmaxf(vres, 0.0f);
            }
        }
    }
}

// ---------------- MFMA flash attention, split-precision (fp32-grade) ----------------
// Block: (b,h) x 64 q-rows; 4 waves x 16 q-rows. KV tiles of 64.
// S = Q*K^T uses K row-major (B^T operand, no transpose); PV uses V^T staged in LDS.
#define QBLK 64
#define KVBLK 64

__global__ __launch_bounds__(256)
void attn_mfma_kernel(const float* __restrict__ q, const float* __restrict__ k,
                      const float* __restrict__ v, float* __restrict__ o)
{
    __shared__ short Kh[2][KVBLK][PADK];   // [d-step][key][32d]
    __shared__ short Kl[2][KVBLK][PADK];
    __shared__ short Vh[2][HSD][PADK];     // transposed: [key-step][d][32keys]
    __shared__ short Vl[2][HSD][PADK];
    __shared__ short Ph[4][2][16][PADK];   // [wave][key-step][qrow][32keys]
    __shared__ short Pl[4][2][16][PADK];

    const int t0 = blockIdx.x * QBLK;
    const int bh = blockIdx.y;
    const int b = bh / HCNT, hh = bh % HCNT;
    const size_t base = (size_t)b * TT * CDIM + (size_t)hh * HSD;
    const int tid = threadIdx.x;
    const int w = tid >> 6, lane = tid & 63;
    const int lrow = lane & 15, lkg = lane >> 4;
    const float sscale = rsqrtf((float)CDIM);   // C^-0.5 (as in reference)

    // Q -> registers as split A-frags (row = lane&15 within wave tile, kg = (lane>>4)*8)
    bf16x8 qh[2], ql[2];
    {
        const float* qr = q + base + (size_t)(t0 + w * 16 + lrow) * CDIM;
        #pragma unroll
        for (int ks = 0; ks < 2; ++ks) {
            #pragma unroll
            for (int j = 0; j < 8; ++j) {
                unsigned short h, l;
                split2(qr[ks * 32 + lkg * 8 + j], h, l);
                qh[ks][j] = (short)h;
                ql[ks][j] = (short)l;
            }
        }
    }

    f32x4 oacc[4] = {};
    float m_[4], l_[4];
    #pragma unroll
    for (int rr = 0; rr < 4; ++rr) { m_[rr] = -1e30f; l_[rr] = 0.0f; }

    for (int s0 = 0; s0 <= t0 + QBLK - 1; s0 += KVBLK) {
        __syncthreads();   // previous tile fully consumed
        {   // stage K (row-major, like GEMM B^T operand)
            const int srow = tid >> 3, skg = (tid & 7) * 4;
            #pragma unroll
            for (int p = 0; p < 2; ++p) {
                const float* krow = k + base + (size_t)(s0 + p * 32 + srow) * CDIM;
                #pragma unroll
                for (int ks = 0; ks < 2; ++ks) {
                    float4 a = *(const float4*)(krow + ks * 32 + skg);
                    ushort4 h, l;
                    split2(a.x, h.x, l.x); split2(a.y, h.y, l.y);
                    split2(a.z, h.z, l.z); split2(a.w, h.w, l.w);
                    *(ushort4*)(&Kh[ks][p * 32 + srow][skg]) = h;
                    *(ushort4*)(&Kl[ks][p * 32 + srow][skg]) = l;
                }
            }
            // stage V transposed: Vt[d][key]
            const int key = tid & 63, dg = (tid >> 6) * 16;
            const float* vrow = v + base + (size_t)(s0 + key) * CDIM + dg;
            const int kst = key >> 5, ko = key & 31;
            #pragma unroll
            for (int dd = 0; dd < 16; dd += 4) {
                float4 a = *(const float4*)(vrow + dd);
                unsigned short h, l;
                split2(a.x, h, l); Vh[kst][dg + dd + 0][ko] = h; Vl[kst][dg + dd + 0][ko] = l;
                split2(a.y, h, l); Vh[kst][dg + dd + 1][ko] = h; Vl[kst][dg + dd + 1][ko] = l;
                split2(a.z, h, l); Vh[kst][dg + dd + 2][ko] = h; Vl[kst][dg + dd + 2][ko] = l;
                split2(a.w, h, l); Vh[kst][dg + dd + 3][ko] = h; Vl[kst][dg + dd + 3][ko] = l;
            }
        }
        __syncthreads();

        // S = Q*K^T  (D rows = q, cols = key)
        f32x4 sacc[4] = {};
        #pragma unroll
        for (int j = 0; j < 4; ++j) {
            #pragma unroll
            for (int ks = 0; ks < 2; ++ks) {
                const bf16x8 bh = *(const bf16x8*)(&Kh[ks][j * 16 + lrow][lkg * 8]);
                const bf16x8 bl = *(const bf16x8*)(&Kl[ks][j * 16 + lrow][lkg * 8]);
                sacc[j] = __builtin_amdgcn_mfma_f32_16x16x32_bf16(qh[ks], bh, sacc[j], 0, 0, 0);
                sacc[j] = __builtin_amdgcn_mfma_f32_16x16x32_bf16(ql[ks], bh, sacc[j], 0, 0, 0);
                sacc[j] = __builtin_amdgcn_mfma_f32_16x16x32_bf16(qh[ks], bl, sacc[j], 0, 0, 0);
            }
        }

        // online softmax (lane owns 4 rows x 4 cols); row-reduce over 16-lane group
        #pragma unroll
        for (int rr = 0; rr < 4; ++rr) {
            const int qi = t0 + w * 16 + lkg * 4 + rr;
            float pv[4];
            float mx = -1e30f;
            #pragma unroll
            for (int j = 0; j < 4; ++j) {
                float s = sacc[j][rr] * sscale;
                if (s0 + j * 16 + lrow > qi) s = -1e30f;
                pv[j] = s;
                mx = fmaxf(mx, s);
            }
            #pragma unroll
            for (int off = 1; off < 16; off <<= 1) mx = fmaxf(mx, __shfl_xor(mx, off));
            const float mnew = fmaxf(m_[rr], mx);
            const float corr = __expf(m_[rr] - mnew);
            float ps = 0.0f;
            #pragma unroll
            for (int j = 0; j < 4; ++j) { pv[j] = __expf(pv[j] - mnew); ps += pv[j]; }
            #pragma unroll
            for (int off = 1; off < 16; off <<= 1) ps += __shfl_xor(ps, off);
            l_[rr] = l_[rr] * corr + ps;
            m_[rr] = mnew;
            #pragma unroll
            for (int jd = 0; jd < 4; ++jd) oacc[jd][rr] *= corr;
            #pragma unroll
            for (int j = 0; j < 4; ++j) {   // write split P (per-wave-private region)
                unsigned short h, l;
                split2(pv[j], h, l);
                const int key = j * 16 + lrow;
                Ph[w][key >> 5][lkg * 4 + rr][key & 31] = h;
                Pl[w][key >> 5][lkg * 4 + rr][key & 31] = l;
            }
        }

        // O += P * V   (A = P from own wave's LDS region, B = Vt)
        #pragma unroll
        for (int ks = 0; ks < 2; ++ks) {
            const bf16x8 ah = *(const bf16x8*)(&Ph[w][ks][lrow][lkg * 8]);
            const bf16x8 al = *(const bf16x8*)(&Pl[w][ks][lrow][lkg * 8]);
            #pragma unroll
            for (int jd = 0; jd < 4; ++jd) {
                const bf16x8 bh = *(const bf16x8*)(&Vh[ks][jd * 16 + lrow][lkg * 8]);
                const bf16x8 bl = *(const bf16x8*)(&Vl[ks][jd * 16 + lrow][lkg * 8]);
                oacc[jd] = __builtin_amdgcn_mfma_f32_16x16x32_bf16(ah, bh, oacc[jd], 0, 0, 0);
                oacc[jd] = __builtin_amdgcn_mfma_f32_16x16x32_bf16(al, bh, oacc[jd], 0, 0, 0);
                oacc[jd] = __builtin_amdgcn_mfma_f32_16x16x32_bf16(ah, bl, oacc[jd], 0, 0, 0);
            }
        }
    }

    #pragma unroll
    for (int rr = 0; rr < 4; ++rr) {
        const int qi = t0 + w * 16 + lkg * 4 + rr;
        const float invl = 1.0f / l_[rr];
        float* orow = o + base + (size_t)qi * CDIM;
        #pragma unroll
        for (int jd = 0; jd < 4; ++jd)
            orow[jd * 16 + lrow] = oacc[jd][rr] * invl;
    }
}

// ---------------- gate: logits + top-2 + softmax -> sel[N], wts[N] ----------------
__global__ __launch_bounds__(256)
void gate_kernel(const float* __restrict__ h2, const float* __restrict__ gw,
                 int2* __restrict__ sel, float2* __restrict__ wts)
{
    __shared__ float gws[ECNT * CDIM];
    int tid = threadIdx.x;
    for (int i = tid; i < ECNT * CDIM; i += 256) gws[i] = gw[i];
    __syncthreads();
    int t = blockIdx.x * 256 + tid;
    const float* hr = h2 + (size_t)t * CDIM;
    float g[ECNT] = {};
    for (int c = 0; c < CDIM; ++c) {
        float hv = hr[c];
        #pragma unroll
        for (int e = 0; e < ECNT; ++e) g[e] = fmaf(hv, gws[e * CDIM + c], g[e]);
    }
    int e0 = 0; float g0 = g[0];
    #pragma unroll
    for (int e = 1; e < ECNT; ++e) if (g[e] > g0) { g0 = g[e]; e0 = e; }
    int e1 = -1; float g1 = -1e30f;
    #pragma unroll
    for (int e = 0; e < ECNT; ++e) if (e != e0 && g[e] > g1) { g1 = g[e]; e1 = e; }
    float z = __expf(g1 - g0);          // <= 1
    float w0 = 1.0f / (1.0f + z);
    sel[t] = make_int2(e0, e1);
    wts[t] = make_float2(w0, 1.0f - w0);
}

// ---------------- routing: build expert-grouped permutation (single block) ----------------
__global__ __launch_bounds__(256)
void route_kernel(const int2* __restrict__ sel, int* __restrict__ perm,
                  int* __restrict__ tokpos, int* __restrict__ meta)
{
    __shared__ int cnt[ECNT], off[ECNT], cur[ECNT];
    const int tid = threadIdx.x;
    if (tid < ECNT) cnt[tid] = 0;
    __syncthreads();
    for (int t = tid; t < NTOK; t += 256) {
        atomicAdd(&cnt[sel[t].x], 1);
        atomicAdd(&cnt[sel[t].y], 1);
    }
    __syncthreads();
    if (tid == 0) {
        int run = 0;
        for (int e = 0; e < ECNT; ++e) {
            off[e] = run; cur[e] = 0;
            int pc = (cnt[e] + BM - 1) / BM * BM;
            meta[2 * e] = run; meta[2 * e + 1] = pc;
            run += pc;
        }
    }
    __syncthreads();
    for (int p = tid; p < TOTCAP; p += 256) perm[p] = 0;   // pad slots -> token 0
    __syncthreads();
    for (int t = tid; t < NTOK; t += 256) {
        int2 s = sel[t];
        int p0 = atomicAdd(&cur[s.x], 1); perm[off[s.x] + p0] = t; tokpos[2 * t]     = off[s.x] + p0;
        int p1 = atomicAdd(&cur[s.y], 1); perm[off[s.y] + p1] = t; tokpos[2 * t + 1] = off[s.y] + p1;
    }
}

// ---------------- gather h2 rows into expert order ----------------
__global__ __launch_bounds__(256)
void gather_kernel(const float* __restrict__ h2, const int* __restrict__ perm,
                   float* __restrict__ xg)
{
    int i = blockIdx.x * 256 + threadIdx.x;   // TOTCAP*CDIM
    int c = i % CDIM, p = i / CDIM;
    xg[i] = h2[(size_t)perm[p] * CDIM + c];
}

// ---------------- combine: x += w0*y[pos0] + w1*y[pos1] ----------------
__global__ __launch_bounds__(256)
void combine_kernel(const float* __restrict__ y, const int* __restrict__ tokpos,
                    const float2* __restrict__ wts, float* __restrict__ x)
{
    int i = blockIdx.x * 256 + threadIdx.x;   // NTOK*CDIM
    int c = i % CDIM, t = i / CDIM;
    float2 wv = wts[t];
    x[i] += wv.x * y[(size_t)tokpos[2 * t] * CDIM + c]
          + wv.y * y[(size_t)tokpos[2 * t + 1] * CDIM + c];
}

// ---------------- per-row cross-entropy ----------------
__global__ __launch_bounds__(256)
void loss_row_kernel(const float* __restrict__ logits, const int* __restrict__ tgt,
                     float* __restrict__ lrow)
{
    int row = blockIdx.x;
    const float* lr = logits + (size_t)row * VOC;
    int tid = threadIdx.x, w = tid >> 6, lane = tid & 63;
    __shared__ float red[4];
    float mx = -1e30f;
    for (int i = tid; i < VOC; i += 256) mx = fmaxf(mx, lr[i]);
    mx = wave_max(mx);
    if (lane == 0) red[w] = mx;
    __syncthreads();
    mx = fmaxf(fmaxf(red[0], red[1]), fmaxf(red[2], red[3]));
    __syncthreads();
    float se = 0.0f;
    for (int i = tid; i < VOC; i += 256) se += expf(lr[i] - mx);
    se = wave_sum(se);
    if (lane == 0) red[w] = se;
    __syncthreads();
    if (tid == 0) {
        float lse = mx + logf(red[0] + red[1] + red[2] + red[3]);
        lrow[row] = lse - lr[tgt[row]];
    }
}

__global__ __launch_bounds__(256)
void loss_reduce_kernel(const float* __restrict__ lrow, float* __restrict__ out)
{
    int tid = threadIdx.x, w = tid >> 6, lane = tid & 63;
    float s = 0.0f;
    for (int i = tid; i < NTOK; i += 256) s += lrow[i];
    s = wave_sum(s);
    __shared__ float red[4];
    if (lane == 0) red[w] = s;
    __syncthreads();
    if (tid == 0) out[0] = (red[0] + red[1] + red[2] + red[3]) * (1.0f / NTOK);
}

// ---------------- launch ----------------
extern "C" void kernel_launch(void* const* d_in, const int* in_sizes, int n_in,
                              void* d_out, int out_size, void* d_ws, size_t ws_size,
                              hipStream_t stream)
{
    const int*   idx     = (const int*)d_in[0];
    const int*   targets = (const int*)d_in[1];
    const float* tok_emb = (const float*)d_in[2];
    const float* pos_emb = (const float*)d_in[3];
    const float* ln1_s   = (const float*)d_in[4];
    const float* ln1_b   = (const float*)d_in[5];
    const float* wq      = (const float*)d_in[6];
    const float* wk      = (const float*)d_in[7];
    const float* wv      = (const float*)d_in[8];
    const float* wo      = (const float*)d_in[9];
    const float* bo      = (const float*)d_in[10];
    const float* ln2_s   = (const float*)d_in[11];
    const float* ln2_b   = (const float*)d_in[12];
    const float* gate_w  = (const float*)d_in[13];
    const float* w1      = (const float*)d_in[14];
    const float* b1      = (const float*)d_in[15];
    const float* w2      = (const float*)d_in[16];
    const float* b2      = (const float*)d_in[17];
    const float* lm_w    = (const float*)d_in[18];
    const float* lm_b    = (const float*)d_in[19];
    float* out = (float*)d_out;

    float* ws   = (float*)d_ws;
    float* wp   = ws;                                // 3*L*C*C  ([w3][l][n][k] B^T)
    float* x    = wp   + (size_t)3 * LCNT * CDIM * CDIM;
    float* hbuf = x    + (size_t)NTOK * CDIM;        // LN1 out, attn out
    float* qbuf = hbuf + (size_t)NTOK * CDIM;        // q / h2 ; y overlays qbuf..vbuf during MoE tail
    float* kbuf = qbuf + (size_t)NTOK * CDIM;
    float* vbuf = kbuf + (size_t)NTOK * CDIM;
    float* xg   = vbuf + (size_t)NTOK * CDIM;        // TOTCAP*C gathered h2
    float* hid  = xg   + (size_t)TOTCAP * CDIM;      // TOTCAP*FF
    float* lrow = hid  + (size_t)TOTCAP * FF;        // NTOK
    float2* wts = (float2*)(lrow + NTOK);            // NTOK float2
    int2*  sel  = (int2*)(wts + NTOK);               // NTOK int2
    int*   perm = (int*)(sel + NTOK);                // TOTCAP
    int*  tokpos= perm + TOTCAP;                     // 2*NTOK
    int*   meta = tokpos + 2 * NTOK;                 // 16
    float* ybuf = qbuf;                              // TOTCAP*C (fits in qbuf+kbuf+vbuf)

    dim3 blk(256);

    repack_kernel<<<(3 * LCNT * CDIM * CDIM) / 256, blk, 0, stream>>>(wq, wk, wv, wp);
    embed_kernel<<<(NTOK * CDIM) / 256, blk, 0, stream>>>(idx, tok_emb, pos_emb, x);

    for (int l = 0; l < LCNT; ++l) {
        ln_kernel<<<NTOK, blk, 0, stream>>>(x, ln1_s + (size_t)l * CDIM, ln1_b + (size_t)l * CDIM, hbuf);

        const size_t mw = (size_t)CDIM * CDIM;
        gemm_bf16_kernel<0, true><<<dim3(CDIM / BN, NTOK / BM), blk, 0, stream>>>(
            CDIM, hbuf, CDIM, wp + (0 * LCNT + l) * mw, CDIM, nullptr, qbuf, CDIM, nullptr, 0, 0);
        gemm_bf16_kernel<0, true><<<dim3(CDIM / BN, NTOK / BM), blk, 0, stream>>>(
            CDIM, hbuf, CDIM, wp + (1 * LCNT + l) * mw, CDIM, nullptr, kbuf, CDIM, nullptr, 0, 0);
        gemm_bf16_kernel<0, true><<<dim3(CDIM / BN, NTOK / BM), blk, 0, stream>>>(
            CDIM, hbuf, CDIM, wp + (2 * LCNT + l) * mw, CDIM, nullptr, vbuf, CDIM, nullptr, 0, 0);

        attn_mfma_kernel<<<dim3(TT / QBLK, BB * HCNT), blk, 0, stream>>>(qbuf, kbuf, vbuf, hbuf);

        gemm_bf16_kernel<1, true><<<dim3(CDIM / BN, NTOK / BM), blk, 0, stream>>>(
            CDIM, hbuf, CDIM, wo + (size_t)l * CDIM * CDIM, CDIM,
            bo + (size_t)l * CDIM, x, CDIM, nullptr, 0, 0);

        // --- MoE: gate -> route -> gather -> expert GEMMs -> combine ---
        float* h2 = qbuf;
        ln_kernel<<<NTOK, blk, 0, stream>>>(x, ln2_s + (size_t)l * CDIM, ln2_b + (size_t)l * CDIM, h2);
        gate_kernel<<<NTOK / 256, blk, 0, stream>>>(h2, gate_w + (size_t)l * ECNT * CDIM, sel, wts);
        route_kernel<<<1, blk, 0, stream>>>(sel, perm, tokpos, meta);
        gather_kernel<<<(TOTCAP * CDIM) / 256, blk, 0, stream>>>(h2, perm, xg);

        const float* w1l = w1 + (size_t)l * ECNT * FF * CDIM;
        const float* b1l = b1 + (size_t)l * ECNT * FF;
        const float* w2l = w2 + (size_t)l * ECNT * CDIM * FF;
        const float* b2l = b2 + (size_t)l * ECNT * CDIM;
        if (l == 0) {   // feeds next layer's router -> keep fp32-grade
            gemm_bf16_kernel<2, true><<<dim3(FF / BN, NTOK / BM, ECNT), blk, 0, stream>>>(
                CDIM, xg, CDIM, w1l, CDIM, b1l, hid, FF, meta, (size_t)FF * CDIM, FF);
            gemm_bf16_kernel<0, true><<<dim3(CDIM / BN, NTOK / BM, ECNT), blk, 0, stream>>>(
                FF, hid, FF, w2l, FF, b2l, ybuf, CDIM, meta, (size_t)CDIM * FF, CDIM);
        } else {        // feeds only logits -> fast single-bf16
            gemm_bf16_kernel<2, false><<<dim3(FF / BN, NTOK / BM, ECNT), blk, 0, stream>>>(
                CDIM, xg, CDIM, w1l, CDIM, b1l, hid, FF, meta, (size_t)FF * CDIM, FF);
            gemm_bf16_kernel<0, false><<<dim3(CDIM / BN, NTOK / BM, ECNT), blk, 0, stream>>>(
                FF, hid, FF, w2l, FF, b2l, ybuf, CDIM, meta, (size_t)CDIM * FF, CDIM);
        }
        combine_kernel<<<(NTOK * CDIM) / 256, blk, 0, stream>>>(ybuf, tokpos, wts, x);
    }

    gemm_bf16_kernel<0, false><<<dim3(VOC / BN, NTOK / BM), blk, 0, stream>>>(
        CDIM, x, CDIM, lm_w, CDIM, lm_b, out, VOC, nullptr, 0, 0);

    loss_row_kernel<<<NTOK, blk, 0, stream>>>(out, targets, lrow);
    loss_reduce_kernel<<<1, blk, 0, stream>>>(lrow, out + (size_t)NTOK * VOC);
}

// Round 7
// 1508.224 us; speedup vs baseline: 8.4811x; 1.1117x over previous
//
#include <hip/hip_runtime.h>
#include <hip/hip_bf16.h>

// Problem constants (from reference)
#define LCNT 2
#define HCNT 12
#define CDIM 768
#define HSD  64
#define ECNT 8
#define VOC  32000
#define BB   2
#define TT   1024
#define NTOK 2048   // B*T
#define FF   3072   // 4*C
#define QKVLD 2304  // 3*C
#define TOTCAP 5120 // 2*NTOK + 8*128 padding capacity

typedef __attribute__((ext_vector_type(8))) short bf16x8;
typedef __attribute__((ext_vector_type(4))) float f32x4;

// ---------------- helpers ----------------
__device__ __forceinline__ float wave_sum(float v) {
    #pragma unroll
    for (int off = 32; off; off >>= 1) v += __shfl_xor(v, off);
    return v;
}
__device__ __forceinline__ float wave_max(float v) {
    #pragma unroll
    for (int off = 32; off; off >>= 1) v = fmaxf(v, __shfl_xor(v, off));
    return v;
}
__device__ __forceinline__ unsigned short f2bf(float f) {
    unsigned int u = __float_as_uint(f);
    unsigned int r = (u + 0x7FFFu + ((u >> 16) & 1u)) >> 16;
    return (unsigned short)r;
}
__device__ __forceinline__ float bf2f(unsigned short h) {
    return __uint_as_float((unsigned int)h << 16);
}
__device__ __forceinline__ void split2(float a, unsigned short& h, unsigned short& l) {
    h = f2bf(a);
    l = f2bf(a - bf2f(h));
}
__device__ __forceinline__ ushort4 cvt4(float4 v) {
    ushort4 r;
    r.x = f2bf(v.x); r.y = f2bf(v.y); r.z = f2bf(v.z); r.w = f2bf(v.w);
    return r;
}

// ---------------- embedding ----------------
__global__ __launch_bounds__(256)
void embed_kernel(const int* __restrict__ idx, const float* __restrict__ tok,
                  const float* __restrict__ pos, float* __restrict__ x)
{
    int i = blockIdx.x * 256 + threadIdx.x;      // N*C total
    int c = i % CDIM;
    int n = i / CDIM;
    int t = n % TT;
    x[i] = tok[(size_t)idx[n] * CDIM + c] + pos[(size_t)t * CDIM + c];
}

// ---------------- repack wq/wk/wv [L,H,C,HS] -> wp[l][w3*C + n][k]  (fused B^T layout) ----------------
__global__ __launch_bounds__(256)
void repack_kernel(const float* __restrict__ wq, const float* __restrict__ wk,
                   const float* __restrict__ wv, float* __restrict__ wp)
{
    int i = blockIdx.x * 256 + threadIdx.x;      // 3*L*C*C
    int kk = i % CDIM;
    int n  = (i / CDIM) % CDIM;
    int w3 = (i / (CDIM * CDIM)) % 3;
    int l  = i / (CDIM * CDIM * 3);
    const float* src = (w3 == 0) ? wq : (w3 == 1) ? wk : wv;
    int h = n / HSD, d = n % HSD;
    wp[(((size_t)l * 3 + w3) * CDIM + n) * CDIM + kk] =
        src[((((size_t)l * HCNT + h) * CDIM) + kk) * HSD + d];
}

// ---------------- layernorm ----------------
__global__ __launch_bounds__(256)
void ln_kernel(const float* __restrict__ x, const float* __restrict__ sc,
               const float* __restrict__ bs, float* __restrict__ out)
{
    int row = blockIdx.x;
    const float* xr = x + (size_t)row * CDIM;
    float* orow = out + (size_t)row * CDIM;
    int tid = threadIdx.x;
    float v0 = xr[tid], v1 = xr[tid + 256], v2 = xr[tid + 512];
    float s1 = v0 + v1 + v2;
    float s2 = v0 * v0 + v1 * v1 + v2 * v2;
    s1 = wave_sum(s1);
    s2 = wave_sum(s2);
    __shared__ float r1[4], r2[4];
    int w = tid >> 6, lane = tid & 63;
    if (lane == 0) { r1[w] = s1; r2[w] = s2; }
    __syncthreads();
    float t1 = r1[0] + r1[1] + r1[2] + r1[3];
    float t2 = r2[0] + r2[1] + r2[2] + r2[3];
    float mu = t1 * (1.0f / CDIM);
    float var = t2 * (1.0f / CDIM) - mu * mu;
    float rstd = rsqrtf(var + 1e-5f);
    orow[tid]       = (v0 - mu) * rstd * sc[tid]       + bs[tid];
    orow[tid + 256] = (v1 - mu) * rstd * sc[tid + 256] + bs[tid + 256];
    orow[tid + 512] = (v2 - mu) * rstd * sc[tid + 512] + bs[tid + 512];
}

// ---------------- bf16 MFMA GEMM (SPLIT: fp32-grade via hi/lo 3-MFMA; FAST: 1 MFMA) ----------------
// C[m,n] = sum_k A[m,k] * B[n,k]   (B row-major [N][K], i.e. B^T)
// MODE 0: out = acc + bias ; MODE 1: out += acc + bias ; MODE 2: out = relu(acc + bias)
// rowmeta != null: expert mode; blockIdx.z = expert; rowmeta[2e]=row offset, rowmeta[2e+1]=padded count
// SWZ: XCD-aware block remap, m-fastest within XCD (requires nwg%8==0, rowmeta==null)
#define BM 128
#define BN 128
#define BK 32
#define PADK 40   // bf16 stride per row (80 B)

template<int MODE, bool SPLIT, bool SWZ = false>
__global__ __launch_bounds__(256)
void gemm_bf16_kernel(int Kd,
                      const float* __restrict__ A, int lda,
                      const float* __restrict__ B, int ldb,
                      const float* __restrict__ bias,
                      float* __restrict__ out, int ldo,
                      const int* __restrict__ rowmeta,
                      size_t bstride, int biasstride)
{
    __shared__ short Ah[BM * PADK];
    __shared__ short Bh[BN * PADK];
    __shared__ short Al[SPLIT ? BM * PADK : 2];
    __shared__ short Bl[SPLIT ? BN * PADK : 2];

    int bx = blockIdx.x, by = blockIdx.y;
    if constexpr (SWZ) {
        const int nwg = gridDim.x * gridDim.y;
        const int chunk = nwg >> 3;                    // nwg % 8 == 0
        const int flat = by * gridDim.x + bx;
        const int newid = (flat & 7) * chunk + (flat >> 3);
        by = newid % gridDim.y;                        // m-tile fastest within XCD
        bx = newid / gridDim.y;
    }

    int roff = 0;
    if (rowmeta) {
        const int ee = blockIdx.z;
        const int rcnt = rowmeta[2 * ee + 1];
        if ((int)(by * BM) >= rcnt) return;
        roff = rowmeta[2 * ee];
        B += (size_t)ee * bstride;
        if (bias) bias += (size_t)ee * biasstride;
    }

    const int tid = threadIdx.x;
    const int m0 = roff + by * BM;
    const int n0 = bx * BN;
    const int w = tid >> 6, lane = tid & 63;
    const int wr = w >> 1, wc = w & 1;          // wave tile (64x64)
    const int lrow = lane & 15, lkg = lane >> 4;
    const int srow = tid >> 3, skg = (tid & 7) * 4;

    const float* Ablk = A + (size_t)m0 * lda;
    const float* Bblk = B + (size_t)n0 * ldb;

    float4 pa[4], pb[4];
    #pragma unroll
    for (int p = 0; p < 4; ++p) {
        pa[p] = *(const float4*)(Ablk + (size_t)(p * 32 + srow) * lda + skg);
        pb[p] = *(const float4*)(Bblk + (size_t)(p * 32 + srow) * ldb + skg);
    }

    f32x4 acc[4][4] = {};
    const int nk = Kd / BK;

    for (int t = 0; t < nk; ++t) {
        __syncthreads();   // previous compute done; LDS free
        #pragma unroll
        for (int p = 0; p < 4; ++p) {
            if constexpr (SPLIT) {
                ushort4 h, l;
                split2(pa[p].x, h.x, l.x); split2(pa[p].y, h.y, l.y);
                split2(pa[p].z, h.z, l.z); split2(pa[p].w, h.w, l.w);
                *(ushort4*)(&Ah[(p * 32 + srow) * PADK + skg]) = h;
                *(ushort4*)(&Al[(p * 32 + srow) * PADK + skg]) = l;
                split2(pb[p].x, h.x, l.x); split2(pb[p].y, h.y, l.y);
                split2(pb[p].z, h.z, l.z); split2(pb[p].w, h.w, l.w);
                *(ushort4*)(&Bh[(p * 32 + srow) * PADK + skg]) = h;
                *(ushort4*)(&Bl[(p * 32 + srow) * PADK + skg]) = l;
            } else {
                *(ushort4*)(&Ah[(p * 32 + srow) * PADK + skg]) = cvt4(pa[p]);
                *(ushort4*)(&Bh[(p * 32 + srow) * PADK + skg]) = cvt4(pb[p]);
            }
        }
        __syncthreads();   // writes visible
        if (t + 1 < nk) {
            const int kb = (t + 1) * BK + skg;
            #pragma unroll
            for (int p = 0; p < 4; ++p) {
                pa[p] = *(const float4*)(Ablk + (size_t)(p * 32 + srow) * lda + kb);
                pb[p] = *(const float4*)(Bblk + (size_t)(p * 32 + srow) * ldb + kb);
            }
        }
        bf16x8 afh[4], afl[4];
        #pragma unroll
        for (int i = 0; i < 4; ++i) {
            afh[i] = *(const bf16x8*)(&Ah[(wr * 64 + i * 16 + lrow) * PADK + lkg * 8]);
            if constexpr (SPLIT)
                afl[i] = *(const bf16x8*)(&Al[(wr * 64 + i * 16 + lrow) * PADK + lkg * 8]);
        }
        #pragma unroll
        for (int j = 0; j < 4; ++j) {
            const bf16x8 bh = *(const bf16x8*)(&Bh[(wc * 64 + j * 16 + lrow) * PADK + lkg * 8]);
            if constexpr (SPLIT) {
                const bf16x8 bl = *(const bf16x8*)(&Bl[(wc * 64 + j * 16 + lrow) * PADK + lkg * 8]);
                #pragma unroll
                for (int i = 0; i < 4; ++i) {
                    acc[i][j] = __builtin_amdgcn_mfma_f32_16x16x32_bf16(afh[i], bh, acc[i][j], 0, 0, 0);
                    acc[i][j] = __builtin_amdgcn_mfma_f32_16x16x32_bf16(afl[i], bh, acc[i][j], 0, 0, 0);
                    acc[i][j] = __builtin_amdgcn_mfma_f32_16x16x32_bf16(afh[i], bl, acc[i][j], 0, 0, 0);
                }
            } else {
                #pragma unroll
                for (int i = 0; i < 4; ++i)
                    acc[i][j] = __builtin_amdgcn_mfma_f32_16x16x32_bf16(afh[i], bh, acc[i][j], 0, 0, 0);
            }
        }
    }

    #pragma unroll
    for (int i = 0; i < 4; ++i) {
        #pragma unroll
        for (int r = 0; r < 4; ++r) {
            const int row = m0 + wr * 64 + i * 16 + lkg * 4 + r;
            #pragma unroll
            for (int j = 0; j < 4; ++j) {
                const int col = n0 + wc * 64 + j * 16 + lrow;
                const float bj = bias ? bias[col] : 0.0f;
                const float vres = acc[i][j][r] + bj;
                float* op = out + (size_t)row * ldo + col;
                if (MODE == 0) *op = vres;
                else if (MODE == 1) *op = *op + vres;
                else *op = fmaxf(vres, 0.0f);
            }
        }
    }
}

// ---------------- MFMA flash attention, split-precision (fp32-grade) ----------------
// Block: (b,h) x 64 q-rows; 4 waves x 16 q-rows. KV tiles of 64.
// qkv: [B,T,3C] (row stride QKVLD); q at +0, k at +C, v at +2C. o: [B,T,C] compact.
#define QBLK 64
#define KVBLK 64

__global__ __launch_bounds__(256)
void attn_mfma_kernel(const float* __restrict__ qkv, float* __restrict__ o)
{
    __shared__ short Kh[2][KVBLK][PADK];   // [d-step][key][32d]
    __shared__ short Kl[2][KVBLK][PADK];
    __shared__ short Vh[2][HSD][PADK];     // transposed: [key-step][d][32keys]
    __shared__ short Vl[2][HSD][PADK];
    __shared__ short Ph[4][2][16][PADK];   // [wave][key-step][qrow][32keys]
    __shared__ short Pl[4][2][16][PADK];

    const int t0 = blockIdx.x * QBLK;
    const int bh = blockIdx.y;
    const int b = bh / HCNT, hh = bh % HCNT;
    const size_t baseq = (size_t)b * TT * QKVLD + (size_t)hh * HSD;
    const size_t obase = (size_t)b * TT * CDIM + (size_t)hh * HSD;
    const float* q = qkv + baseq;
    const float* k = qkv + baseq + CDIM;
    const float* v = qkv + baseq + 2 * CDIM;
    const int tid = threadIdx.x;
    const int w = tid >> 6, lane = tid & 63;
    const int lrow = lane & 15, lkg = lane >> 4;
    const float sscale = rsqrtf((float)CDIM);   // C^-0.5 (as in reference)

    // Q -> registers as split A-frags (row = lane&15 within wave tile, kg = (lane>>4)*8)
    bf16x8 qh[2], ql[2];
    {
        const float* qr = q + (size_t)(t0 + w * 16 + lrow) * QKVLD;
        #pragma unroll
        for (int ks = 0; ks < 2; ++ks) {
            #pragma unroll
            for (int j = 0; j < 8; ++j) {
                unsigned short h, l;
                split2(qr[ks * 32 + lkg * 8 + j], h, l);
                qh[ks][j] = (short)h;
                ql[ks][j] = (short)l;
            }
        }
    }

    f32x4 oacc[4] = {};
    float m_[4], l_[4];
    #pragma unroll
    for (int rr = 0; rr < 4; ++rr) { m_[rr] = -1e30f; l_[rr] = 0.0f; }

    for (int s0 = 0; s0 <= t0 + QBLK - 1; s0 += KVBLK) {
        __syncthreads();   // previous tile fully consumed
        {   // stage K (row-major, like GEMM B^T operand)
            const int srow = tid >> 3, skg = (tid & 7) * 4;
            #pragma unroll
            for (int p = 0; p < 2; ++p) {
                const float* krow = k + (size_t)(s0 + p * 32 + srow) * QKVLD;
                #pragma unroll
                for (int ks = 0; ks < 2; ++ks) {
                    float4 a = *(const float4*)(krow + ks * 32 + skg);
                    ushort4 h, l;
                    split2(a.x, h.x, l.x); split2(a.y, h.y, l.y);
                    split2(a.z, h.z, l.z); split2(a.w, h.w, l.w);
                    *(ushort4*)(&Kh[ks][p * 32 + srow][skg]) = h;
                    *(ushort4*)(&Kl[ks][p * 32 + srow][skg]) = l;
                }
            }
            // stage V transposed: Vt[d][key]
            const int key = tid & 63, dg = (tid >> 6) * 16;
            const float* vrow = v + (size_t)(s0 + key) * QKVLD + dg;
            const int kst = key >> 5, ko = key & 31;
            #pragma unroll
            for (int dd = 0; dd < 16; dd += 4) {
                float4 a = *(const float4*)(vrow + dd);
                unsigned short h, l;
                split2(a.x, h, l); Vh[kst][dg + dd + 0][ko] = h; Vl[kst][dg + dd + 0][ko] = l;
                split2(a.y, h, l); Vh[kst][dg + dd + 1][ko] = h; Vl[kst][dg + dd + 1][ko] = l;
                split2(a.z, h, l); Vh[kst][dg + dd + 2][ko] = h; Vl[kst][dg + dd + 2][ko] = l;
                split2(a.w, h, l); Vh[kst][dg + dd + 3][ko] = h; Vl[kst][dg + dd + 3][ko] = l;
            }
        }
        __syncthreads();

        // S = Q*K^T  (D rows = q, cols = key)
        f32x4 sacc[4] = {};
        #pragma unroll
        for (int j = 0; j < 4; ++j) {
            #pragma unroll
            for (int ks = 0; ks < 2; ++ks) {
                const bf16x8 bh = *(const bf16x8*)(&Kh[ks][j * 16 + lrow][lkg * 8]);
                const bf16x8 bl = *(const bf16x8*)(&Kl[ks][j * 16 + lrow][lkg * 8]);
                sacc[j] = __builtin_amdgcn_mfma_f32_16x16x32_bf16(qh[ks], bh, sacc[j], 0, 0, 0);
                sacc[j] = __builtin_amdgcn_mfma_f32_16x16x32_bf16(ql[ks], bh, sacc[j], 0, 0, 0);
                sacc[j] = __builtin_amdgcn_mfma_f32_16x16x32_bf16(qh[ks], bl, sacc[j], 0, 0, 0);
            }
        }

        // online softmax (lane owns 4 rows x 4 cols); row-reduce over 16-lane group
        #pragma unroll
        for (int rr = 0; rr < 4; ++rr) {
            const int qi = t0 + w * 16 + lkg * 4 + rr;
            float pv[4];
            float mx = -1e30f;
            #pragma unroll
            for (int j = 0; j < 4; ++j) {
                float s = sacc[j][rr] * sscale;
                if (s0 + j * 16 + lrow > qi) s = -1e30f;
                pv[j] = s;
                mx = fmaxf(mx, s);
            }
            #pragma unroll
            for (int off = 1; off < 16; off <<= 1) mx = fmaxf(mx, __shfl_xor(mx, off));
            const float mnew = fmaxf(m_[rr], mx);
            const float corr = __expf(m_[rr] - mnew);
            float ps = 0.0f;
            #pragma unroll
            for (int j = 0; j < 4; ++j) { pv[j] = __expf(pv[j] - mnew); ps += pv[j]; }
            #pragma unroll
            for (int off = 1; off < 16; off <<= 1) ps += __shfl_xor(ps, off);
            l_[rr] = l_[rr] * corr + ps;
            m_[rr] = mnew;
            #pragma unroll
            for (int jd = 0; jd < 4; ++jd) oacc[jd][rr] *= corr;
            #pragma unroll
            for (int j = 0; j < 4; ++j) {   // write split P (per-wave-private region)
                unsigned short h, l;
                split2(pv[j], h, l);
                const int key = j * 16 + lrow;
                Ph[w][key >> 5][lkg * 4 + rr][key & 31] = h;
                Pl[w][key >> 5][lkg * 4 + rr][key & 31] = l;
            }
        }

        // O += P * V   (A = P from own wave's LDS region, B = Vt)
        #pragma unroll
        for (int ks = 0; ks < 2; ++ks) {
            const bf16x8 ah = *(const bf16x8*)(&Ph[w][ks][lrow][lkg * 8]);
            const bf16x8 al = *(const bf16x8*)(&Pl[w][ks][lrow][lkg * 8]);
            #pragma unroll
            for (int jd = 0; jd < 4; ++jd) {
                const bf16x8 bh = *(const bf16x8*)(&Vh[ks][jd * 16 + lrow][lkg * 8]);
                const bf16x8 bl = *(const bf16x8*)(&Vl[ks][jd * 16 + lrow][lkg * 8]);
                oacc[jd] = __builtin_amdgcn_mfma_f32_16x16x32_bf16(ah, bh, oacc[jd], 0, 0, 0);
                oacc[jd] = __builtin_amdgcn_mfma_f32_16x16x32_bf16(al, bh, oacc[jd], 0, 0, 0);
                oacc[jd] = __builtin_amdgcn_mfma_f32_16x16x32_bf16(ah, bl, oacc[jd], 0, 0, 0);
            }
        }
    }

    #pragma unroll
    for (int rr = 0; rr < 4; ++rr) {
        const int qi = t0 + w * 16 + lkg * 4 + rr;
        const float invl = 1.0f / l_[rr];
        float* orow = o + obase + (size_t)qi * CDIM;
        #pragma unroll
        for (int jd = 0; jd < 4; ++jd)
            orow[jd * 16 + lrow] = oacc[jd][rr] * invl;
    }
}

// ---------------- gate: logits + top-2 + softmax -> sel[N], wts[N] ----------------
__global__ __launch_bounds__(256)
void gate_kernel(const float* __restrict__ h2, const float* __restrict__ gw,
                 int2* __restrict__ sel, float2* __restrict__ wts)
{
    __shared__ float gws[ECNT * CDIM];
    int tid = threadIdx.x;
    for (int i = tid; i < ECNT * CDIM; i += 256) gws[i] = gw[i];
    __syncthreads();
    int t = blockIdx.x * 256 + tid;
    const float* hr = h2 + (size_t)t * CDIM;
    float g[ECNT] = {};
    for (int c = 0; c < CDIM; ++c) {
        float hv = hr[c];
        #pragma unroll
        for (int e = 0; e < ECNT; ++e) g[e] = fmaf(hv, gws[e * CDIM + c], g[e]);
    }
    int e0 = 0; float g0 = g[0];
    #pragma unroll
    for (int e = 1; e < ECNT; ++e) if (g[e] > g0) { g0 = g[e]; e0 = e; }
    int e1 = -1; float g1 = -1e30f;
    #pragma unroll
    for (int e = 0; e < ECNT; ++e) if (e != e0 && g[e] > g1) { g1 = g[e]; e1 = e; }
    float z = __expf(g1 - g0);          // <= 1
    float w0 = 1.0f / (1.0f + z);
    sel[t] = make_int2(e0, e1);
    wts[t] = make_float2(w0, 1.0f - w0);
}

// ---------------- routing: build expert-grouped permutation (single block) ----------------
__global__ __launch_bounds__(256)
void route_kernel(const int2* __restrict__ sel, int* __restrict__ perm,
                  int* __restrict__ tokpos, int* __restrict__ meta)
{
    __shared__ int cnt[ECNT], off[ECNT], cur[ECNT];
    const int tid = threadIdx.x;
    if (tid < ECNT) cnt[tid] = 0;
    __syncthreads();
    for (int t = tid; t < NTOK; t += 256) {
        atomicAdd(&cnt[sel[t].x], 1);
        atomicAdd(&cnt[sel[t].y], 1);
    }
    __syncthreads();
    if (tid == 0) {
        int run = 0;
        for (int e = 0; e < ECNT; ++e) {
            off[e] = run; cur[e] = 0;
            int pc = (cnt[e] + BM - 1) / BM * BM;
            meta[2 * e] = run; meta[2 * e + 1] = pc;
            run += pc;
        }
    }
    __syncthreads();
    for (int p = tid; p < TOTCAP; p += 256) perm[p] = 0;   // pad slots -> token 0
    __syncthreads();
    for (int t = tid; t < NTOK; t += 256) {
        int2 s = sel[t];
        int p0 = atomicAdd(&cur[s.x], 1); perm[off[s.x] + p0] = t; tokpos[2 * t]     = off[s.x] + p0;
        int p1 = atomicAdd(&cur[s.y], 1); perm[off[s.y] + p1] = t; tokpos[2 * t + 1] = off[s.y] + p1;
    }
}

// ---------------- gather h2 rows into expert order ----------------
__global__ __launch_bounds__(256)
void gather_kernel(const float* __restrict__ h2, const int* __restrict__ perm,
                   float* __restrict__ xg)
{
    int i = blockIdx.x * 256 + threadIdx.x;   // TOTCAP*CDIM
    int c = i % CDIM, p = i / CDIM;
    xg[i] = h2[(size_t)perm[p] * CDIM + c];
}

// ---------------- combine: x += w0*y[pos0] + w1*y[pos1] ----------------
__global__ __launch_bounds__(256)
void combine_kernel(const float* __restrict__ y, const int* __restrict__ tokpos,
                    const float2* __restrict__ wts, float* __restrict__ x)
{
    int i = blockIdx.x * 256 + threadIdx.x;   // NTOK*CDIM
    int c = i % CDIM, t = i / CDIM;
    float2 wv = wts[t];
    x[i] += wv.x * y[(size_t)tokpos[2 * t] * CDIM + c]
          + wv.y * y[(size_t)tokpos[2 * t + 1] * CDIM + c];
}

// ---------------- per-row cross-entropy ----------------
__global__ __launch_bounds__(256)
void loss_row_kernel(const float* __restrict__ logits, const int* __restrict__ tgt,
                     float* __restrict__ lrow)
{
    int row = blockIdx.x;
    const float* lr = logits + (size_t)row * VOC;
    int tid = threadIdx.x, w = tid >> 6, lane = tid & 63;
    __shared__ float red[4];
    float mx = -1e30f;
    for (int i = tid; i < VOC; i += 256) mx = fmaxf(mx, lr[i]);
    mx = wave_max(mx);
    if (lane == 0) red[w] = mx;
    __syncthreads();
    mx = fmaxf(fmaxf(red[0], red[1]), fmaxf(red[2], red[3]));
    __syncthreads();
    float se = 0.0f;
    for (int i = tid; i < VOC; i += 256) se += expf(lr[i] - mx);
    se = wave_sum(se);
    if (lane == 0) red[w] = se;
    __syncthreads();
    if (tid == 0) {
        float lse = mx + logf(red[0] + red[1] + red[2] + red[3]);
        lrow[row] = lse - lr[tgt[row]];
    }
}

__global__ __launch_bounds__(256)
void loss_reduce_kernel(const float* __restrict__ lrow, float* __restrict__ out)
{
    int tid = threadIdx.x, w = tid >> 6, lane = tid & 63;
    float s = 0.0f;
    for (int i = tid; i < NTOK; i += 256) s += lrow[i];
    s = wave_sum(s);
    __shared__ float red[4];
    if (lane == 0) red[w] = s;
    __syncthreads();
    if (tid == 0) out[0] = (red[0] + red[1] + red[2] + red[3]) * (1.0f / NTOK);
}

// ---------------- launch ----------------
extern "C" void kernel_launch(void* const* d_in, const int* in_sizes, int n_in,
                              void* d_out, int out_size, void* d_ws, size_t ws_size,
                              hipStream_t stream)
{
    const int*   idx     = (const int*)d_in[0];
    const int*   targets = (const int*)d_in[1];
    const float* tok_emb = (const float*)d_in[2];
    const float* pos_emb = (const float*)d_in[3];
    const float* ln1_s   = (const float*)d_in[4];
    const float* ln1_b   = (const float*)d_in[5];
    const float* wq      = (const float*)d_in[6];
    const float* wk      = (const float*)d_in[7];
    const float* wv      = (const float*)d_in[8];
    const float* wo      = (const float*)d_in[9];
    const float* bo      = (const float*)d_in[10];
    const float* ln2_s   = (const float*)d_in[11];
    const float* ln2_b   = (const float*)d_in[12];
    const float* gate_w  = (const float*)d_in[13];
    const float* w1      = (const float*)d_in[14];
    const float* b1      = (const float*)d_in[15];
    const float* w2      = (const float*)d_in[16];
    const float* b2      = (const float*)d_in[17];
    const float* lm_w    = (const float*)d_in[18];
    const float* lm_b    = (const float*)d_in[19];
    float* out = (float*)d_out;

    float* ws   = (float*)d_ws;
    float* wp   = ws;                                // 3*L*C*C  ([l][3C][C] fused B^T)
    float* x    = wp   + (size_t)3 * LCNT * CDIM * CDIM;
    float* hbuf = x    + (size_t)NTOK * CDIM;        // LN1 out, attn out
    float* qkv  = hbuf + (size_t)NTOK * CDIM;        // [NTOK][2304]; h2/ybuf overlay after attn
    float* xg   = qkv  + (size_t)NTOK * QKVLD;       // TOTCAP*C gathered h2
    float* hid  = xg   + (size_t)TOTCAP * CDIM;      // TOTCAP*FF
    float* lrow = hid  + (size_t)TOTCAP * FF;        // NTOK
    float2* wts = (float2*)(lrow + NTOK);            // NTOK float2
    int2*  sel  = (int2*)(wts + NTOK);               // NTOK int2
    int*   perm = (int*)(sel + NTOK);                // TOTCAP
    int*  tokpos= perm + TOTCAP;                     // 2*NTOK
    int*   meta = tokpos + 2 * NTOK;                 // 16

    dim3 blk(256);

    repack_kernel<<<(3 * LCNT * CDIM * CDIM) / 256, blk, 0, stream>>>(wq, wk, wv, wp);
    embed_kernel<<<(NTOK * CDIM) / 256, blk, 0, stream>>>(idx, tok_emb, pos_emb, x);

    for (int l = 0; l < LCNT; ++l) {
        ln_kernel<<<NTOK, blk, 0, stream>>>(x, ln1_s + (size_t)l * CDIM, ln1_b + (size_t)l * CDIM, hbuf);

        // fused QKV projection: [NTOK,768] x [2304,768]^T -> [NTOK,2304]
        gemm_bf16_kernel<0, true><<<dim3(QKVLD / BN, NTOK / BM), blk, 0, stream>>>(
            CDIM, hbuf, CDIM, wp + (size_t)l * 3 * CDIM * CDIM, CDIM,
            nullptr, qkv, QKVLD, nullptr, 0, 0);

        attn_mfma_kernel<<<dim3(TT / QBLK, BB * HCNT), blk, 0, stream>>>(qkv, hbuf);

        gemm_bf16_kernel<1, true><<<dim3(CDIM / BN, NTOK / BM), blk, 0, stream>>>(
            CDIM, hbuf, CDIM, wo + (size_t)l * CDIM * CDIM, CDIM,
            bo + (size_t)l * CDIM, x, CDIM, nullptr, 0, 0);

        // --- MoE: gate -> route -> gather -> expert GEMMs -> combine ---
        float* h2 = qkv;       // attn consumed qkv; reuse as compact [NTOK][C]
        float* ybuf = qkv;     // w2 output overlays h2 after gather
        ln_kernel<<<NTOK, blk, 0, stream>>>(x, ln2_s + (size_t)l * CDIM, ln2_b + (size_t)l * CDIM, h2);
        gate_kernel<<<NTOK / 256, blk, 0, stream>>>(h2, gate_w + (size_t)l * ECNT * CDIM, sel, wts);
        route_kernel<<<1, blk, 0, stream>>>(sel, perm, tokpos, meta);
        gather_kernel<<<(TOTCAP * CDIM) / 256, blk, 0, stream>>>(h2, perm, xg);

        const float* w1l = w1 + (size_t)l * ECNT * FF * CDIM;
        const float* b1l = b1 + (size_t)l * ECNT * FF;
        const float* w2l = w2 + (size_t)l * ECNT * CDIM * FF;
        const float* b2l = b2 + (size_t)l * ECNT * CDIM;
        if (l == 0) {   // feeds next layer's router -> keep fp32-grade
            gemm_bf16_kernel<2, true><<<dim3(FF / BN, NTOK / BM, ECNT), blk, 0, stream>>>(
                CDIM, xg, CDIM, w1l, CDIM, b1l, hid, FF, meta, (size_t)FF * CDIM, FF);
            gemm_bf16_kernel<0, true><<<dim3(CDIM / BN, NTOK / BM, ECNT), blk, 0, stream>>>(
                FF, hid, FF, w2l, FF, b2l, ybuf, CDIM, meta, (size_t)CDIM * FF, CDIM);
        } else {        // feeds only logits -> fast single-bf16
            gemm_bf16_kernel<2, false><<<dim3(FF / BN, NTOK / BM, ECNT), blk, 0, stream>>>(
                CDIM, xg, CDIM, w1l, CDIM, b1l, hid, FF, meta, (size_t)FF * CDIM, FF);
            gemm_bf16_kernel<0, false><<<dim3(CDIM / BN, NTOK / BM, ECNT), blk, 0, stream>>>(
                FF, hid, FF, w2l, FF, b2l, ybuf, CDIM, meta, (size_t)CDIM * FF, CDIM);
        }
        combine_kernel<<<(NTOK * CDIM) / 256, blk, 0, stream>>>(ybuf, tokpos, wts, x);
    }

    // LM head with XCD-aware, M-fastest swizzle (4000 blocks % 8 == 0)
    gemm_bf16_kernel<0, false, true><<<dim3(VOC / BN, NTOK / BM), blk, 0, stream>>>(
        CDIM, x, CDIM, lm_w, CDIM, lm_b, out, VOC, nullptr, 0, 0);

    loss_row_kernel<<<NTOK, blk, 0, stream>>>(out, targets, lrow);
    loss_reduce_kernel<<<1, blk, 0, stream>>>(lrow, out + (size_t)NTOK * VOC);
}

// Round 8
// 1437.358 us; speedup vs baseline: 8.8993x; 1.0493x over previous
//
#include <hip/hip_runtime.h>
#include <hip/hip_bf16.h>

// Problem constants (from reference)
#define LCNT 2
#define HCNT 12
#define CDIM 768
#define HSD  64
#define ECNT 8
#define VOC  32000
#define BB   2
#define TT   1024
#define NTOK 2048   // B*T
#define FF   3072   // 4*C
#define QKVLD 2304  // 3*C
#define TOTCAP 5120 // 2*NTOK + 8*128 padding capacity

typedef __attribute__((ext_vector_type(8))) short bf16x8;
typedef __attribute__((ext_vector_type(4))) float f32x4;

// ---------------- helpers ----------------
__device__ __forceinline__ float wave_sum(float v) {
    #pragma unroll
    for (int off = 32; off; off >>= 1) v += __shfl_xor(v, off);
    return v;
}
__device__ __forceinline__ float wave_max(float v) {
    #pragma unroll
    for (int off = 32; off; off >>= 1) v = fmaxf(v, __shfl_xor(v, off));
    return v;
}
__device__ __forceinline__ unsigned short f2bf(float f) {
    unsigned int u = __float_as_uint(f);
    unsigned int r = (u + 0x7FFFu + ((u >> 16) & 1u)) >> 16;
    return (unsigned short)r;
}
__device__ __forceinline__ float bf2f(unsigned short h) {
    return __uint_as_float((unsigned int)h << 16);
}
__device__ __forceinline__ void split2(float a, unsigned short& h, unsigned short& l) {
    h = f2bf(a);
    l = f2bf(a - bf2f(h));
}
__device__ __forceinline__ ushort4 cvt4(float4 v) {
    ushort4 r;
    r.x = f2bf(v.x); r.y = f2bf(v.y); r.z = f2bf(v.z); r.w = f2bf(v.w);
    return r;
}

// ---------------- fp32 -> bf16 bulk convert (vectorized, grid-stride) ----------------
__global__ __launch_bounds__(256)
void cvt_bf16_kernel(const float* __restrict__ in, unsigned short* __restrict__ out, int n4)
{
    for (int i = blockIdx.x * 256 + threadIdx.x; i < n4; i += gridDim.x * 256) {
        float4 v = reinterpret_cast<const float4*>(in)[i];
        reinterpret_cast<ushort4*>(out)[i] = cvt4(v);
    }
}

// ---------------- embedding ----------------
__global__ __launch_bounds__(256)
void embed_kernel(const int* __restrict__ idx, const float* __restrict__ tok,
                  const float* __restrict__ pos, float* __restrict__ x)
{
    int i = blockIdx.x * 256 + threadIdx.x;      // N*C total
    int c = i % CDIM;
    int n = i / CDIM;
    int t = n % TT;
    x[i] = tok[(size_t)idx[n] * CDIM + c] + pos[(size_t)t * CDIM + c];
}

// ---------------- repack wq/wk/wv [L,H,C,HS] -> wp[l][w3*C + n][k]  (fused B^T layout) ----------------
__global__ __launch_bounds__(256)
void repack_kernel(const float* __restrict__ wq, const float* __restrict__ wk,
                   const float* __restrict__ wv, float* __restrict__ wp)
{
    int i = blockIdx.x * 256 + threadIdx.x;      // 3*L*C*C
    int kk = i % CDIM;
    int n  = (i / CDIM) % CDIM;
    int w3 = (i / (CDIM * CDIM)) % 3;
    int l  = i / (CDIM * CDIM * 3);
    const float* src = (w3 == 0) ? wq : (w3 == 1) ? wk : wv;
    int h = n / HSD, d = n % HSD;
    wp[(((size_t)l * 3 + w3) * CDIM + n) * CDIM + kk] =
        src[((((size_t)l * HCNT + h) * CDIM) + kk) * HSD + d];
}

// ---------------- layernorm ----------------
__global__ __launch_bounds__(256)
void ln_kernel(const float* __restrict__ x, const float* __restrict__ sc,
               const float* __restrict__ bs, float* __restrict__ out)
{
    int row = blockIdx.x;
    const float* xr = x + (size_t)row * CDIM;
    float* orow = out + (size_t)row * CDIM;
    int tid = threadIdx.x;
    float v0 = xr[tid], v1 = xr[tid + 256], v2 = xr[tid + 512];
    float s1 = v0 + v1 + v2;
    float s2 = v0 * v0 + v1 * v1 + v2 * v2;
    s1 = wave_sum(s1);
    s2 = wave_sum(s2);
    __shared__ float r1[4], r2[4];
    int w = tid >> 6, lane = tid & 63;
    if (lane == 0) { r1[w] = s1; r2[w] = s2; }
    __syncthreads();
    float t1 = r1[0] + r1[1] + r1[2] + r1[3];
    float t2 = r2[0] + r2[1] + r2[2] + r2[3];
    float mu = t1 * (1.0f / CDIM);
    float var = t2 * (1.0f / CDIM) - mu * mu;
    float rstd = rsqrtf(var + 1e-5f);
    orow[tid]       = (v0 - mu) * rstd * sc[tid]       + bs[tid];
    orow[tid + 256] = (v1 - mu) * rstd * sc[tid + 256] + bs[tid + 256];
    orow[tid + 512] = (v2 - mu) * rstd * sc[tid + 512] + bs[tid + 512];
}

#define BM 128
#define BN 128
#define BK 32
#define PADK 40   // bf16 stride per row (80 B)

// ---------------- split-precision bf16 MFMA GEMM (fp32-grade, 3 MFMA) ----------------
// C[m,n] = sum_k A[m,k] * B[n,k]   (B row-major [N][K], i.e. B^T)
// MODE 0: out = acc + bias ; MODE 1: out += acc + bias ; MODE 2: out = relu(acc + bias)
template<int MODE, bool SPLIT>
__global__ __launch_bounds__(256)
void gemm_bf16_kernel(int Kd,
                      const float* __restrict__ A, int lda,
                      const float* __restrict__ B, int ldb,
                      const float* __restrict__ bias,
                      float* __restrict__ out, int ldo,
                      const int* __restrict__ rowmeta,
                      size_t bstride, int biasstride)
{
    __shared__ short Ah[BM * PADK];
    __shared__ short Bh[BN * PADK];
    __shared__ short Al[SPLIT ? BM * PADK : 2];
    __shared__ short Bl[SPLIT ? BN * PADK : 2];

    int roff = 0;
    if (rowmeta) {
        const int ee = blockIdx.z;
        const int rcnt = rowmeta[2 * ee + 1];
        if ((int)(blockIdx.y * BM) >= rcnt) return;
        roff = rowmeta[2 * ee];
        B += (size_t)ee * bstride;
        if (bias) bias += (size_t)ee * biasstride;
    }

    const int tid = threadIdx.x;
    const int m0 = roff + blockIdx.y * BM;
    const int n0 = blockIdx.x * BN;
    const int w = tid >> 6, lane = tid & 63;
    const int wr = w >> 1, wc = w & 1;          // wave tile (64x64)
    const int lrow = lane & 15, lkg = lane >> 4;
    const int srow = tid >> 3, skg = (tid & 7) * 4;

    const float* Ablk = A + (size_t)m0 * lda;
    const float* Bblk = B + (size_t)n0 * ldb;

    float4 pa[4], pb[4];
    #pragma unroll
    for (int p = 0; p < 4; ++p) {
        pa[p] = *(const float4*)(Ablk + (size_t)(p * 32 + srow) * lda + skg);
        pb[p] = *(const float4*)(Bblk + (size_t)(p * 32 + srow) * ldb + skg);
    }

    f32x4 acc[4][4] = {};
    const int nk = Kd / BK;

    for (int t = 0; t < nk; ++t) {
        __syncthreads();   // previous compute done; LDS free
        #pragma unroll
        for (int p = 0; p < 4; ++p) {
            if constexpr (SPLIT) {
                ushort4 h, l;
                split2(pa[p].x, h.x, l.x); split2(pa[p].y, h.y, l.y);
                split2(pa[p].z, h.z, l.z); split2(pa[p].w, h.w, l.w);
                *(ushort4*)(&Ah[(p * 32 + srow) * PADK + skg]) = h;
                *(ushort4*)(&Al[(p * 32 + srow) * PADK + skg]) = l;
                split2(pb[p].x, h.x, l.x); split2(pb[p].y, h.y, l.y);
                split2(pb[p].z, h.z, l.z); split2(pb[p].w, h.w, l.w);
                *(ushort4*)(&Bh[(p * 32 + srow) * PADK + skg]) = h;
                *(ushort4*)(&Bl[(p * 32 + srow) * PADK + skg]) = l;
            } else {
                *(ushort4*)(&Ah[(p * 32 + srow) * PADK + skg]) = cvt4(pa[p]);
                *(ushort4*)(&Bh[(p * 32 + srow) * PADK + skg]) = cvt4(pb[p]);
            }
        }
        __syncthreads();   // writes visible
        if (t + 1 < nk) {
            const int kb = (t + 1) * BK + skg;
            #pragma unroll
            for (int p = 0; p < 4; ++p) {
                pa[p] = *(const float4*)(Ablk + (size_t)(p * 32 + srow) * lda + kb);
                pb[p] = *(const float4*)(Bblk + (size_t)(p * 32 + srow) * ldb + kb);
            }
        }
        bf16x8 afh[4], afl[4];
        #pragma unroll
        for (int i = 0; i < 4; ++i) {
            afh[i] = *(const bf16x8*)(&Ah[(wr * 64 + i * 16 + lrow) * PADK + lkg * 8]);
            if constexpr (SPLIT)
                afl[i] = *(const bf16x8*)(&Al[(wr * 64 + i * 16 + lrow) * PADK + lkg * 8]);
        }
        #pragma unroll
        for (int j = 0; j < 4; ++j) {
            const bf16x8 bh = *(const bf16x8*)(&Bh[(wc * 64 + j * 16 + lrow) * PADK + lkg * 8]);
            if constexpr (SPLIT) {
                const bf16x8 bl = *(const bf16x8*)(&Bl[(wc * 64 + j * 16 + lrow) * PADK + lkg * 8]);
                #pragma unroll
                for (int i = 0; i < 4; ++i) {
                    acc[i][j] = __builtin_amdgcn_mfma_f32_16x16x32_bf16(afh[i], bh, acc[i][j], 0, 0, 0);
                    acc[i][j] = __builtin_amdgcn_mfma_f32_16x16x32_bf16(afl[i], bh, acc[i][j], 0, 0, 0);
                    acc[i][j] = __builtin_amdgcn_mfma_f32_16x16x32_bf16(afh[i], bl, acc[i][j], 0, 0, 0);
                }
            } else {
                #pragma unroll
                for (int i = 0; i < 4; ++i)
                    acc[i][j] = __builtin_amdgcn_mfma_f32_16x16x32_bf16(afh[i], bh, acc[i][j], 0, 0, 0);
            }
        }
    }

    #pragma unroll
    for (int i = 0; i < 4; ++i) {
        #pragma unroll
        for (int r = 0; r < 4; ++r) {
            const int row = m0 + wr * 64 + i * 16 + lkg * 4 + r;
            #pragma unroll
            for (int j = 0; j < 4; ++j) {
                const int col = n0 + wc * 64 + j * 16 + lrow;
                const float bj = bias ? bias[col] : 0.0f;
                const float vres = acc[i][j][r] + bj;
                float* op = out + (size_t)row * ldo + col;
                if (MODE == 0) *op = vres;
                else if (MODE == 1) *op = *op + vres;
                else *op = fmaxf(vres, 0.0f);
            }
        }
    }
}

// ---------------- fast bf16 GEMM, pre-converted A (and optionally B) ----------------
// A: bf16 [M][K]. B: BBF ? bf16 [N][K] : fp32 [N][K] (inline cvt).
// MODE 0: out = acc + bias ; MODE 2: out = relu(acc + bias). OUTBF: write bf16.
// SWZ: XCD-aware block remap, m-fastest within XCD (requires nwg%8==0, rowmeta==null)
template<int MODE, bool SWZ, bool OUTBF, bool BBF>
__global__ __launch_bounds__(256)
void gemm_fastw_kernel(int Kd,
                       const unsigned short* __restrict__ A, int lda,
                       const void* __restrict__ Bv, int ldb,
                       const float* __restrict__ bias,
                       void* __restrict__ outv, int ldo,
                       const int* __restrict__ rowmeta,
                       size_t bstride, int biasstride)
{
    __shared__ short Ah[BM * PADK];
    __shared__ short Bh[BN * PADK];

    int bx = blockIdx.x, by = blockIdx.y;
    if constexpr (SWZ) {
        const int nwg = gridDim.x * gridDim.y;
        const int chunk = nwg >> 3;                    // nwg % 8 == 0
        const int flat = by * gridDim.x + bx;
        const int newid = (flat & 7) * chunk + (flat >> 3);
        by = newid % gridDim.y;                        // m-tile fastest within XCD
        bx = newid / gridDim.y;
    }

    const float* Bf = (const float*)Bv;
    const unsigned short* Bb = (const unsigned short*)Bv;
    float* outf = (float*)outv;
    unsigned short* outb = (unsigned short*)outv;

    int roff = 0;
    if (rowmeta) {
        const int ee = blockIdx.z;
        const int rcnt = rowmeta[2 * ee + 1];
        if ((int)(by * BM) >= rcnt) return;
        roff = rowmeta[2 * ee];
        if (BBF) Bb += (size_t)ee * bstride; else Bf += (size_t)ee * bstride;
        if (bias) bias += (size_t)ee * biasstride;
    }

    const int tid = threadIdx.x;
    const int m0 = roff + by * BM;
    const int n0 = bx * BN;
    const int w = tid >> 6, lane = tid & 63;
    const int wr = w >> 1, wc = w & 1;          // wave tile (64x64)
    const int lrow = lane & 15, lkg = lane >> 4;
    const int srow = tid >> 3, skg = (tid & 7) * 4;

    const unsigned short* Ablk = A + (size_t)m0 * lda;
    const float* Bfblk = Bf + (size_t)n0 * ldb;
    const unsigned short* Bbblk = Bb + (size_t)n0 * ldb;

    ushort4 pa[4];
    ushort4 pbb[4];
    float4  pbf[4];
    #pragma unroll
    for (int p = 0; p < 4; ++p) {
        pa[p] = *(const ushort4*)(Ablk + (size_t)(p * 32 + srow) * lda + skg);
        if constexpr (BBF) pbb[p] = *(const ushort4*)(Bbblk + (size_t)(p * 32 + srow) * ldb + skg);
        else               pbf[p] = *(const float4*)(Bfblk + (size_t)(p * 32 + srow) * ldb + skg);
    }

    f32x4 acc[4][4] = {};
    const int nk = Kd / BK;

    for (int t = 0; t < nk; ++t) {
        __syncthreads();
        #pragma unroll
        for (int p = 0; p < 4; ++p) {
            *(ushort4*)(&Ah[(p * 32 + srow) * PADK + skg]) = pa[p];
            *(ushort4*)(&Bh[(p * 32 + srow) * PADK + skg]) = BBF ? pbb[p] : cvt4(pbf[p]);
        }
        __syncthreads();
        if (t + 1 < nk) {
            const int kb = (t + 1) * BK + skg;
            #pragma unroll
            for (int p = 0; p < 4; ++p) {
                pa[p] = *(const ushort4*)(Ablk + (size_t)(p * 32 + srow) * lda + kb);
                if constexpr (BBF) pbb[p] = *(const ushort4*)(Bbblk + (size_t)(p * 32 + srow) * ldb + kb);
                else               pbf[p] = *(const float4*)(Bfblk + (size_t)(p * 32 + srow) * ldb + kb);
            }
        }
        bf16x8 af[4];
        #pragma unroll
        for (int i = 0; i < 4; ++i)
            af[i] = *(const bf16x8*)(&Ah[(wr * 64 + i * 16 + lrow) * PADK + lkg * 8]);
        #pragma unroll
        for (int j = 0; j < 4; ++j) {
            const bf16x8 bh = *(const bf16x8*)(&Bh[(wc * 64 + j * 16 + lrow) * PADK + lkg * 8]);
            #pragma unroll
            for (int i = 0; i < 4; ++i)
                acc[i][j] = __builtin_amdgcn_mfma_f32_16x16x32_bf16(af[i], bh, acc[i][j], 0, 0, 0);
        }
    }

    #pragma unroll
    for (int i = 0; i < 4; ++i) {
        #pragma unroll
        for (int r = 0; r < 4; ++r) {
            const int row = m0 + wr * 64 + i * 16 + lkg * 4 + r;
            #pragma unroll
            for (int j = 0; j < 4; ++j) {
                const int col = n0 + wc * 64 + j * 16 + lrow;
                const float bj = bias ? bias[col] : 0.0f;
                float vres = acc[i][j][r] + bj;
                if (MODE == 2) vres = fmaxf(vres, 0.0f);
                if constexpr (OUTBF) outb[(size_t)row * ldo + col] = f2bf(vres);
                else                 outf[(size_t)row * ldo + col] = vres;
            }
        }
    }
}

// ---------------- MFMA flash attention, split-precision (fp32-grade) ----------------
#define QBLK 64
#define KVBLK 64

__global__ __launch_bounds__(256)
void attn_mfma_kernel(const float* __restrict__ qkv, float* __restrict__ o)
{
    __shared__ short Kh[2][KVBLK][PADK];
    __shared__ short Kl[2][KVBLK][PADK];
    __shared__ short Vh[2][HSD][PADK];
    __shared__ short Vl[2][HSD][PADK];
    __shared__ short Ph[4][2][16][PADK];
    __shared__ short Pl[4][2][16][PADK];

    const int t0 = blockIdx.x * QBLK;
    const int bh = blockIdx.y;
    const int b = bh / HCNT, hh = bh % HCNT;
    const size_t baseq = (size_t)b * TT * QKVLD + (size_t)hh * HSD;
    const size_t obase = (size_t)b * TT * CDIM + (size_t)hh * HSD;
    const float* q = qkv + baseq;
    const float* k = qkv + baseq + CDIM;
    const float* v = qkv + baseq + 2 * CDIM;
    const int tid = threadIdx.x;
    const int w = tid >> 6, lane = tid & 63;
    const int lrow = lane & 15, lkg = lane >> 4;
    const float sscale = rsqrtf((float)CDIM);

    bf16x8 qh[2], ql[2];
    {
        const float* qr = q + (size_t)(t0 + w * 16 + lrow) * QKVLD;
        #pragma unroll
        for (int ks = 0; ks < 2; ++ks) {
            #pragma unroll
            for (int j = 0; j < 8; ++j) {
                unsigned short h, l;
                split2(qr[ks * 32 + lkg * 8 + j], h, l);
                qh[ks][j] = (short)h;
                ql[ks][j] = (short)l;
            }
        }
    }

    f32x4 oacc[4] = {};
    float m_[4], l_[4];
    #pragma unroll
    for (int rr = 0; rr < 4; ++rr) { m_[rr] = -1e30f; l_[rr] = 0.0f; }

    for (int s0 = 0; s0 <= t0 + QBLK - 1; s0 += KVBLK) {
        __syncthreads();
        {
            const int srow = tid >> 3, skg = (tid & 7) * 4;
            #pragma unroll
            for (int p = 0; p < 2; ++p) {
                const float* krow = k + (size_t)(s0 + p * 32 + srow) * QKVLD;
                #pragma unroll
                for (int ks = 0; ks < 2; ++ks) {
                    float4 a = *(const float4*)(krow + ks * 32 + skg);
                    ushort4 h, l;
                    split2(a.x, h.x, l.x); split2(a.y, h.y, l.y);
                    split2(a.z, h.z, l.z); split2(a.w, h.w, l.w);
                    *(ushort4*)(&Kh[ks][p * 32 + srow][skg]) = h;
                    *(ushort4*)(&Kl[ks][p * 32 + srow][skg]) = l;
                }
            }
            const int key = tid & 63, dg = (tid >> 6) * 16;
            const float* vrow = v + (size_t)(s0 + key) * QKVLD + dg;
            const int kst = key >> 5, ko = key & 31;
            #pragma unroll
            for (int dd = 0; dd < 16; dd += 4) {
                float4 a = *(const float4*)(vrow + dd);
                unsigned short h, l;
                split2(a.x, h, l); Vh[kst][dg + dd + 0][ko] = h; Vl[kst][dg + dd + 0][ko] = l;
                split2(a.y, h, l); Vh[kst][dg + dd + 1][ko] = h; Vl[kst][dg + dd + 1][ko] = l;
                split2(a.z, h, l); Vh[kst][dg + dd + 2][ko] = h; Vl[kst][dg + dd + 2][ko] = l;
                split2(a.w, h, l); Vh[kst][dg + dd + 3][ko] = h; Vl[kst][dg + dd + 3][ko] = l;
            }
        }
        __syncthreads();

        f32x4 sacc[4] = {};
        #pragma unroll
        for (int j = 0; j < 4; ++j) {
            #pragma unroll
            for (int ks = 0; ks < 2; ++ks) {
                const bf16x8 bh = *(const bf16x8*)(&Kh[ks][j * 16 + lrow][lkg * 8]);
                const bf16x8 bl = *(const bf16x8*)(&Kl[ks][j * 16 + lrow][lkg * 8]);
                sacc[j] = __builtin_amdgcn_mfma_f32_16x16x32_bf16(qh[ks], bh, sacc[j], 0, 0, 0);
                sacc[j] = __builtin_amdgcn_mfma_f32_16x16x32_bf16(ql[ks], bh, sacc[j], 0, 0, 0);
                sacc[j] = __builtin_amdgcn_mfma_f32_16x16x32_bf16(qh[ks], bl, sacc[j], 0, 0, 0);
            }
        }

        #pragma unroll
        for (int rr = 0; rr < 4; ++rr) {
            const int qi = t0 + w * 16 + lkg * 4 + rr;
            float pv[4];
            float mx = -1e30f;
            #pragma unroll
            for (int j = 0; j < 4; ++j) {
                float s = sacc[j][rr] * sscale;
                if (s0 + j * 16 + lrow > qi) s = -1e30f;
                pv[j] = s;
                mx = fmaxf(mx, s);
            }
            #pragma unroll
            for (int off = 1; off < 16; off <<= 1) mx = fmaxf(mx, __shfl_xor(mx, off));
            const float mnew = fmaxf(m_[rr], mx);
            const float corr = __expf(m_[rr] - mnew);
            float ps = 0.0f;
            #pragma unroll
            for (int j = 0; j < 4; ++j) { pv[j] = __expf(pv[j] - mnew); ps += pv[j]; }
            #pragma unroll
            for (int off = 1; off < 16; off <<= 1) ps += __shfl_xor(ps, off);
            l_[rr] = l_[rr] * corr + ps;
            m_[rr] = mnew;
            #pragma unroll
            for (int jd = 0; jd < 4; ++jd) oacc[jd][rr] *= corr;
            #pragma unroll
            for (int j = 0; j < 4; ++j) {
                unsigned short h, l;
                split2(pv[j], h, l);
                const int key = j * 16 + lrow;
                Ph[w][key >> 5][lkg * 4 + rr][key & 31] = h;
                Pl[w][key >> 5][lkg * 4 + rr][key & 31] = l;
            }
        }

        #pragma unroll
        for (int ks = 0; ks < 2; ++ks) {
            const bf16x8 ah = *(const bf16x8*)(&Ph[w][ks][lrow][lkg * 8]);
            const bf16x8 al = *(const bf16x8*)(&Pl[w][ks][lrow][lkg * 8]);
            #pragma unroll
            for (int jd = 0; jd < 4; ++jd) {
                const bf16x8 bh = *(const bf16x8*)(&Vh[ks][jd * 16 + lrow][lkg * 8]);
                const bf16x8 bl = *(const bf16x8*)(&Vl[ks][jd * 16 + lrow][lkg * 8]);
                oacc[jd] = __builtin_amdgcn_mfma_f32_16x16x32_bf16(ah, bh, oacc[jd], 0, 0, 0);
                oacc[jd] = __builtin_amdgcn_mfma_f32_16x16x32_bf16(al, bh, oacc[jd], 0, 0, 0);
                oacc[jd] = __builtin_amdgcn_mfma_f32_16x16x32_bf16(ah, bl, oacc[jd], 0, 0, 0);
            }
        }
    }

    #pragma unroll
    for (int rr = 0; rr < 4; ++rr) {
        const int qi = t0 + w * 16 + lkg * 4 + rr;
        const float invl = 1.0f / l_[rr];
        float* orow = o + obase + (size_t)qi * CDIM;
        #pragma unroll
        for (int jd = 0; jd < 4; ++jd)
            orow[jd * 16 + lrow] = oacc[jd][rr] * invl;
    }
}

// ---------------- gate: logits + top-2 + softmax -> sel[N], wts[N] ----------------
__global__ __launch_bounds__(256)
void gate_kernel(const float* __restrict__ h2, const float* __restrict__ gw,
                 int2* __restrict__ sel, float2* __restrict__ wts)
{
    __shared__ float gws[ECNT * CDIM];
    int tid = threadIdx.x;
    for (int i = tid; i < ECNT * CDIM; i += 256) gws[i] = gw[i];
    __syncthreads();
    int t = blockIdx.x * 256 + tid;
    const float* hr = h2 + (size_t)t * CDIM;
    float g[ECNT] = {};
    for (int c = 0; c < CDIM; ++c) {
        float hv = hr[c];
        #pragma unroll
        for (int e = 0; e < ECNT; ++e) g[e] = fmaf(hv, gws[e * CDIM + c], g[e]);
    }
    int e0 = 0; float g0 = g[0];
    #pragma unroll
    for (int e = 1; e < ECNT; ++e) if (g[e] > g0) { g0 = g[e]; e0 = e; }
    int e1 = -1; float g1 = -1e30f;
    #pragma unroll
    for (int e = 0; e < ECNT; ++e) if (e != e0 && g[e] > g1) { g1 = g[e]; e1 = e; }
    float z = __expf(g1 - g0);          // <= 1
    float w0 = 1.0f / (1.0f + z);
    sel[t] = make_int2(e0, e1);
    wts[t] = make_float2(w0, 1.0f - w0);
}

// ---------------- routing: build expert-grouped permutation (single block) ----------------
__global__ __launch_bounds__(256)
void route_kernel(const int2* __restrict__ sel, int* __restrict__ perm,
                  int* __restrict__ tokpos, int* __restrict__ meta)
{
    __shared__ int cnt[ECNT], off[ECNT], cur[ECNT];
    const int tid = threadIdx.x;
    if (tid < ECNT) cnt[tid] = 0;
    __syncthreads();
    for (int t = tid; t < NTOK; t += 256) {
        atomicAdd(&cnt[sel[t].x], 1);
        atomicAdd(&cnt[sel[t].y], 1);
    }
    __syncthreads();
    if (tid == 0) {
        int run = 0;
        for (int e = 0; e < ECNT; ++e) {
            off[e] = run; cur[e] = 0;
            int pc = (cnt[e] + BM - 1) / BM * BM;
            meta[2 * e] = run; meta[2 * e + 1] = pc;
            run += pc;
        }
    }
    __syncthreads();
    for (int p = tid; p < TOTCAP; p += 256) perm[p] = 0;   // pad slots -> token 0
    __syncthreads();
    for (int t = tid; t < NTOK; t += 256) {
        int2 s = sel[t];
        int p0 = atomicAdd(&cur[s.x], 1); perm[off[s.x] + p0] = t; tokpos[2 * t]     = off[s.x] + p0;
        int p1 = atomicAdd(&cur[s.y], 1); perm[off[s.y] + p1] = t; tokpos[2 * t + 1] = off[s.y] + p1;
    }
}

// ---------------- gather h2 rows into expert order ----------------
__global__ __launch_bounds__(256)
void gather_kernel(const float* __restrict__ h2, const int* __restrict__ perm,
                   float* __restrict__ xg)
{
    int i = blockIdx.x * 256 + threadIdx.x;   // TOTCAP*CDIM
    int c = i % CDIM, p = i / CDIM;
    xg[i] = h2[(size_t)perm[p] * CDIM + c];
}

__global__ __launch_bounds__(256)
void gather_bf16_kernel(const float* __restrict__ h2, const int* __restrict__ perm,
                        unsigned short* __restrict__ xg)
{
    int i = blockIdx.x * 256 + threadIdx.x;   // TOTCAP*CDIM
    int c = i % CDIM, p = i / CDIM;
    xg[i] = f2bf(h2[(size_t)perm[p] * CDIM + c]);
}

// ---------------- combine: x += w0*y[pos0] + w1*y[pos1] ----------------
__global__ __launch_bounds__(256)
void combine_kernel(const float* __restrict__ y, const int* __restrict__ tokpos,
                    const float2* __restrict__ wts, float* __restrict__ x)
{
    int i = blockIdx.x * 256 + threadIdx.x;   // NTOK*CDIM
    int c = i % CDIM, t = i / CDIM;
    float2 wv = wts[t];
    x[i] += wv.x * y[(size_t)tokpos[2 * t] * CDIM + c]
          + wv.y * y[(size_t)tokpos[2 * t + 1] * CDIM + c];
}

// ---------------- per-row cross-entropy ----------------
__global__ __launch_bounds__(256)
void loss_row_kernel(const float* __restrict__ logits, const int* __restrict__ tgt,
                     float* __restrict__ lrow)
{
    int row = blockIdx.x;
    const float* lr = logits + (size_t)row * VOC;
    int tid = threadIdx.x, w = tid >> 6, lane = tid & 63;
    __shared__ float red[4];
    float mx = -1e30f;
    for (int i = tid; i < VOC; i += 256) mx = fmaxf(mx, lr[i]);
    mx = wave_max(mx);
    if (lane == 0) red[w] = mx;
    __syncthreads();
    mx = fmaxf(fmaxf(red[0], red[1]), fmaxf(red[2], red[3]));
    __syncthreads();
    float se = 0.0f;
    for (int i = tid; i < VOC; i += 256) se += expf(lr[i] - mx);
    se = wave_sum(se);
    if (lane == 0) red[w] = se;
    __syncthreads();
    if (tid == 0) {
        float lse = mx + logf(red[0] + red[1] + red[2] + red[3]);
        lrow[row] = lse - lr[tgt[row]];
    }
}

__global__ __launch_bounds__(256)
void loss_reduce_kernel(const float* __restrict__ lrow, float* __restrict__ out)
{
    int tid = threadIdx.x, w = tid >> 6, lane = tid & 63;
    float s = 0.0f;
    for (int i = tid; i < NTOK; i += 256) s += lrow[i];
    s = wave_sum(s);
    __shared__ float red[4];
    if (lane == 0) red[w] = s;
    __syncthreads();
    if (tid == 0) out[0] = (red[0] + red[1] + red[2] + red[3]) * (1.0f / NTOK);
}

// ---------------- launch ----------------
extern "C" void kernel_launch(void* const* d_in, const int* in_sizes, int n_in,
                              void* d_out, int out_size, void* d_ws, size_t ws_size,
                              hipStream_t stream)
{
    const int*   idx     = (const int*)d_in[0];
    const int*   targets = (const int*)d_in[1];
    const float* tok_emb = (const float*)d_in[2];
    const float* pos_emb = (const float*)d_in[3];
    const float* ln1_s   = (const float*)d_in[4];
    const float* ln1_b   = (const float*)d_in[5];
    const float* wq      = (const float*)d_in[6];
    const float* wk      = (const float*)d_in[7];
    const float* wv      = (const float*)d_in[8];
    const float* wo      = (const float*)d_in[9];
    const float* bo      = (const float*)d_in[10];
    const float* ln2_s   = (const float*)d_in[11];
    const float* ln2_b   = (const float*)d_in[12];
    const float* gate_w  = (const float*)d_in[13];
    const float* w1      = (const float*)d_in[14];
    const float* b1      = (const float*)d_in[15];
    const float* w2      = (const float*)d_in[16];
    const float* b2      = (const float*)d_in[17];
    const float* lm_w    = (const float*)d_in[18];
    const float* lm_b    = (const float*)d_in[19];
    float* out = (float*)d_out;

    float* ws   = (float*)d_ws;
    float* wp   = ws;                                // 3*L*C*C  ([l][3C][C] fused B^T)
    float* x    = wp   + (size_t)3 * LCNT * CDIM * CDIM;
    float* hbuf = x    + (size_t)NTOK * CDIM;        // LN1 out, attn out
    float* qkv  = hbuf + (size_t)NTOK * CDIM;        // [NTOK][2304]; h2/ybuf overlay after attn
    float* xg   = qkv  + (size_t)NTOK * QKVLD;       // TOTCAP*C gathered h2 (fp32 l0 / bf16 l1)
    float* hid  = xg   + (size_t)TOTCAP * CDIM;      // TOTCAP*FF fp32 (l0); bf16 hid + lm_w_bf overlay (l1/head)
    float* lrow = hid  + (size_t)TOTCAP * FF;        // NTOK
    float2* wts = (float2*)(lrow + NTOK);            // NTOK float2
    int2*  sel  = (int2*)(wts + NTOK);               // NTOK int2
    int*   perm = (int*)(sel + NTOK);                // TOTCAP
    int*  tokpos= perm + TOTCAP;                     // 2*NTOK
    int*   meta = tokpos + 2 * NTOK;                 // 16
    unsigned short* x_bf = (unsigned short*)(meta + 16);  // NTOK*C bf16 (fresh, 3.1 MB)

    unsigned short* xg_bf  = (unsigned short*)xg;    // aliases xg (l1 only)
    unsigned short* hid_bf = (unsigned short*)hid;   // aliases hid (l1 only)
    unsigned short* lmw_bf = (unsigned short*)hid;   // aliases hid (after l1 experts done)

    dim3 blk(256);

    repack_kernel<<<(3 * LCNT * CDIM * CDIM) / 256, blk, 0, stream>>>(wq, wk, wv, wp);
    embed_kernel<<<(NTOK * CDIM) / 256, blk, 0, stream>>>(idx, tok_emb, pos_emb, x);

    for (int l = 0; l < LCNT; ++l) {
        ln_kernel<<<NTOK, blk, 0, stream>>>(x, ln1_s + (size_t)l * CDIM, ln1_b + (size_t)l * CDIM, hbuf);

        // fused QKV projection: [NTOK,768] x [2304,768]^T -> [NTOK,2304]
        gemm_bf16_kernel<0, true><<<dim3(QKVLD / BN, NTOK / BM), blk, 0, stream>>>(
            CDIM, hbuf, CDIM, wp + (size_t)l * 3 * CDIM * CDIM, CDIM,
            nullptr, qkv, QKVLD, nullptr, 0, 0);

        attn_mfma_kernel<<<dim3(TT / QBLK, BB * HCNT), blk, 0, stream>>>(qkv, hbuf);

        gemm_bf16_kernel<1, true><<<dim3(CDIM / BN, NTOK / BM), blk, 0, stream>>>(
            CDIM, hbuf, CDIM, wo + (size_t)l * CDIM * CDIM, CDIM,
            bo + (size_t)l * CDIM, x, CDIM, nullptr, 0, 0);

        // --- MoE: gate -> route -> gather -> expert GEMMs -> combine ---
        float* h2 = qkv;       // attn consumed qkv; reuse as compact [NTOK][C]
        float* ybuf = qkv;     // w2 output overlays h2 after gather
        ln_kernel<<<NTOK, blk, 0, stream>>>(x, ln2_s + (size_t)l * CDIM, ln2_b + (size_t)l * CDIM, h2);
        gate_kernel<<<NTOK / 256, blk, 0, stream>>>(h2, gate_w + (size_t)l * ECNT * CDIM, sel, wts);
        route_kernel<<<1, blk, 0, stream>>>(sel, perm, tokpos, meta);

        const float* w1l = w1 + (size_t)l * ECNT * FF * CDIM;
        const float* b1l = b1 + (size_t)l * ECNT * FF;
        const float* w2l = w2 + (size_t)l * ECNT * CDIM * FF;
        const float* b2l = b2 + (size_t)l * ECNT * CDIM;
        if (l == 0) {   // feeds next layer's router -> keep fp32-grade (split 3-MFMA)
            gather_kernel<<<(TOTCAP * CDIM) / 256, blk, 0, stream>>>(h2, perm, xg);
            gemm_bf16_kernel<2, true><<<dim3(FF / BN, TOTCAP / BM, ECNT), blk, 0, stream>>>(
                CDIM, xg, CDIM, w1l, CDIM, b1l, hid, FF, meta, (size_t)FF * CDIM, FF);
            gemm_bf16_kernel<0, true><<<dim3(CDIM / BN, TOTCAP / BM, ECNT), blk, 0, stream>>>(
                FF, hid, FF, w2l, FF, b2l, ybuf, CDIM, meta, (size_t)CDIM * FF, CDIM);
        } else {        // feeds only logits -> fast 1-MFMA, bf16 activations end-to-end
            gather_bf16_kernel<<<(TOTCAP * CDIM) / 256, blk, 0, stream>>>(h2, perm, xg_bf);
            gemm_fastw_kernel<2, false, true, false><<<dim3(FF / BN, TOTCAP / BM, ECNT), blk, 0, stream>>>(
                CDIM, xg_bf, CDIM, w1l, CDIM, b1l, hid_bf, FF, meta, (size_t)FF * CDIM, FF);
            gemm_fastw_kernel<0, false, false, false><<<dim3(CDIM / BN, TOTCAP / BM, ECNT), blk, 0, stream>>>(
                FF, hid_bf, FF, w2l, FF, b2l, ybuf, CDIM, meta, (size_t)CDIM * FF, CDIM);
        }
        combine_kernel<<<(NTOK * CDIM) / 256, blk, 0, stream>>>(ybuf, tokpos, wts, x);
    }

    // pre-convert LM head operands to bf16 (hid region is dead now)
    cvt_bf16_kernel<<<2048, blk, 0, stream>>>(lm_w, lmw_bf, VOC * CDIM / 4);
    cvt_bf16_kernel<<<512, blk, 0, stream>>>(x, x_bf, NTOK * CDIM / 4);

    // LM head: bf16 x bf16, XCD-aware m-fastest swizzle (4000 blocks % 8 == 0)
    gemm_fastw_kernel<0, true, false, true><<<dim3(VOC / BN, NTOK / BM), blk, 0, stream>>>(
        CDIM, x_bf, CDIM, lmw_bf, CDIM, lm_b, out, VOC, nullptr, 0, 0);

    loss_row_kernel<<<NTOK, blk, 0, stream>>>(out, targets, lrow);
    loss_reduce_kernel<<<1, blk, 0, stream>>>(lrow, out + (size_t)NTOK * VOC);
}

// Round 9
// 1408.673 us; speedup vs baseline: 9.0805x; 1.0204x over previous
//
#include <hip/hip_runtime.h>
#include <hip/hip_bf16.h>

// Problem constants (from reference)
#define LCNT 2
#define HCNT 12
#define CDIM 768
#define HSD  64
#define ECNT 8
#define VOC  32000
#define BB   2
#define TT   1024
#define NTOK 2048   // B*T
#define FF   3072   // 4*C
#define QKVLD 2304  // 3*C
#define TOTCAP 5120 // 2*NTOK + 8*128 padding capacity

typedef __attribute__((ext_vector_type(8))) short bf16x8;
typedef __attribute__((ext_vector_type(4))) float f32x4;

// ---------------- helpers ----------------
__device__ __forceinline__ float wave_sum(float v) {
    #pragma unroll
    for (int off = 32; off; off >>= 1) v += __shfl_xor(v, off);
    return v;
}
__device__ __forceinline__ float wave_max(float v) {
    #pragma unroll
    for (int off = 32; off; off >>= 1) v = fmaxf(v, __shfl_xor(v, off));
    return v;
}
__device__ __forceinline__ unsigned short f2bf(float f) {
    unsigned int u = __float_as_uint(f);
    unsigned int r = (u + 0x7FFFu + ((u >> 16) & 1u)) >> 16;
    return (unsigned short)r;
}
__device__ __forceinline__ float bf2f(unsigned short h) {
    return __uint_as_float((unsigned int)h << 16);
}
__device__ __forceinline__ void split2(float a, unsigned short& h, unsigned short& l) {
    h = f2bf(a);
    l = f2bf(a - bf2f(h));
}
__device__ __forceinline__ ushort4 cvt4(float4 v) {
    ushort4 r;
    r.x = f2bf(v.x); r.y = f2bf(v.y); r.z = f2bf(v.z); r.w = f2bf(v.w);
    return r;
}
// async 16B global->LDS (dest = wave-uniform base + lane*16)
__device__ __forceinline__ void gload16(const void* g, void* l) {
    __builtin_amdgcn_global_load_lds(
        (const __attribute__((address_space(1))) unsigned int*)g,
        (__attribute__((address_space(3))) unsigned int*)l,
        16, 0, 0);
}

// ---------------- fp32 -> bf16 bulk convert ----------------
__global__ __launch_bounds__(256)
void cvt_bf16_kernel(const float* __restrict__ in, unsigned short* __restrict__ out, int n4)
{
    for (int i = blockIdx.x * 256 + threadIdx.x; i < n4; i += gridDim.x * 256) {
        float4 v = reinterpret_cast<const float4*>(in)[i];
        reinterpret_cast<ushort4*>(out)[i] = cvt4(v);
    }
}

// ---------------- fp32 -> split hi/lo bf16 bulk ----------------
__global__ __launch_bounds__(256)
void splitw_kernel(const float* __restrict__ in, unsigned short* __restrict__ oh,
                   unsigned short* __restrict__ ol, int n4)
{
    for (int i = blockIdx.x * 256 + threadIdx.x; i < n4; i += gridDim.x * 256) {
        float4 v = reinterpret_cast<const float4*>(in)[i];
        ushort4 h, l;
        split2(v.x, h.x, l.x); split2(v.y, h.y, l.y);
        split2(v.z, h.z, l.z); split2(v.w, h.w, l.w);
        reinterpret_cast<ushort4*>(oh)[i] = h;
        reinterpret_cast<ushort4*>(ol)[i] = l;
    }
}

// ---------------- embedding ----------------
__global__ __launch_bounds__(256)
void embed_kernel(const int* __restrict__ idx, const float* __restrict__ tok,
                  const float* __restrict__ pos, float* __restrict__ x)
{
    int i = blockIdx.x * 256 + threadIdx.x;      // N*C total
    int c = i % CDIM;
    int n = i / CDIM;
    int t = n % TT;
    x[i] = tok[(size_t)idx[n] * CDIM + c] + pos[(size_t)t * CDIM + c];
}

// ---------------- repack wq/wk/wv [L,H,C,HS] -> split hi/lo [l][w3*C + n][k] (fused B^T) ----------------
__global__ __launch_bounds__(256)
void repack_kernel(const float* __restrict__ wq, const float* __restrict__ wk,
                   const float* __restrict__ wv, unsigned short* __restrict__ wph,
                   unsigned short* __restrict__ wpl)
{
    int i = blockIdx.x * 256 + threadIdx.x;      // 3*L*C*C
    int kk = i % CDIM;
    int n  = (i / CDIM) % CDIM;
    int w3 = (i / (CDIM * CDIM)) % 3;
    int l  = i / (CDIM * CDIM * 3);
    const float* src = (w3 == 0) ? wq : (w3 == 1) ? wk : wv;
    int h = n / HSD, d = n % HSD;
    float v = src[((((size_t)l * HCNT + h) * CDIM) + kk) * HSD + d];
    unsigned short hh, ll;
    split2(v, hh, ll);
    size_t o = (((size_t)l * 3 + w3) * CDIM + n) * CDIM + kk;
    wph[o] = hh;
    wpl[o] = ll;
}

// ---------------- layernorm ----------------
__global__ __launch_bounds__(256)
void ln_kernel(const float* __restrict__ x, const float* __restrict__ sc,
               const float* __restrict__ bs, float* __restrict__ out)
{
    int row = blockIdx.x;
    const float* xr = x + (size_t)row * CDIM;
    float* orow = out + (size_t)row * CDIM;
    int tid = threadIdx.x;
    float v0 = xr[tid], v1 = xr[tid + 256], v2 = xr[tid + 512];
    float s1 = v0 + v1 + v2;
    float s2 = v0 * v0 + v1 * v1 + v2 * v2;
    s1 = wave_sum(s1);
    s2 = wave_sum(s2);
    __shared__ float r1[4], r2[4];
    int w = tid >> 6, lane = tid & 63;
    if (lane == 0) { r1[w] = s1; r2[w] = s2; }
    __syncthreads();
    float t1 = r1[0] + r1[1] + r1[2] + r1[3];
    float t2 = r2[0] + r2[1] + r2[2] + r2[3];
    float mu = t1 * (1.0f / CDIM);
    float var = t2 * (1.0f / CDIM) - mu * mu;
    float rstd = rsqrtf(var + 1e-5f);
    orow[tid]       = (v0 - mu) * rstd * sc[tid]       + bs[tid];
    orow[tid + 256] = (v1 - mu) * rstd * sc[tid + 256] + bs[tid + 256];
    orow[tid + 512] = (v2 - mu) * rstd * sc[tid + 512] + bs[tid + 512];
}

#define BM 128
#define BN 128
#define BK 32
#define PADK 40   // bf16 stride per row (80 B)

// ---------------- split-precision bf16 MFMA GEMM (fp32-grade, 3 MFMA) ----------------
// C[m,n] = sum_k A[m,k] * B[n,k]   (B row-major [N][K], i.e. B^T)
// MODE 0: out = acc + bias ; MODE 1: out += acc + bias ; MODE 2: out = relu(acc + bias)
template<int MODE, bool SPLIT>
__global__ __launch_bounds__(256)
void gemm_bf16_kernel(int Kd,
                      const float* __restrict__ A, int lda,
                      const float* __restrict__ B, int ldb,
                      const float* __restrict__ bias,
                      float* __restrict__ out, int ldo,
                      const int* __restrict__ rowmeta,
                      size_t bstride, int biasstride)
{
    __shared__ short Ah[BM * PADK];
    __shared__ short Bh[BN * PADK];
    __shared__ short Al[SPLIT ? BM * PADK : 2];
    __shared__ short Bl[SPLIT ? BN * PADK : 2];

    int roff = 0;
    if (rowmeta) {
        const int ee = blockIdx.z;
        const int rcnt = rowmeta[2 * ee + 1];
        if ((int)(blockIdx.y * BM) >= rcnt) return;
        roff = rowmeta[2 * ee];
        B += (size_t)ee * bstride;
        if (bias) bias += (size_t)ee * biasstride;
    }

    const int tid = threadIdx.x;
    const int m0 = roff + blockIdx.y * BM;
    const int n0 = blockIdx.x * BN;
    const int w = tid >> 6, lane = tid & 63;
    const int wr = w >> 1, wc = w & 1;          // wave tile (64x64)
    const int lrow = lane & 15, lkg = lane >> 4;
    const int srow = tid >> 3, skg = (tid & 7) * 4;

    const float* Ablk = A + (size_t)m0 * lda;
    const float* Bblk = B + (size_t)n0 * ldb;

    float4 pa[4], pb[4];
    #pragma unroll
    for (int p = 0; p < 4; ++p) {
        pa[p] = *(const float4*)(Ablk + (size_t)(p * 32 + srow) * lda + skg);
        pb[p] = *(const float4*)(Bblk + (size_t)(p * 32 + srow) * ldb + skg);
    }

    f32x4 acc[4][4] = {};
    const int nk = Kd / BK;

    for (int t = 0; t < nk; ++t) {
        __syncthreads();   // previous compute done; LDS free
        #pragma unroll
        for (int p = 0; p < 4; ++p) {
            if constexpr (SPLIT) {
                ushort4 h, l;
                split2(pa[p].x, h.x, l.x); split2(pa[p].y, h.y, l.y);
                split2(pa[p].z, h.z, l.z); split2(pa[p].w, h.w, l.w);
                *(ushort4*)(&Ah[(p * 32 + srow) * PADK + skg]) = h;
                *(ushort4*)(&Al[(p * 32 + srow) * PADK + skg]) = l;
                split2(pb[p].x, h.x, l.x); split2(pb[p].y, h.y, l.y);
                split2(pb[p].z, h.z, l.z); split2(pb[p].w, h.w, l.w);
                *(ushort4*)(&Bh[(p * 32 + srow) * PADK + skg]) = h;
                *(ushort4*)(&Bl[(p * 32 + srow) * PADK + skg]) = l;
            } else {
                *(ushort4*)(&Ah[(p * 32 + srow) * PADK + skg]) = cvt4(pa[p]);
                *(ushort4*)(&Bh[(p * 32 + srow) * PADK + skg]) = cvt4(pb[p]);
            }
        }
        __syncthreads();   // writes visible
        if (t + 1 < nk) {
            const int kb = (t + 1) * BK + skg;
            #pragma unroll
            for (int p = 0; p < 4; ++p) {
                pa[p] = *(const float4*)(Ablk + (size_t)(p * 32 + srow) * lda + kb);
                pb[p] = *(const float4*)(Bblk + (size_t)(p * 32 + srow) * ldb + kb);
            }
        }
        bf16x8 afh[4], afl[4];
        #pragma unroll
        for (int i = 0; i < 4; ++i) {
            afh[i] = *(const bf16x8*)(&Ah[(wr * 64 + i * 16 + lrow) * PADK + lkg * 8]);
            if constexpr (SPLIT)
                afl[i] = *(const bf16x8*)(&Al[(wr * 64 + i * 16 + lrow) * PADK + lkg * 8]);
        }
        #pragma unroll
        for (int j = 0; j < 4; ++j) {
            const bf16x8 bh = *(const bf16x8*)(&Bh[(wc * 64 + j * 16 + lrow) * PADK + lkg * 8]);
            if constexpr (SPLIT) {
                const bf16x8 bl = *(const bf16x8*)(&Bl[(wc * 64 + j * 16 + lrow) * PADK + lkg * 8]);
                #pragma unroll
                for (int i = 0; i < 4; ++i) {
                    acc[i][j] = __builtin_amdgcn_mfma_f32_16x16x32_bf16(afh[i], bh, acc[i][j], 0, 0, 0);
                    acc[i][j] = __builtin_amdgcn_mfma_f32_16x16x32_bf16(afl[i], bh, acc[i][j], 0, 0, 0);
                    acc[i][j] = __builtin_amdgcn_mfma_f32_16x16x32_bf16(afh[i], bl, acc[i][j], 0, 0, 0);
                }
            } else {
                #pragma unroll
                for (int i = 0; i < 4; ++i)
                    acc[i][j] = __builtin_amdgcn_mfma_f32_16x16x32_bf16(afh[i], bh, acc[i][j], 0, 0, 0);
            }
        }
    }

    #pragma unroll
    for (int i = 0; i < 4; ++i) {
        #pragma unroll
        for (int r = 0; r < 4; ++r) {
            const int row = m0 + wr * 64 + i * 16 + lkg * 4 + r;
            #pragma unroll
            for (int j = 0; j < 4; ++j) {
                const int col = n0 + wc * 64 + j * 16 + lrow;
                const float bj = bias ? bias[col] : 0.0f;
                const float vres = acc[i][j][r] + bj;
                float* op = out + (size_t)row * ldo + col;
                if (MODE == 0) *op = vres;
                else if (MODE == 1) *op = *op + vres;
                else *op = fmaxf(vres, 0.0f);
            }
        }
    }
}

// ---------------- split GEMM with PRE-SPLIT B (weights hi/lo bf16), A fp32 inline-split ----------------
// MODE 0: out = acc + bias ; MODE 1: out += acc + bias
template<int MODE>
__global__ __launch_bounds__(256)
void gemm_splitpb_kernel(int Kd,
                         const float* __restrict__ A, int lda,
                         const unsigned short* __restrict__ Bhg,
                         const unsigned short* __restrict__ Blg, int ldb,
                         const float* __restrict__ bias,
                         float* __restrict__ out, int ldo)
{
    __shared__ short Ah[BM * PADK];
    __shared__ short Al[BM * PADK];
    __shared__ short Bh[BN * PADK];
    __shared__ short Bl[BN * PADK];

    const int tid = threadIdx.x;
    const int m0 = blockIdx.y * BM;
    const int n0 = blockIdx.x * BN;
    const int w = tid >> 6, lane = tid & 63;
    const int wr = w >> 1, wc = w & 1;
    const int lrow = lane & 15, lkg = lane >> 4;
    const int srow = tid >> 3, skg = (tid & 7) * 4;

    const float* Ablk = A + (size_t)m0 * lda;
    const unsigned short* Bhblk = Bhg + (size_t)n0 * ldb;
    const unsigned short* Blblk = Blg + (size_t)n0 * ldb;

    float4 pa[4];
    ushort4 pbh[4], pbl[4];
    #pragma unroll
    for (int p = 0; p < 4; ++p) {
        pa[p]  = *(const float4*)(Ablk + (size_t)(p * 32 + srow) * lda + skg);
        pbh[p] = *(const ushort4*)(Bhblk + (size_t)(p * 32 + srow) * ldb + skg);
        pbl[p] = *(const ushort4*)(Blblk + (size_t)(p * 32 + srow) * ldb + skg);
    }

    f32x4 acc[4][4] = {};
    const int nk = Kd / BK;

    for (int t = 0; t < nk; ++t) {
        __syncthreads();
        #pragma unroll
        for (int p = 0; p < 4; ++p) {
            ushort4 h, l;
            split2(pa[p].x, h.x, l.x); split2(pa[p].y, h.y, l.y);
            split2(pa[p].z, h.z, l.z); split2(pa[p].w, h.w, l.w);
            *(ushort4*)(&Ah[(p * 32 + srow) * PADK + skg]) = h;
            *(ushort4*)(&Al[(p * 32 + srow) * PADK + skg]) = l;
            *(ushort4*)(&Bh[(p * 32 + srow) * PADK + skg]) = pbh[p];
            *(ushort4*)(&Bl[(p * 32 + srow) * PADK + skg]) = pbl[p];
        }
        __syncthreads();
        if (t + 1 < nk) {
            const int kb = (t + 1) * BK + skg;
            #pragma unroll
            for (int p = 0; p < 4; ++p) {
                pa[p]  = *(const float4*)(Ablk + (size_t)(p * 32 + srow) * lda + kb);
                pbh[p] = *(const ushort4*)(Bhblk + (size_t)(p * 32 + srow) * ldb + kb);
                pbl[p] = *(const ushort4*)(Blblk + (size_t)(p * 32 + srow) * ldb + kb);
            }
        }
        bf16x8 afh[4], afl[4];
        #pragma unroll
        for (int i = 0; i < 4; ++i) {
            afh[i] = *(const bf16x8*)(&Ah[(wr * 64 + i * 16 + lrow) * PADK + lkg * 8]);
            afl[i] = *(const bf16x8*)(&Al[(wr * 64 + i * 16 + lrow) * PADK + lkg * 8]);
        }
        #pragma unroll
        for (int j = 0; j < 4; ++j) {
            const bf16x8 bh = *(const bf16x8*)(&Bh[(wc * 64 + j * 16 + lrow) * PADK + lkg * 8]);
            const bf16x8 bl = *(const bf16x8*)(&Bl[(wc * 64 + j * 16 + lrow) * PADK + lkg * 8]);
            #pragma unroll
            for (int i = 0; i < 4; ++i) {
                acc[i][j] = __builtin_amdgcn_mfma_f32_16x16x32_bf16(afh[i], bh, acc[i][j], 0, 0, 0);
                acc[i][j] = __builtin_amdgcn_mfma_f32_16x16x32_bf16(afl[i], bh, acc[i][j], 0, 0, 0);
                acc[i][j] = __builtin_amdgcn_mfma_f32_16x16x32_bf16(afh[i], bl, acc[i][j], 0, 0, 0);
            }
        }
    }

    #pragma unroll
    for (int i = 0; i < 4; ++i) {
        #pragma unroll
        for (int r = 0; r < 4; ++r) {
            const int row = m0 + wr * 64 + i * 16 + lkg * 4 + r;
            #pragma unroll
            for (int j = 0; j < 4; ++j) {
                const int col = n0 + wc * 64 + j * 16 + lrow;
                const float bj = bias ? bias[col] : 0.0f;
                const float vres = acc[i][j][r] + bj;
                float* op = out + (size_t)row * ldo + col;
                if (MODE == 0) *op = vres;
                else *op = *op + vres;
            }
        }
    }
}

// ---------------- fast bf16 GEMM, pre-converted A (and optionally B), reg-staged ----------------
template<int MODE, bool SWZ, bool OUTBF, bool BBF>
__global__ __launch_bounds__(256)
void gemm_fastw_kernel(int Kd,
                       const unsigned short* __restrict__ A, int lda,
                       const void* __restrict__ Bv, int ldb,
                       const float* __restrict__ bias,
                       void* __restrict__ outv, int ldo,
                       const int* __restrict__ rowmeta,
                       size_t bstride, int biasstride)
{
    __shared__ short Ah[BM * PADK];
    __shared__ short Bh[BN * PADK];

    int bx = blockIdx.x, by = blockIdx.y;
    if constexpr (SWZ) {
        const int nwg = gridDim.x * gridDim.y;
        const int chunk = nwg >> 3;
        const int flat = by * gridDim.x + bx;
        const int newid = (flat & 7) * chunk + (flat >> 3);
        by = newid % gridDim.y;
        bx = newid / gridDim.y;
    }

    const float* Bf = (const float*)Bv;
    const unsigned short* Bb = (const unsigned short*)Bv;
    float* outf = (float*)outv;
    unsigned short* outb = (unsigned short*)outv;

    int roff = 0;
    if (rowmeta) {
        const int ee = blockIdx.z;
        const int rcnt = rowmeta[2 * ee + 1];
        if ((int)(by * BM) >= rcnt) return;
        roff = rowmeta[2 * ee];
        if (BBF) Bb += (size_t)ee * bstride; else Bf += (size_t)ee * bstride;
        if (bias) bias += (size_t)ee * biasstride;
    }

    const int tid = threadIdx.x;
    const int m0 = roff + by * BM;
    const int n0 = bx * BN;
    const int w = tid >> 6, lane = tid & 63;
    const int wr = w >> 1, wc = w & 1;
    const int lrow = lane & 15, lkg = lane >> 4;
    const int srow = tid >> 3, skg = (tid & 7) * 4;

    const unsigned short* Ablk = A + (size_t)m0 * lda;
    const float* Bfblk = Bf + (size_t)n0 * ldb;
    const unsigned short* Bbblk = Bb + (size_t)n0 * ldb;

    ushort4 pa[4];
    ushort4 pbb[4];
    float4  pbf[4];
    #pragma unroll
    for (int p = 0; p < 4; ++p) {
        pa[p] = *(const ushort4*)(Ablk + (size_t)(p * 32 + srow) * lda + skg);
        if constexpr (BBF) pbb[p] = *(const ushort4*)(Bbblk + (size_t)(p * 32 + srow) * ldb + skg);
        else               pbf[p] = *(const float4*)(Bfblk + (size_t)(p * 32 + srow) * ldb + skg);
    }

    f32x4 acc[4][4] = {};
    const int nk = Kd / BK;

    for (int t = 0; t < nk; ++t) {
        __syncthreads();
        #pragma unroll
        for (int p = 0; p < 4; ++p) {
            *(ushort4*)(&Ah[(p * 32 + srow) * PADK + skg]) = pa[p];
            *(ushort4*)(&Bh[(p * 32 + srow) * PADK + skg]) = BBF ? pbb[p] : cvt4(pbf[p]);
        }
        __syncthreads();
        if (t + 1 < nk) {
            const int kb = (t + 1) * BK + skg;
            #pragma unroll
            for (int p = 0; p < 4; ++p) {
                pa[p] = *(const ushort4*)(Ablk + (size_t)(p * 32 + srow) * lda + kb);
                if constexpr (BBF) pbb[p] = *(const ushort4*)(Bbblk + (size_t)(p * 32 + srow) * ldb + kb);
                else               pbf[p] = *(const float4*)(Bfblk + (size_t)(p * 32 + srow) * ldb + kb);
            }
        }
        bf16x8 af[4];
        #pragma unroll
        for (int i = 0; i < 4; ++i)
            af[i] = *(const bf16x8*)(&Ah[(wr * 64 + i * 16 + lrow) * PADK + lkg * 8]);
        #pragma unroll
        for (int j = 0; j < 4; ++j) {
            const bf16x8 bh = *(const bf16x8*)(&Bh[(wc * 64 + j * 16 + lrow) * PADK + lkg * 8]);
            #pragma unroll
            for (int i = 0; i < 4; ++i)
                acc[i][j] = __builtin_amdgcn_mfma_f32_16x16x32_bf16(af[i], bh, acc[i][j], 0, 0, 0);
        }
    }

    #pragma unroll
    for (int i = 0; i < 4; ++i) {
        #pragma unroll
        for (int r = 0; r < 4; ++r) {
            const int row = m0 + wr * 64 + i * 16 + lkg * 4 + r;
            #pragma unroll
            for (int j = 0; j < 4; ++j) {
                const int col = n0 + wc * 64 + j * 16 + lrow;
                const float bj = bias ? bias[col] : 0.0f;
                float vres = acc[i][j][r] + bj;
                if (MODE == 2) vres = fmaxf(vres, 0.0f);
                if constexpr (OUTBF) outb[(size_t)row * ldo + col] = f2bf(vres);
                else                 outf[(size_t)row * ldo + col] = vres;
            }
        }
    }
}

// ---------------- fast bf16 GEMM with global_load_lds staging (m97 structure) ----------------
// A,B bf16 [*,K] row-major; out fp32 = acc + bias. Linear LDS [128][32].
template<bool SWZ>
__global__ __launch_bounds__(256)
void gemm_lds_kernel(int Kd,
                     const unsigned short* __restrict__ A, int lda,
                     const unsigned short* __restrict__ B, int ldb,
                     const float* __restrict__ bias,
                     float* __restrict__ out, int ldo)
{
    __shared__ unsigned short Asl[BM * BK];   // 8 KB
    __shared__ unsigned short Bsl[BN * BK];   // 8 KB

    int bx = blockIdx.x, by = blockIdx.y;
    if constexpr (SWZ) {
        const int nwg = gridDim.x * gridDim.y;
        const int chunk = nwg >> 3;
        const int flat = by * gridDim.x + bx;
        const int newid = (flat & 7) * chunk + (flat >> 3);
        by = newid % gridDim.y;
        bx = newid / gridDim.y;
    }

    const int tid = threadIdx.x;
    const int m0 = by * BM;
    const int n0 = bx * BN;
    const int w = tid >> 6, lane = tid & 63;
    const int wr = w >> 1, wc = w & 1;
    const int lrow = lane & 15, lkg = lane >> 4;
    // gload mapping: lane i covers row (i>>2), elements (i&3)*8 within a 16-row chunk
    const int grow = lane >> 2, gcol = (lane & 3) * 8;

    const unsigned short* Ablk = A + (size_t)m0 * lda;
    const unsigned short* Bblk = B + (size_t)n0 * ldb;

    f32x4 acc[4][4] = {};
    const int nk = Kd / BK;

    for (int t = 0; t < nk; ++t) {
        const int k0 = t * BK;
        __syncthreads();   // previous tile consumed
        #pragma unroll
        for (int j = 0; j < 2; ++j) {
            const int rbase = w * 32 + j * 16;
            gload16(Ablk + (size_t)(rbase + grow) * lda + k0 + gcol, Asl + rbase * BK);
            gload16(Bblk + (size_t)(rbase + grow) * ldb + k0 + gcol, Bsl + rbase * BK);
        }
        __syncthreads();   // vmcnt(0) drained by compiler before barrier

        bf16x8 af[4];
        #pragma unroll
        for (int i = 0; i < 4; ++i)
            af[i] = *(const bf16x8*)(Asl + (wr * 64 + i * 16 + lrow) * BK + lkg * 8);
        #pragma unroll
        for (int j = 0; j < 4; ++j) {
            const bf16x8 bh = *(const bf16x8*)(Bsl + (wc * 64 + j * 16 + lrow) * BK + lkg * 8);
            #pragma unroll
            for (int i = 0; i < 4; ++i)
                acc[i][j] = __builtin_amdgcn_mfma_f32_16x16x32_bf16(af[i], bh, acc[i][j], 0, 0, 0);
        }
    }

    #pragma unroll
    for (int i = 0; i < 4; ++i) {
        #pragma unroll
        for (int r = 0; r < 4; ++r) {
            const int row = m0 + wr * 64 + i * 16 + lkg * 4 + r;
            #pragma unroll
            for (int j = 0; j < 4; ++j) {
                const int col = n0 + wc * 64 + j * 16 + lrow;
                const float bj = bias ? bias[col] : 0.0f;
                out[(size_t)row * ldo + col] = acc[i][j][r] + bj;
            }
        }
    }
}

// ---------------- MFMA flash attention, split-precision (fp32-grade) ----------------
#define QBLK 64
#define KVBLK 64

__global__ __launch_bounds__(256)
void attn_mfma_kernel(const float* __restrict__ qkv, float* __restrict__ o)
{
    __shared__ short Kh[2][KVBLK][PADK];
    __shared__ short Kl[2][KVBLK][PADK];
    __shared__ short Vh[2][HSD][PADK];
    __shared__ short Vl[2][HSD][PADK];
    __shared__ short Ph[4][2][16][PADK];
    __shared__ short Pl[4][2][16][PADK];

    const int t0 = blockIdx.x * QBLK;
    const int bh = blockIdx.y;
    const int b = bh / HCNT, hh = bh % HCNT;
    const size_t baseq = (size_t)b * TT * QKVLD + (size_t)hh * HSD;
    const size_t obase = (size_t)b * TT * CDIM + (size_t)hh * HSD;
    const float* q = qkv + baseq;
    const float* k = qkv + baseq + CDIM;
    const float* v = qkv + baseq + 2 * CDIM;
    const int tid = threadIdx.x;
    const int w = tid >> 6, lane = tid & 63;
    const int lrow = lane & 15, lkg = lane >> 4;
    const float sscale = rsqrtf((float)CDIM);

    bf16x8 qh[2], ql[2];
    {
        const float* qr = q + (size_t)(t0 + w * 16 + lrow) * QKVLD;
        #pragma unroll
        for (int ks = 0; ks < 2; ++ks) {
            #pragma unroll
            for (int j = 0; j < 8; ++j) {
                unsigned short h, l;
                split2(qr[ks * 32 + lkg * 8 + j], h, l);
                qh[ks][j] = (short)h;
                ql[ks][j] = (short)l;
            }
        }
    }

    f32x4 oacc[4] = {};
    float m_[4], l_[4];
    #pragma unroll
    for (int rr = 0; rr < 4; ++rr) { m_[rr] = -1e30f; l_[rr] = 0.0f; }

    for (int s0 = 0; s0 <= t0 + QBLK - 1; s0 += KVBLK) {
        __syncthreads();
        {
            const int srow = tid >> 3, skg = (tid & 7) * 4;
            #pragma unroll
            for (int p = 0; p < 2; ++p) {
                const float* krow = k + (size_t)(s0 + p * 32 + srow) * QKVLD;
                #pragma unroll
                for (int ks = 0; ks < 2; ++ks) {
                    float4 a = *(const float4*)(krow + ks * 32 + skg);
                    ushort4 h, l;
                    split2(a.x, h.x, l.x); split2(a.y, h.y, l.y);
                    split2(a.z, h.z, l.z); split2(a.w, h.w, l.w);
                    *(ushort4*)(&Kh[ks][p * 32 + srow][skg]) = h;
                    *(ushort4*)(&Kl[ks][p * 32 + srow][skg]) = l;
                }
            }
            const int key = tid & 63, dg = (tid >> 6) * 16;
            const float* vrow = v + (size_t)(s0 + key) * QKVLD + dg;
            const int kst = key >> 5, ko = key & 31;
            #pragma unroll
            for (int dd = 0; dd < 16; dd += 4) {
                float4 a = *(const float4*)(vrow + dd);
                unsigned short h, l;
                split2(a.x, h, l); Vh[kst][dg + dd + 0][ko] = h; Vl[kst][dg + dd + 0][ko] = l;
                split2(a.y, h, l); Vh[kst][dg + dd + 1][ko] = h; Vl[kst][dg + dd + 1][ko] = l;
                split2(a.z, h, l); Vh[kst][dg + dd + 2][ko] = h; Vl[kst][dg + dd + 2][ko] = l;
                split2(a.w, h, l); Vh[kst][dg + dd + 3][ko] = h; Vl[kst][dg + dd + 3][ko] = l;
            }
        }
        __syncthreads();

        f32x4 sacc[4] = {};
        #pragma unroll
        for (int j = 0; j < 4; ++j) {
            #pragma unroll
            for (int ks = 0; ks < 2; ++ks) {
                const bf16x8 bh = *(const bf16x8*)(&Kh[ks][j * 16 + lrow][lkg * 8]);
                const bf16x8 bl = *(const bf16x8*)(&Kl[ks][j * 16 + lrow][lkg * 8]);
                sacc[j] = __builtin_amdgcn_mfma_f32_16x16x32_bf16(qh[ks], bh, sacc[j], 0, 0, 0);
                sacc[j] = __builtin_amdgcn_mfma_f32_16x16x32_bf16(ql[ks], bh, sacc[j], 0, 0, 0);
                sacc[j] = __builtin_amdgcn_mfma_f32_16x16x32_bf16(qh[ks], bl, sacc[j], 0, 0, 0);
            }
        }

        #pragma unroll
        for (int rr = 0; rr < 4; ++rr) {
            const int qi = t0 + w * 16 + lkg * 4 + rr;
            float pv[4];
            float mx = -1e30f;
            #pragma unroll
            for (int j = 0; j < 4; ++j) {
                float s = sacc[j][rr] * sscale;
                if (s0 + j * 16 + lrow > qi) s = -1e30f;
                pv[j] = s;
                mx = fmaxf(mx, s);
            }
            #pragma unroll
            for (int off = 1; off < 16; off <<= 1) mx = fmaxf(mx, __shfl_xor(mx, off));
            const float mnew = fmaxf(m_[rr], mx);
            const float corr = __expf(m_[rr] - mnew);
            float ps = 0.0f;
            #pragma unroll
            for (int j = 0; j < 4; ++j) { pv[j] = __expf(pv[j] - mnew); ps += pv[j]; }
            #pragma unroll
            for (int off = 1; off < 16; off <<= 1) ps += __shfl_xor(ps, off);
            l_[rr] = l_[rr] * corr + ps;
            m_[rr] = mnew;
            #pragma unroll
            for (int jd = 0; jd < 4; ++jd) oacc[jd][rr] *= corr;
            #pragma unroll
            for (int j = 0; j < 4; ++j) {
                unsigned short h, l;
                split2(pv[j], h, l);
                const int key = j * 16 + lrow;
                Ph[w][key >> 5][lkg * 4 + rr][key & 31] = h;
                Pl[w][key >> 5][lkg * 4 + rr][key & 31] = l;
            }
        }

        #pragma unroll
        for (int ks = 0; ks < 2; ++ks) {
            const bf16x8 ah = *(const bf16x8*)(&Ph[w][ks][lrow][lkg * 8]);
            const bf16x8 al = *(const bf16x8*)(&Pl[w][ks][lrow][lkg * 8]);
            #pragma unroll
            for (int jd = 0; jd < 4; ++jd) {
                const bf16x8 bh = *(const bf16x8*)(&Vh[ks][jd * 16 + lrow][lkg * 8]);
                const bf16x8 bl = *(const bf16x8*)(&Vl[ks][jd * 16 + lrow][lkg * 8]);
                oacc[jd] = __builtin_amdgcn_mfma_f32_16x16x32_bf16(ah, bh, oacc[jd], 0, 0, 0);
                oacc[jd] = __builtin_amdgcn_mfma_f32_16x16x32_bf16(al, bh, oacc[jd], 0, 0, 0);
                oacc[jd] = __builtin_amdgcn_mfma_f32_16x16x32_bf16(ah, bl, oacc[jd], 0, 0, 0);
            }
        }
    }

    #pragma unroll
    for (int rr = 0; rr < 4; ++rr) {
        const int qi = t0 + w * 16 + lkg * 4 + rr;
        const float invl = 1.0f / l_[rr];
        float* orow = o + obase + (size_t)qi * CDIM;
        #pragma unroll
        for (int jd = 0; jd < 4; ++jd)
            orow[jd * 16 + lrow] = oacc[jd][rr] * invl;
    }
}

// ---------------- gate: logits + top-2 + softmax -> sel[N], wts[N] ----------------
__global__ __launch_bounds__(256)
void gate_kernel(const float* __restrict__ h2, const float* __restrict__ gw,
                 int2* __restrict__ sel, float2* __restrict__ wts)
{
    __shared__ float gws[ECNT * CDIM];
    int tid = threadIdx.x;
    for (int i = tid; i < ECNT * CDIM; i += 256) gws[i] = gw[i];
    __syncthreads();
    int t = blockIdx.x * 256 + tid;
    const float* hr = h2 + (size_t)t * CDIM;
    float g[ECNT] = {};
    for (int c = 0; c < CDIM; ++c) {
        float hv = hr[c];
        #pragma unroll
        for (int e = 0; e < ECNT; ++e) g[e] = fmaf(hv, gws[e * CDIM + c], g[e]);
    }
    int e0 = 0; float g0 = g[0];
    #pragma unroll
    for (int e = 1; e < ECNT; ++e) if (g[e] > g0) { g0 = g[e]; e0 = e; }
    int e1 = -1; float g1 = -1e30f;
    #pragma unroll
    for (int e = 0; e < ECNT; ++e) if (e != e0 && g[e] > g1) { g1 = g[e]; e1 = e; }
    float z = __expf(g1 - g0);          // <= 1
    float w0 = 1.0f / (1.0f + z);
    sel[t] = make_int2(e0, e1);
    wts[t] = make_float2(w0, 1.0f - w0);
}

// ---------------- routing: build expert-grouped permutation (single block) ----------------
__global__ __launch_bounds__(256)
void route_kernel(const int2* __restrict__ sel, int* __restrict__ perm,
                  int* __restrict__ tokpos, int* __restrict__ meta)
{
    __shared__ int cnt[ECNT], off[ECNT], cur[ECNT];
    const int tid = threadIdx.x;
    if (tid < ECNT) cnt[tid] = 0;
    __syncthreads();
    for (int t = tid; t < NTOK; t += 256) {
        atomicAdd(&cnt[sel[t].x], 1);
        atomicAdd(&cnt[sel[t].y], 1);
    }
    __syncthreads();
    if (tid == 0) {
        int run = 0;
        for (int e = 0; e < ECNT; ++e) {
            off[e] = run; cur[e] = 0;
            int pc = (cnt[e] + BM - 1) / BM * BM;
            meta[2 * e] = run; meta[2 * e + 1] = pc;
            run += pc;
        }
    }
    __syncthreads();
    for (int p = tid; p < TOTCAP; p += 256) perm[p] = 0;   // pad slots -> token 0
    __syncthreads();
    for (int t = tid; t < NTOK; t += 256) {
        int2 s = sel[t];
        int p0 = atomicAdd(&cur[s.x], 1); perm[off[s.x] + p0] = t; tokpos[2 * t]     = off[s.x] + p0;
        int p1 = atomicAdd(&cur[s.y], 1); perm[off[s.y] + p1] = t; tokpos[2 * t + 1] = off[s.y] + p1;
    }
}

// ---------------- gather h2 rows into expert order ----------------
__global__ __launch_bounds__(256)
void gather_kernel(const float* __restrict__ h2, const int* __restrict__ perm,
                   float* __restrict__ xg)
{
    int i = blockIdx.x * 256 + threadIdx.x;   // TOTCAP*CDIM
    int c = i % CDIM, p = i / CDIM;
    xg[i] = h2[(size_t)perm[p] * CDIM + c];
}

__global__ __launch_bounds__(256)
void gather_bf16_kernel(const float* __restrict__ h2, const int* __restrict__ perm,
                        unsigned short* __restrict__ xg)
{
    int i = blockIdx.x * 256 + threadIdx.x;   // TOTCAP*CDIM
    int c = i % CDIM, p = i / CDIM;
    xg[i] = f2bf(h2[(size_t)perm[p] * CDIM + c]);
}

// ---------------- combine: x += w0*y[pos0] + w1*y[pos1] ----------------
__global__ __launch_bounds__(256)
void combine_kernel(const float* __restrict__ y, const int* __restrict__ tokpos,
                    const float2* __restrict__ wts, float* __restrict__ x)
{
    int i = blockIdx.x * 256 + threadIdx.x;   // NTOK*CDIM
    int c = i % CDIM, t = i / CDIM;
    float2 wv = wts[t];
    x[i] += wv.x * y[(size_t)tokpos[2 * t] * CDIM + c]
          + wv.y * y[(size_t)tokpos[2 * t + 1] * CDIM + c];
}

// ---------------- per-row cross-entropy ----------------
__global__ __launch_bounds__(256)
void loss_row_kernel(const float* __restrict__ logits, const int* __restrict__ tgt,
                     float* __restrict__ lrow)
{
    int row = blockIdx.x;
    const float* lr = logits + (size_t)row * VOC;
    int tid = threadIdx.x, w = tid >> 6, lane = tid & 63;
    __shared__ float red[4];
    float mx = -1e30f;
    for (int i = tid; i < VOC; i += 256) mx = fmaxf(mx, lr[i]);
    mx = wave_max(mx);
    if (lane == 0) red[w] = mx;
    __syncthreads();
    mx = fmaxf(fmaxf(red[0], red[1]), fmaxf(red[2], red[3]));
    __syncthreads();
    float se = 0.0f;
    for (int i = tid; i < VOC; i += 256) se += expf(lr[i] - mx);
    se = wave_sum(se);
    if (lane == 0) red[w] = se;
    __syncthreads();
    if (tid == 0) {
        float lse = mx + logf(red[0] + red[1] + red[2] + red[3]);
        lrow[row] = lse - lr[tgt[row]];
    }
}

__global__ __launch_bounds__(256)
void loss_reduce_kernel(const float* __restrict__ lrow, float* __restrict__ out)
{
    int tid = threadIdx.x, w = tid >> 6, lane = tid & 63;
    float s = 0.0f;
    for (int i = tid; i < NTOK; i += 256) s += lrow[i];
    s = wave_sum(s);
    __shared__ float red[4];
    if (lane == 0) red[w] = s;
    __syncthreads();
    if (tid == 0) out[0] = (red[0] + red[1] + red[2] + red[3]) * (1.0f / NTOK);
}

// ---------------- launch ----------------
extern "C" void kernel_launch(void* const* d_in, const int* in_sizes, int n_in,
                              void* d_out, int out_size, void* d_ws, size_t ws_size,
                              hipStream_t stream)
{
    const int*   idx     = (const int*)d_in[0];
    const int*   targets = (const int*)d_in[1];
    const float* tok_emb = (const float*)d_in[2];
    const float* pos_emb = (const float*)d_in[3];
    const float* ln1_s   = (const float*)d_in[4];
    const float* ln1_b   = (const float*)d_in[5];
    const float* wq      = (const float*)d_in[6];
    const float* wk      = (const float*)d_in[7];
    const float* wv      = (const float*)d_in[8];
    const float* wo      = (const float*)d_in[9];
    const float* bo      = (const float*)d_in[10];
    const float* ln2_s   = (const float*)d_in[11];
    const float* ln2_b   = (const float*)d_in[12];
    const float* gate_w  = (const float*)d_in[13];
    const float* w1      = (const float*)d_in[14];
    const float* b1      = (const float*)d_in[15];
    const float* w2      = (const float*)d_in[16];
    const float* b2      = (const float*)d_in[17];
    const float* lm_w    = (const float*)d_in[18];
    const float* lm_b    = (const float*)d_in[19];
    float* out = (float*)d_out;

    // ws layout (pre-split attn weights replace old fp32 wp)
    unsigned short* wph = (unsigned short*)d_ws;                     // 3*L*C*C
    unsigned short* wpl = wph + (size_t)3 * LCNT * CDIM * CDIM;      // 3*L*C*C
    unsigned short* woh = wpl + (size_t)3 * LCNT * CDIM * CDIM;      // L*C*C
    unsigned short* wol = woh + (size_t)LCNT * CDIM * CDIM;          // L*C*C
    float* x    = (float*)(wol + (size_t)LCNT * CDIM * CDIM);
    float* hbuf = x    + (size_t)NTOK * CDIM;        // LN1 out, attn out
    float* qkv  = hbuf + (size_t)NTOK * CDIM;        // [NTOK][2304]; h2/ybuf overlay after attn
    float* xg   = qkv  + (size_t)NTOK * QKVLD;       // TOTCAP*C gathered h2 (fp32 l0 / bf16 l1)
    float* hid  = xg   + (size_t)TOTCAP * CDIM;      // TOTCAP*FF fp32 (l0); bf16 hid + lm_w_bf overlay (l1/head)
    float* lrow = hid  + (size_t)TOTCAP * FF;        // NTOK
    float2* wts = (float2*)(lrow + NTOK);            // NTOK float2
    int2*  sel  = (int2*)(wts + NTOK);               // NTOK int2
    int*   perm = (int*)(sel + NTOK);                // TOTCAP
    int*  tokpos= perm + TOTCAP;                     // 2*NTOK
    int*   meta = tokpos + 2 * NTOK;                 // 16
    unsigned short* x_bf = (unsigned short*)(meta + 16);  // NTOK*C bf16

    unsigned short* xg_bf  = (unsigned short*)xg;    // aliases xg (l1 only)
    unsigned short* hid_bf = (unsigned short*)hid;   // aliases hid (l1 only)
    unsigned short* lmw_bf = (unsigned short*)hid;   // aliases hid (after l1 experts done)

    dim3 blk(256);

    repack_kernel<<<(3 * LCNT * CDIM * CDIM) / 256, blk, 0, stream>>>(wq, wk, wv, wph, wpl);
    splitw_kernel<<<1024, blk, 0, stream>>>(wo, woh, wol, LCNT * CDIM * CDIM / 4);
    embed_kernel<<<(NTOK * CDIM) / 256, blk, 0, stream>>>(idx, tok_emb, pos_emb, x);

    for (int l = 0; l < LCNT; ++l) {
        ln_kernel<<<NTOK, blk, 0, stream>>>(x, ln1_s + (size_t)l * CDIM, ln1_b + (size_t)l * CDIM, hbuf);

        // fused QKV projection (split, pre-split B): [NTOK,768] x [2304,768]^T -> [NTOK,2304]
        gemm_splitpb_kernel<0><<<dim3(QKVLD / BN, NTOK / BM), blk, 0, stream>>>(
            CDIM, hbuf, CDIM, wph + (size_t)l * 3 * CDIM * CDIM, wpl + (size_t)l * 3 * CDIM * CDIM,
            CDIM, nullptr, qkv, QKVLD);

        attn_mfma_kernel<<<dim3(TT / QBLK, BB * HCNT), blk, 0, stream>>>(qkv, hbuf);

        gemm_splitpb_kernel<1><<<dim3(CDIM / BN, NTOK / BM), blk, 0, stream>>>(
            CDIM, hbuf, CDIM, woh + (size_t)l * CDIM * CDIM, wol + (size_t)l * CDIM * CDIM,
            CDIM, bo + (size_t)l * CDIM, x, CDIM);

        // --- MoE: gate -> route -> gather -> expert GEMMs -> combine ---
        float* h2 = qkv;       // attn consumed qkv; reuse as compact [NTOK][C]
        float* ybuf = qkv;     // w2 output overlays h2 after gather
        ln_kernel<<<NTOK, blk, 0, stream>>>(x, ln2_s + (size_t)l * CDIM, ln2_b + (size_t)l * CDIM, h2);
        gate_kernel<<<NTOK / 256, blk, 0, stream>>>(h2, gate_w + (size_t)l * ECNT * CDIM, sel, wts);
        route_kernel<<<1, blk, 0, stream>>>(sel, perm, tokpos, meta);

        const float* w1l = w1 + (size_t)l * ECNT * FF * CDIM;
        const float* b1l = b1 + (size_t)l * ECNT * FF;
        const float* w2l = w2 + (size_t)l * ECNT * CDIM * FF;
        const float* b2l = b2 + (size_t)l * ECNT * CDIM;
        if (l == 0) {   // feeds next layer's router -> keep fp32-grade (split 3-MFMA)
            gather_kernel<<<(TOTCAP * CDIM) / 256, blk, 0, stream>>>(h2, perm, xg);
            gemm_bf16_kernel<2, true><<<dim3(FF / BN, TOTCAP / BM, ECNT), blk, 0, stream>>>(
                CDIM, xg, CDIM, w1l, CDIM, b1l, hid, FF, meta, (size_t)FF * CDIM, FF);
            gemm_bf16_kernel<0, true><<<dim3(CDIM / BN, TOTCAP / BM, ECNT), blk, 0, stream>>>(
                FF, hid, FF, w2l, FF, b2l, ybuf, CDIM, meta, (size_t)CDIM * FF, CDIM);
        } else {        // feeds only logits -> fast 1-MFMA, bf16 activations end-to-end
            gather_bf16_kernel<<<(TOTCAP * CDIM) / 256, blk, 0, stream>>>(h2, perm, xg_bf);
            gemm_fastw_kernel<2, false, true, false><<<dim3(FF / BN, TOTCAP / BM, ECNT), blk, 0, stream>>>(
                CDIM, xg_bf, CDIM, w1l, CDIM, b1l, hid_bf, FF, meta, (size_t)FF * CDIM, FF);
            gemm_fastw_kernel<0, false, false, false><<<dim3(CDIM / BN, TOTCAP / BM, ECNT), blk, 0, stream>>>(
                FF, hid_bf, FF, w2l, FF, b2l, ybuf, CDIM, meta, (size_t)CDIM * FF, CDIM);
        }
        combine_kernel<<<(NTOK * CDIM) / 256, blk, 0, stream>>>(ybuf, tokpos, wts, x);
    }

    // pre-convert LM head operands to bf16 (hid region is dead now)
    cvt_bf16_kernel<<<2048, blk, 0, stream>>>(lm_w, lmw_bf, VOC * CDIM / 4);
    cvt_bf16_kernel<<<512, blk, 0, stream>>>(x, x_bf, NTOK * CDIM / 4);

    // LM head: bf16 x bf16 via global_load_lds staging, XCD-aware m-fastest swizzle
    gemm_lds_kernel<true><<<dim3(VOC / BN, NTOK / BM), blk, 0, stream>>>(
        CDIM, x_bf, CDIM, lmw_bf, CDIM, lm_b, out, VOC);

    loss_row_kernel<<<NTOK, blk, 0, stream>>>(out, targets, lrow);
    loss_reduce_kernel<<<1, blk, 0, stream>>>(lrow, out + (size_t)NTOK * VOC);
}

// Round 10
// 1371.595 us; speedup vs baseline: 9.3260x; 1.0270x over previous
//
#include <hip/hip_runtime.h>
#include <hip/hip_bf16.h>

// Problem constants (from reference)
#define LCNT 2
#define HCNT 12
#define CDIM 768
#define HSD  64
#define ECNT 8
#define VOC  32000
#define BB   2
#define TT   1024
#define NTOK 2048   // B*T
#define FF   3072   // 4*C
#define QKVLD 2304  // 3*C
#define TOTCAP 5120 // 2*NTOK + 8*128 padding capacity
#define SKN  4      // split-K factor for l0 w2

typedef __attribute__((ext_vector_type(8))) short bf16x8;
typedef __attribute__((ext_vector_type(4))) float f32x4;

// ---------------- helpers ----------------
__device__ __forceinline__ float wave_sum(float v) {
    #pragma unroll
    for (int off = 32; off; off >>= 1) v += __shfl_xor(v, off);
    return v;
}
__device__ __forceinline__ float wave_max(float v) {
    #pragma unroll
    for (int off = 32; off; off >>= 1) v = fmaxf(v, __shfl_xor(v, off));
    return v;
}
__device__ __forceinline__ unsigned short f2bf(float f) {
    unsigned int u = __float_as_uint(f);
    unsigned int r = (u + 0x7FFFu + ((u >> 16) & 1u)) >> 16;
    return (unsigned short)r;
}
__device__ __forceinline__ float bf2f(unsigned short h) {
    return __uint_as_float((unsigned int)h << 16);
}
__device__ __forceinline__ void split2(float a, unsigned short& h, unsigned short& l) {
    h = f2bf(a);
    l = f2bf(a - bf2f(h));
}
__device__ __forceinline__ ushort4 cvt4(float4 v) {
    ushort4 r;
    r.x = f2bf(v.x); r.y = f2bf(v.y); r.z = f2bf(v.z); r.w = f2bf(v.w);
    return r;
}
// async 16B global->LDS (dest = wave-uniform base + lane*16)
__device__ __forceinline__ void gload16(const void* g, void* l) {
    __builtin_amdgcn_global_load_lds(
        (const __attribute__((address_space(1))) unsigned int*)g,
        (__attribute__((address_space(3))) unsigned int*)l,
        16, 0, 0);
}

// ---------------- fp32 -> bf16 bulk convert ----------------
__global__ __launch_bounds__(256)
void cvt_bf16_kernel(const float* __restrict__ in, unsigned short* __restrict__ out, int n4)
{
    for (int i = blockIdx.x * 256 + threadIdx.x; i < n4; i += gridDim.x * 256) {
        float4 v = reinterpret_cast<const float4*>(in)[i];
        reinterpret_cast<ushort4*>(out)[i] = cvt4(v);
    }
}

// ---------------- fp32 -> split hi/lo bf16 bulk ----------------
__global__ __launch_bounds__(256)
void splitw_kernel(const float* __restrict__ in, unsigned short* __restrict__ oh,
                   unsigned short* __restrict__ ol, int n4)
{
    for (int i = blockIdx.x * 256 + threadIdx.x; i < n4; i += gridDim.x * 256) {
        float4 v = reinterpret_cast<const float4*>(in)[i];
        ushort4 h, l;
        split2(v.x, h.x, l.x); split2(v.y, h.y, l.y);
        split2(v.z, h.z, l.z); split2(v.w, h.w, l.w);
        reinterpret_cast<ushort4*>(oh)[i] = h;
        reinterpret_cast<ushort4*>(ol)[i] = l;
    }
}

// ---------------- embedding ----------------
__global__ __launch_bounds__(256)
void embed_kernel(const int* __restrict__ idx, const float* __restrict__ tok,
                  const float* __restrict__ pos, float* __restrict__ x)
{
    int i = blockIdx.x * 256 + threadIdx.x;      // N*C total
    int c = i % CDIM;
    int n = i / CDIM;
    int t = n % TT;
    x[i] = tok[(size_t)idx[n] * CDIM + c] + pos[(size_t)t * CDIM + c];
}

// ---------------- repack wq/wk/wv [L,H,C,HS] -> split hi/lo [l][w3*C + n][k] (fused B^T) ----------------
__global__ __launch_bounds__(256)
void repack_kernel(const float* __restrict__ wq, const float* __restrict__ wk,
                   const float* __restrict__ wv, unsigned short* __restrict__ wph,
                   unsigned short* __restrict__ wpl)
{
    int i = blockIdx.x * 256 + threadIdx.x;      // 3*L*C*C
    int kk = i % CDIM;
    int n  = (i / CDIM) % CDIM;
    int w3 = (i / (CDIM * CDIM)) % 3;
    int l  = i / (CDIM * CDIM * 3);
    const float* src = (w3 == 0) ? wq : (w3 == 1) ? wk : wv;
    int h = n / HSD, d = n % HSD;
    float v = src[((((size_t)l * HCNT + h) * CDIM) + kk) * HSD + d];
    unsigned short hh, ll;
    split2(v, hh, ll);
    size_t o = (((size_t)l * 3 + w3) * CDIM + n) * CDIM + kk;
    wph[o] = hh;
    wpl[o] = ll;
}

// ---------------- layernorm ----------------
__global__ __launch_bounds__(256)
void ln_kernel(const float* __restrict__ x, const float* __restrict__ sc,
               const float* __restrict__ bs, float* __restrict__ out)
{
    int row = blockIdx.x;
    const float* xr = x + (size_t)row * CDIM;
    float* orow = out + (size_t)row * CDIM;
    int tid = threadIdx.x;
    float v0 = xr[tid], v1 = xr[tid + 256], v2 = xr[tid + 512];
    float s1 = v0 + v1 + v2;
    float s2 = v0 * v0 + v1 * v1 + v2 * v2;
    s1 = wave_sum(s1);
    s2 = wave_sum(s2);
    __shared__ float r1[4], r2[4];
    int w = tid >> 6, lane = tid & 63;
    if (lane == 0) { r1[w] = s1; r2[w] = s2; }
    __syncthreads();
    float t1 = r1[0] + r1[1] + r1[2] + r1[3];
    float t2 = r2[0] + r2[1] + r2[2] + r2[3];
    float mu = t1 * (1.0f / CDIM);
    float var = t2 * (1.0f / CDIM) - mu * mu;
    float rstd = rsqrtf(var + 1e-5f);
    orow[tid]       = (v0 - mu) * rstd * sc[tid]       + bs[tid];
    orow[tid + 256] = (v1 - mu) * rstd * sc[tid + 256] + bs[tid + 256];
    orow[tid + 512] = (v2 - mu) * rstd * sc[tid + 512] + bs[tid + 512];
}

#define BM 128
#define BN 128
#define BK 32
#define PADK 40   // bf16 stride per row (80 B)

// ---------------- split-precision bf16 MFMA GEMM (fp32-grade, 3 MFMA) ----------------
// C[m,n] = sum_k A[m,k] * B[n,k]   (B row-major [N][K], i.e. B^T)
// MODE 0: out = acc + bias ; MODE 1: out += acc + bias ; MODE 2: out = relu(acc + bias)
template<int MODE, bool SPLIT>
__global__ __launch_bounds__(256)
void gemm_bf16_kernel(int Kd,
                      const float* __restrict__ A, int lda,
                      const float* __restrict__ B, int ldb,
                      const float* __restrict__ bias,
                      float* __restrict__ out, int ldo,
                      const int* __restrict__ rowmeta,
                      size_t bstride, int biasstride)
{
    __shared__ short Ah[BM * PADK];
    __shared__ short Bh[BN * PADK];
    __shared__ short Al[SPLIT ? BM * PADK : 2];
    __shared__ short Bl[SPLIT ? BN * PADK : 2];

    int roff = 0;
    if (rowmeta) {
        const int ee = blockIdx.z;
        const int rcnt = rowmeta[2 * ee + 1];
        if ((int)(blockIdx.y * BM) >= rcnt) return;
        roff = rowmeta[2 * ee];
        B += (size_t)ee * bstride;
        if (bias) bias += (size_t)ee * biasstride;
    }

    const int tid = threadIdx.x;
    const int m0 = roff + blockIdx.y * BM;
    const int n0 = blockIdx.x * BN;
    const int w = tid >> 6, lane = tid & 63;
    const int wr = w >> 1, wc = w & 1;          // wave tile (64x64)
    const int lrow = lane & 15, lkg = lane >> 4;
    const int srow = tid >> 3, skg = (tid & 7) * 4;

    const float* Ablk = A + (size_t)m0 * lda;
    const float* Bblk = B + (size_t)n0 * ldb;

    float4 pa[4], pb[4];
    #pragma unroll
    for (int p = 0; p < 4; ++p) {
        pa[p] = *(const float4*)(Ablk + (size_t)(p * 32 + srow) * lda + skg);
        pb[p] = *(const float4*)(Bblk + (size_t)(p * 32 + srow) * ldb + skg);
    }

    f32x4 acc[4][4] = {};
    const int nk = Kd / BK;

    for (int t = 0; t < nk; ++t) {
        __syncthreads();
        #pragma unroll
        for (int p = 0; p < 4; ++p) {
            if constexpr (SPLIT) {
                ushort4 h, l;
                split2(pa[p].x, h.x, l.x); split2(pa[p].y, h.y, l.y);
                split2(pa[p].z, h.z, l.z); split2(pa[p].w, h.w, l.w);
                *(ushort4*)(&Ah[(p * 32 + srow) * PADK + skg]) = h;
                *(ushort4*)(&Al[(p * 32 + srow) * PADK + skg]) = l;
                split2(pb[p].x, h.x, l.x); split2(pb[p].y, h.y, l.y);
                split2(pb[p].z, h.z, l.z); split2(pb[p].w, h.w, l.w);
                *(ushort4*)(&Bh[(p * 32 + srow) * PADK + skg]) = h;
                *(ushort4*)(&Bl[(p * 32 + srow) * PADK + skg]) = l;
            } else {
                *(ushort4*)(&Ah[(p * 32 + srow) * PADK + skg]) = cvt4(pa[p]);
                *(ushort4*)(&Bh[(p * 32 + srow) * PADK + skg]) = cvt4(pb[p]);
            }
        }
        __syncthreads();
        if (t + 1 < nk) {
            const int kb = (t + 1) * BK + skg;
            #pragma unroll
            for (int p = 0; p < 4; ++p) {
                pa[p] = *(const float4*)(Ablk + (size_t)(p * 32 + srow) * lda + kb);
                pb[p] = *(const float4*)(Bblk + (size_t)(p * 32 + srow) * ldb + kb);
            }
        }
        bf16x8 afh[4], afl[4];
        #pragma unroll
        for (int i = 0; i < 4; ++i) {
            afh[i] = *(const bf16x8*)(&Ah[(wr * 64 + i * 16 + lrow) * PADK + lkg * 8]);
            if constexpr (SPLIT)
                afl[i] = *(const bf16x8*)(&Al[(wr * 64 + i * 16 + lrow) * PADK + lkg * 8]);
        }
        #pragma unroll
        for (int j = 0; j < 4; ++j) {
            const bf16x8 bh = *(const bf16x8*)(&Bh[(wc * 64 + j * 16 + lrow) * PADK + lkg * 8]);
            if constexpr (SPLIT) {
                const bf16x8 bl = *(const bf16x8*)(&Bl[(wc * 64 + j * 16 + lrow) * PADK + lkg * 8]);
                #pragma unroll
                for (int i = 0; i < 4; ++i) {
                    acc[i][j] = __builtin_amdgcn_mfma_f32_16x16x32_bf16(afh[i], bh, acc[i][j], 0, 0, 0);
                    acc[i][j] = __builtin_amdgcn_mfma_f32_16x16x32_bf16(afl[i], bh, acc[i][j], 0, 0, 0);
                    acc[i][j] = __builtin_amdgcn_mfma_f32_16x16x32_bf16(afh[i], bl, acc[i][j], 0, 0, 0);
                }
            } else {
                #pragma unroll
                for (int i = 0; i < 4; ++i)
                    acc[i][j] = __builtin_amdgcn_mfma_f32_16x16x32_bf16(afh[i], bh, acc[i][j], 0, 0, 0);
            }
        }
    }

    #pragma unroll
    for (int i = 0; i < 4; ++i) {
        #pragma unroll
        for (int r = 0; r < 4; ++r) {
            const int row = m0 + wr * 64 + i * 16 + lkg * 4 + r;
            #pragma unroll
            for (int j = 0; j < 4; ++j) {
                const int col = n0 + wc * 64 + j * 16 + lrow;
                const float bj = bias ? bias[col] : 0.0f;
                const float vres = acc[i][j][r] + bj;
                float* op = out + (size_t)row * ldo + col;
                if (MODE == 0) *op = vres;
                else if (MODE == 1) *op = *op + vres;
                else *op = fmaxf(vres, 0.0f);
            }
        }
    }
}

// ---------------- split-K expert GEMM (split precision), partial outputs ----------------
// blockIdx.z = ee*SKN + kz; computes K chunk [kz*Kc,(kz+1)*Kc) into part[kz].
// bias added only for kz==0.
__global__ __launch_bounds__(256)
void gemm_sk_kernel(int Kc,
                    const float* __restrict__ A, int lda,
                    const float* __restrict__ B, int ldb,
                    const float* __restrict__ bias,
                    float* __restrict__ part, int ldo, size_t pstride,
                    const int* __restrict__ rowmeta,
                    size_t bstride, int biasstride)
{
    __shared__ short Ah[BM * PADK];
    __shared__ short Bh[BN * PADK];
    __shared__ short Al[BM * PADK];
    __shared__ short Bl[BN * PADK];

    const int zz = blockIdx.z;
    const int ee = zz / SKN, kz = zz % SKN;
    const int rcnt = rowmeta[2 * ee + 1];
    if ((int)(blockIdx.y * BM) >= rcnt) return;
    const int roff = rowmeta[2 * ee];
    const float* Bp = B + (size_t)ee * bstride + (size_t)kz * Kc;
    const float* Ap = A + (size_t)kz * Kc;
    const float* biasp = (kz == 0 && bias) ? bias + (size_t)ee * biasstride : nullptr;
    float* out = part + (size_t)kz * pstride;

    const int tid = threadIdx.x;
    const int m0 = roff + blockIdx.y * BM;
    const int n0 = blockIdx.x * BN;
    const int w = tid >> 6, lane = tid & 63;
    const int wr = w >> 1, wc = w & 1;
    const int lrow = lane & 15, lkg = lane >> 4;
    const int srow = tid >> 3, skg = (tid & 7) * 4;

    const float* Ablk = Ap + (size_t)m0 * lda;
    const float* Bblk = Bp + (size_t)n0 * ldb;

    float4 pa[4], pb[4];
    #pragma unroll
    for (int p = 0; p < 4; ++p) {
        pa[p] = *(const float4*)(Ablk + (size_t)(p * 32 + srow) * lda + skg);
        pb[p] = *(const float4*)(Bblk + (size_t)(p * 32 + srow) * ldb + skg);
    }

    f32x4 acc[4][4] = {};
    const int nk = Kc / BK;

    for (int t = 0; t < nk; ++t) {
        __syncthreads();
        #pragma unroll
        for (int p = 0; p < 4; ++p) {
            ushort4 h, l;
            split2(pa[p].x, h.x, l.x); split2(pa[p].y, h.y, l.y);
            split2(pa[p].z, h.z, l.z); split2(pa[p].w, h.w, l.w);
            *(ushort4*)(&Ah[(p * 32 + srow) * PADK + skg]) = h;
            *(ushort4*)(&Al[(p * 32 + srow) * PADK + skg]) = l;
            split2(pb[p].x, h.x, l.x); split2(pb[p].y, h.y, l.y);
            split2(pb[p].z, h.z, l.z); split2(pb[p].w, h.w, l.w);
            *(ushort4*)(&Bh[(p * 32 + srow) * PADK + skg]) = h;
            *(ushort4*)(&Bl[(p * 32 + srow) * PADK + skg]) = l;
        }
        __syncthreads();
        if (t + 1 < nk) {
            const int kb = (t + 1) * BK + skg;
            #pragma unroll
            for (int p = 0; p < 4; ++p) {
                pa[p] = *(const float4*)(Ablk + (size_t)(p * 32 + srow) * lda + kb);
                pb[p] = *(const float4*)(Bblk + (size_t)(p * 32 + srow) * ldb + kb);
            }
        }
        bf16x8 afh[4], afl[4];
        #pragma unroll
        for (int i = 0; i < 4; ++i) {
            afh[i] = *(const bf16x8*)(&Ah[(wr * 64 + i * 16 + lrow) * PADK + lkg * 8]);
            afl[i] = *(const bf16x8*)(&Al[(wr * 64 + i * 16 + lrow) * PADK + lkg * 8]);
        }
        #pragma unroll
        for (int j = 0; j < 4; ++j) {
            const bf16x8 bh = *(const bf16x8*)(&Bh[(wc * 64 + j * 16 + lrow) * PADK + lkg * 8]);
            const bf16x8 bl = *(const bf16x8*)(&Bl[(wc * 64 + j * 16 + lrow) * PADK + lkg * 8]);
            #pragma unroll
            for (int i = 0; i < 4; ++i) {
                acc[i][j] = __builtin_amdgcn_mfma_f32_16x16x32_bf16(afh[i], bh, acc[i][j], 0, 0, 0);
                acc[i][j] = __builtin_amdgcn_mfma_f32_16x16x32_bf16(afl[i], bh, acc[i][j], 0, 0, 0);
                acc[i][j] = __builtin_amdgcn_mfma_f32_16x16x32_bf16(afh[i], bl, acc[i][j], 0, 0, 0);
            }
        }
    }

    #pragma unroll
    for (int i = 0; i < 4; ++i) {
        #pragma unroll
        for (int r = 0; r < 4; ++r) {
            const int row = m0 + wr * 64 + i * 16 + lkg * 4 + r;
            #pragma unroll
            for (int j = 0; j < 4; ++j) {
                const int col = n0 + wc * 64 + j * 16 + lrow;
                const float bj = biasp ? biasp[col] : 0.0f;
                out[(size_t)row * ldo + col] = acc[i][j][r] + bj;
            }
        }
    }
}

// ---------------- split GEMM with PRE-SPLIT B; optional split hi/lo output ----------------
// MODE 0: out = acc + bias ; MODE 1: out += acc + bias
template<int MODE, bool OUTSPLIT>
__global__ __launch_bounds__(256)
void gemm_splitpb_kernel(int Kd,
                         const float* __restrict__ A, int lda,
                         const unsigned short* __restrict__ Bhg,
                         const unsigned short* __restrict__ Blg, int ldb,
                         const float* __restrict__ bias,
                         float* __restrict__ out,
                         unsigned short* __restrict__ outh,
                         unsigned short* __restrict__ outl, int ldo)
{
    __shared__ short Ah[BM * PADK];
    __shared__ short Al[BM * PADK];
    __shared__ short Bh[BN * PADK];
    __shared__ short Bl[BN * PADK];

    const int tid = threadIdx.x;
    const int m0 = blockIdx.y * BM;
    const int n0 = blockIdx.x * BN;
    const int w = tid >> 6, lane = tid & 63;
    const int wr = w >> 1, wc = w & 1;
    const int lrow = lane & 15, lkg = lane >> 4;
    const int srow = tid >> 3, skg = (tid & 7) * 4;

    const float* Ablk = A + (size_t)m0 * lda;
    const unsigned short* Bhblk = Bhg + (size_t)n0 * ldb;
    const unsigned short* Blblk = Blg + (size_t)n0 * ldb;

    float4 pa[4];
    ushort4 pbh[4], pbl[4];
    #pragma unroll
    for (int p = 0; p < 4; ++p) {
        pa[p]  = *(const float4*)(Ablk + (size_t)(p * 32 + srow) * lda + skg);
        pbh[p] = *(const ushort4*)(Bhblk + (size_t)(p * 32 + srow) * ldb + skg);
        pbl[p] = *(const ushort4*)(Blblk + (size_t)(p * 32 + srow) * ldb + skg);
    }

    f32x4 acc[4][4] = {};
    const int nk = Kd / BK;

    for (int t = 0; t < nk; ++t) {
        __syncthreads();
        #pragma unroll
        for (int p = 0; p < 4; ++p) {
            ushort4 h, l;
            split2(pa[p].x, h.x, l.x); split2(pa[p].y, h.y, l.y);
            split2(pa[p].z, h.z, l.z); split2(pa[p].w, h.w, l.w);
            *(ushort4*)(&Ah[(p * 32 + srow) * PADK + skg]) = h;
            *(ushort4*)(&Al[(p * 32 + srow) * PADK + skg]) = l;
            *(ushort4*)(&Bh[(p * 32 + srow) * PADK + skg]) = pbh[p];
            *(ushort4*)(&Bl[(p * 32 + srow) * PADK + skg]) = pbl[p];
        }
        __syncthreads();
        if (t + 1 < nk) {
            const int kb = (t + 1) * BK + skg;
            #pragma unroll
            for (int p = 0; p < 4; ++p) {
                pa[p]  = *(const float4*)(Ablk + (size_t)(p * 32 + srow) * lda + kb);
                pbh[p] = *(const ushort4*)(Bhblk + (size_t)(p * 32 + srow) * ldb + kb);
                pbl[p] = *(const ushort4*)(Blblk + (size_t)(p * 32 + srow) * ldb + kb);
            }
        }
        bf16x8 afh[4], afl[4];
        #pragma unroll
        for (int i = 0; i < 4; ++i) {
            afh[i] = *(const bf16x8*)(&Ah[(wr * 64 + i * 16 + lrow) * PADK + lkg * 8]);
            afl[i] = *(const bf16x8*)(&Al[(wr * 64 + i * 16 + lrow) * PADK + lkg * 8]);
        }
        #pragma unroll
        for (int j = 0; j < 4; ++j) {
            const bf16x8 bh = *(const bf16x8*)(&Bh[(wc * 64 + j * 16 + lrow) * PADK + lkg * 8]);
            const bf16x8 bl = *(const bf16x8*)(&Bl[(wc * 64 + j * 16 + lrow) * PADK + lkg * 8]);
            #pragma unroll
            for (int i = 0; i < 4; ++i) {
                acc[i][j] = __builtin_amdgcn_mfma_f32_16x16x32_bf16(afh[i], bh, acc[i][j], 0, 0, 0);
                acc[i][j] = __builtin_amdgcn_mfma_f32_16x16x32_bf16(afl[i], bh, acc[i][j], 0, 0, 0);
                acc[i][j] = __builtin_amdgcn_mfma_f32_16x16x32_bf16(afh[i], bl, acc[i][j], 0, 0, 0);
            }
        }
    }

    #pragma unroll
    for (int i = 0; i < 4; ++i) {
        #pragma unroll
        for (int r = 0; r < 4; ++r) {
            const int row = m0 + wr * 64 + i * 16 + lkg * 4 + r;
            #pragma unroll
            for (int j = 0; j < 4; ++j) {
                const int col = n0 + wc * 64 + j * 16 + lrow;
                const float bj = bias ? bias[col] : 0.0f;
                const float vres = acc[i][j][r] + bj;
                if constexpr (OUTSPLIT) {
                    unsigned short h, l;
                    split2(vres, h, l);
                    outh[(size_t)row * ldo + col] = h;
                    outl[(size_t)row * ldo + col] = l;
                } else {
                    float* op = out + (size_t)row * ldo + col;
                    if (MODE == 0) *op = vres;
                    else *op = *op + vres;
                }
            }
        }
    }
}

// ---------------- fast bf16 GEMM, pre-converted A (and optionally B), reg-staged ----------------
template<int MODE, bool SWZ, bool OUTBF, bool BBF>
__global__ __launch_bounds__(256)
void gemm_fastw_kernel(int Kd,
                       const unsigned short* __restrict__ A, int lda,
                       const void* __restrict__ Bv, int ldb,
                       const float* __restrict__ bias,
                       void* __restrict__ outv, int ldo,
                       const int* __restrict__ rowmeta,
                       size_t bstride, int biasstride)
{
    __shared__ short Ah[BM * PADK];
    __shared__ short Bh[BN * PADK];

    int bx = blockIdx.x, by = blockIdx.y;
    if constexpr (SWZ) {
        const int nwg = gridDim.x * gridDim.y;
        const int chunk = nwg >> 3;
        const int flat = by * gridDim.x + bx;
        const int newid = (flat & 7) * chunk + (flat >> 3);
        by = newid % gridDim.y;
        bx = newid / gridDim.y;
    }

    const float* Bf = (const float*)Bv;
    const unsigned short* Bb = (const unsigned short*)Bv;
    float* outf = (float*)outv;
    unsigned short* outb = (unsigned short*)outv;

    int roff = 0;
    if (rowmeta) {
        const int ee = blockIdx.z;
        const int rcnt = rowmeta[2 * ee + 1];
        if ((int)(by * BM) >= rcnt) return;
        roff = rowmeta[2 * ee];
        if (BBF) Bb += (size_t)ee * bstride; else Bf += (size_t)ee * bstride;
        if (bias) bias += (size_t)ee * biasstride;
    }

    const int tid = threadIdx.x;
    const int m0 = roff + by * BM;
    const int n0 = bx * BN;
    const int w = tid >> 6, lane = tid & 63;
    const int wr = w >> 1, wc = w & 1;
    const int lrow = lane & 15, lkg = lane >> 4;
    const int srow = tid >> 3, skg = (tid & 7) * 4;

    const unsigned short* Ablk = A + (size_t)m0 * lda;
    const float* Bfblk = Bf + (size_t)n0 * ldb;
    const unsigned short* Bbblk = Bb + (size_t)n0 * ldb;

    ushort4 pa[4];
    ushort4 pbb[4];
    float4  pbf[4];
    #pragma unroll
    for (int p = 0; p < 4; ++p) {
        pa[p] = *(const ushort4*)(Ablk + (size_t)(p * 32 + srow) * lda + skg);
        if constexpr (BBF) pbb[p] = *(const ushort4*)(Bbblk + (size_t)(p * 32 + srow) * ldb + skg);
        else               pbf[p] = *(const float4*)(Bfblk + (size_t)(p * 32 + srow) * ldb + skg);
    }

    f32x4 acc[4][4] = {};
    const int nk = Kd / BK;

    for (int t = 0; t < nk; ++t) {
        __syncthreads();
        #pragma unroll
        for (int p = 0; p < 4; ++p) {
            *(ushort4*)(&Ah[(p * 32 + srow) * PADK + skg]) = pa[p];
            *(ushort4*)(&Bh[(p * 32 + srow) * PADK + skg]) = BBF ? pbb[p] : cvt4(pbf[p]);
        }
        __syncthreads();
        if (t + 1 < nk) {
            const int kb = (t + 1) * BK + skg;
            #pragma unroll
            for (int p = 0; p < 4; ++p) {
                pa[p] = *(const ushort4*)(Ablk + (size_t)(p * 32 + srow) * lda + kb);
                if constexpr (BBF) pbb[p] = *(const ushort4*)(Bbblk + (size_t)(p * 32 + srow) * ldb + kb);
                else               pbf[p] = *(const float4*)(Bfblk + (size_t)(p * 32 + srow) * ldb + kb);
            }
        }
        bf16x8 af[4];
        #pragma unroll
        for (int i = 0; i < 4; ++i)
            af[i] = *(const bf16x8*)(&Ah[(wr * 64 + i * 16 + lrow) * PADK + lkg * 8]);
        #pragma unroll
        for (int j = 0; j < 4; ++j) {
            const bf16x8 bh = *(const bf16x8*)(&Bh[(wc * 64 + j * 16 + lrow) * PADK + lkg * 8]);
            #pragma unroll
            for (int i = 0; i < 4; ++i)
                acc[i][j] = __builtin_amdgcn_mfma_f32_16x16x32_bf16(af[i], bh, acc[i][j], 0, 0, 0);
        }
    }

    #pragma unroll
    for (int i = 0; i < 4; ++i) {
        #pragma unroll
        for (int r = 0; r < 4; ++r) {
            const int row = m0 + wr * 64 + i * 16 + lkg * 4 + r;
            #pragma unroll
            for (int j = 0; j < 4; ++j) {
                const int col = n0 + wc * 64 + j * 16 + lrow;
                const float bj = bias ? bias[col] : 0.0f;
                float vres = acc[i][j][r] + bj;
                if (MODE == 2) vres = fmaxf(vres, 0.0f);
                if constexpr (OUTBF) outb[(size_t)row * ldo + col] = f2bf(vres);
                else                 outf[(size_t)row * ldo + col] = vres;
            }
        }
    }
}

// ---------------- fast bf16 GEMM with global_load_lds staging (m97 structure) ----------------
template<bool SWZ>
__global__ __launch_bounds__(256)
void gemm_lds_kernel(int Kd,
                     const unsigned short* __restrict__ A, int lda,
                     const unsigned short* __restrict__ B, int ldb,
                     const float* __restrict__ bias,
                     float* __restrict__ out, int ldo)
{
    __shared__ unsigned short Asl[BM * BK];   // 8 KB
    __shared__ unsigned short Bsl[BN * BK];   // 8 KB

    int bx = blockIdx.x, by = blockIdx.y;
    if constexpr (SWZ) {
        const int nwg = gridDim.x * gridDim.y;
        const int chunk = nwg >> 3;
        const int flat = by * gridDim.x + bx;
        const int newid = (flat & 7) * chunk + (flat >> 3);
        by = newid % gridDim.y;
        bx = newid / gridDim.y;
    }

    const int tid = threadIdx.x;
    const int m0 = by * BM;
    const int n0 = bx * BN;
    const int w = tid >> 6, lane = tid & 63;
    const int wr = w >> 1, wc = w & 1;
    const int lrow = lane & 15, lkg = lane >> 4;
    const int grow = lane >> 2, gcol = (lane & 3) * 8;

    const unsigned short* Ablk = A + (size_t)m0 * lda;
    const unsigned short* Bblk = B + (size_t)n0 * ldb;

    f32x4 acc[4][4] = {};
    const int nk = Kd / BK;

    for (int t = 0; t < nk; ++t) {
        const int k0 = t * BK;
        __syncthreads();
        #pragma unroll
        for (int j = 0; j < 2; ++j) {
            const int rbase = w * 32 + j * 16;
            gload16(Ablk + (size_t)(rbase + grow) * lda + k0 + gcol, Asl + rbase * BK);
            gload16(Bblk + (size_t)(rbase + grow) * ldb + k0 + gcol, Bsl + rbase * BK);
        }
        __syncthreads();

        bf16x8 af[4];
        #pragma unroll
        for (int i = 0; i < 4; ++i)
            af[i] = *(const bf16x8*)(Asl + (wr * 64 + i * 16 + lrow) * BK + lkg * 8);
        #pragma unroll
        for (int j = 0; j < 4; ++j) {
            const bf16x8 bh = *(const bf16x8*)(Bsl + (wc * 64 + j * 16 + lrow) * BK + lkg * 8);
            #pragma unroll
            for (int i = 0; i < 4; ++i)
                acc[i][j] = __builtin_amdgcn_mfma_f32_16x16x32_bf16(af[i], bh, acc[i][j], 0, 0, 0);
        }
    }

    #pragma unroll
    for (int i = 0; i < 4; ++i) {
        #pragma unroll
        for (int r = 0; r < 4; ++r) {
            const int row = m0 + wr * 64 + i * 16 + lkg * 4 + r;
            #pragma unroll
            for (int j = 0; j < 4; ++j) {
                const int col = n0 + wc * 64 + j * 16 + lrow;
                const float bj = bias ? bias[col] : 0.0f;
                out[(size_t)row * ldo + col] = acc[i][j][r] + bj;
            }
        }
    }
}

// ---------------- MFMA flash attention, pre-split hi/lo qkv input ----------------
#define QBLK 64
#define KVBLK 64

__global__ __launch_bounds__(256)
void attn_mfma_kernel(const unsigned short* __restrict__ qh_g,
                      const unsigned short* __restrict__ ql_g,
                      float* __restrict__ o)
{
    __shared__ short Kh[2][KVBLK][PADK];
    __shared__ short Kl[2][KVBLK][PADK];
    __shared__ short Vh[2][HSD][PADK];
    __shared__ short Vl[2][HSD][PADK];
    __shared__ short Ph[4][2][16][PADK];
    __shared__ short Pl[4][2][16][PADK];

    const int t0 = blockIdx.x * QBLK;
    const int bh = blockIdx.y;
    const int b = bh / HCNT, hh = bh % HCNT;
    const size_t baseq = (size_t)b * TT * QKVLD + (size_t)hh * HSD;
    const size_t obase = (size_t)b * TT * CDIM + (size_t)hh * HSD;
    const unsigned short* kh_g = qh_g + baseq + CDIM;
    const unsigned short* kl_g = ql_g + baseq + CDIM;
    const unsigned short* vh_g = qh_g + baseq + 2 * CDIM;
    const unsigned short* vl_g = ql_g + baseq + 2 * CDIM;
    const int tid = threadIdx.x;
    const int w = tid >> 6, lane = tid & 63;
    const int lrow = lane & 15, lkg = lane >> 4;
    const float sscale = rsqrtf((float)CDIM);

    bf16x8 qh[2], ql[2];
    {
        const size_t qroff = baseq + (size_t)(t0 + w * 16 + lrow) * QKVLD;
        #pragma unroll
        for (int ks = 0; ks < 2; ++ks) {
            qh[ks] = *(const bf16x8*)(qh_g + qroff + ks * 32 + lkg * 8);
            ql[ks] = *(const bf16x8*)(ql_g + qroff + ks * 32 + lkg * 8);
        }
    }

    f32x4 oacc[4] = {};
    float m_[4], l_[4];
    #pragma unroll
    for (int rr = 0; rr < 4; ++rr) { m_[rr] = -1e30f; l_[rr] = 0.0f; }

    for (int s0 = 0; s0 <= t0 + QBLK - 1; s0 += KVBLK) {
        __syncthreads();
        {   // stage K (pure copies)
            const int srow = tid >> 3, skg = (tid & 7) * 4;
            #pragma unroll
            for (int p = 0; p < 2; ++p) {
                const size_t kroff = (size_t)(s0 + p * 32 + srow) * QKVLD;
                #pragma unroll
                for (int ks = 0; ks < 2; ++ks) {
                    *(ushort4*)(&Kh[ks][p * 32 + srow][skg]) = *(const ushort4*)(kh_g + kroff + ks * 32 + skg);
                    *(ushort4*)(&Kl[ks][p * 32 + srow][skg]) = *(const ushort4*)(kl_g + kroff + ks * 32 + skg);
                }
            }
            // stage V transposed (pure copies)
            const int key = tid & 63, dg = (tid >> 6) * 16;
            const size_t vroff = (size_t)(s0 + key) * QKVLD + dg;
            const int kst = key >> 5, ko = key & 31;
            #pragma unroll
            for (int dd = 0; dd < 16; dd += 4) {
                ushort4 hv = *(const ushort4*)(vh_g + vroff + dd);
                ushort4 lv = *(const ushort4*)(vl_g + vroff + dd);
                Vh[kst][dg + dd + 0][ko] = hv.x; Vl[kst][dg + dd + 0][ko] = lv.x;
                Vh[kst][dg + dd + 1][ko] = hv.y; Vl[kst][dg + dd + 1][ko] = lv.y;
                Vh[kst][dg + dd + 2][ko] = hv.z; Vl[kst][dg + dd + 2][ko] = lv.z;
                Vh[kst][dg + dd + 3][ko] = hv.w; Vl[kst][dg + dd + 3][ko] = lv.w;
            }
        }
        __syncthreads();

        f32x4 sacc[4] = {};
        #pragma unroll
        for (int j = 0; j < 4; ++j) {
            #pragma unroll
            for (int ks = 0; ks < 2; ++ks) {
                const bf16x8 bh = *(const bf16x8*)(&Kh[ks][j * 16 + lrow][lkg * 8]);
                const bf16x8 bl = *(const bf16x8*)(&Kl[ks][j * 16 + lrow][lkg * 8]);
                sacc[j] = __builtin_amdgcn_mfma_f32_16x16x32_bf16(qh[ks], bh, sacc[j], 0, 0, 0);
                sacc[j] = __builtin_amdgcn_mfma_f32_16x16x32_bf16(ql[ks], bh, sacc[j], 0, 0, 0);
                sacc[j] = __builtin_amdgcn_mfma_f32_16x16x32_bf16(qh[ks], bl, sacc[j], 0, 0, 0);
            }
        }

        #pragma unroll
        for (int rr = 0; rr < 4; ++rr) {
            const int qi = t0 + w * 16 + lkg * 4 + rr;
            float pv[4];
            float mx = -1e30f;
            #pragma unroll
            for (int j = 0; j < 4; ++j) {
                float s = sacc[j][rr] * sscale;
                if (s0 + j * 16 + lrow > qi) s = -1e30f;
                pv[j] = s;
                mx = fmaxf(mx, s);
            }
            #pragma unroll
            for (int off = 1; off < 16; off <<= 1) mx = fmaxf(mx, __shfl_xor(mx, off));
            const float mnew = fmaxf(m_[rr], mx);
            const float corr = __expf(m_[rr] - mnew);
            float ps = 0.0f;
            #pragma unroll
            for (int j = 0; j < 4; ++j) { pv[j] = __expf(pv[j] - mnew); ps += pv[j]; }
            #pragma unroll
            for (int off = 1; off < 16; off <<= 1) ps += __shfl_xor(ps, off);
            l_[rr] = l_[rr] * corr + ps;
            m_[rr] = mnew;
            #pragma unroll
            for (int jd = 0; jd < 4; ++jd) oacc[jd][rr] *= corr;
            #pragma unroll
            for (int j = 0; j < 4; ++j) {
                unsigned short h, l;
                split2(pv[j], h, l);
                const int key = j * 16 + lrow;
                Ph[w][key >> 5][lkg * 4 + rr][key & 31] = h;
                Pl[w][key >> 5][lkg * 4 + rr][key & 31] = l;
            }
        }

        #pragma unroll
        for (int ks = 0; ks < 2; ++ks) {
            const bf16x8 ah = *(const bf16x8*)(&Ph[w][ks][lrow][lkg * 8]);
            const bf16x8 al = *(const bf16x8*)(&Pl[w][ks][lrow][lkg * 8]);
            #pragma unroll
            for (int jd = 0; jd < 4; ++jd) {
                const bf16x8 bh = *(const bf16x8*)(&Vh[ks][jd * 16 + lrow][lkg * 8]);
                const bf16x8 bl = *(const bf16x8*)(&Vl[ks][jd * 16 + lrow][lkg * 8]);
                oacc[jd] = __builtin_amdgcn_mfma_f32_16x16x32_bf16(ah, bh, oacc[jd], 0, 0, 0);
                oacc[jd] = __builtin_amdgcn_mfma_f32_16x16x32_bf16(al, bh, oacc[jd], 0, 0, 0);
                oacc[jd] = __builtin_amdgcn_mfma_f32_16x16x32_bf16(ah, bl, oacc[jd], 0, 0, 0);
            }
        }
    }

    #pragma unroll
    for (int rr = 0; rr < 4; ++rr) {
        const int qi = t0 + w * 16 + lkg * 4 + rr;
        const float invl = 1.0f / l_[rr];
        float* orow = o + obase + (size_t)qi * CDIM;
        #pragma unroll
        for (int jd = 0; jd < 4; ++jd)
            orow[jd * 16 + lrow] = oacc[jd][rr] * invl;
    }
}

// ---------------- gate: logits + top-2 + softmax -> sel[N], wts[N] ----------------
__global__ __launch_bounds__(256)
void gate_kernel(const float* __restrict__ h2, const float* __restrict__ gw,
                 int2* __restrict__ sel, float2* __restrict__ wts)
{
    __shared__ float gws[ECNT * CDIM];
    int tid = threadIdx.x;
    for (int i = tid; i < ECNT * CDIM; i += 256) gws[i] = gw[i];
    __syncthreads();
    int t = blockIdx.x * 256 + tid;
    const float* hr = h2 + (size_t)t * CDIM;
    float g[ECNT] = {};
    for (int c = 0; c < CDIM; ++c) {
        float hv = hr[c];
        #pragma unroll
        for (int e = 0; e < ECNT; ++e) g[e] = fmaf(hv, gws[e * CDIM + c], g[e]);
    }
    int e0 = 0; float g0 = g[0];
    #pragma unroll
    for (int e = 1; e < ECNT; ++e) if (g[e] > g0) { g0 = g[e]; e0 = e; }
    int e1 = -1; float g1 = -1e30f;
    #pragma unroll
    for (int e = 0; e < ECNT; ++e) if (e != e0 && g[e] > g1) { g1 = g[e]; e1 = e; }
    float z = __expf(g1 - g0);          // <= 1
    float w0 = 1.0f / (1.0f + z);
    sel[t] = make_int2(e0, e1);
    wts[t] = make_float2(w0, 1.0f - w0);
}

// ---------------- routing: build expert-grouped permutation (single block) ----------------
__global__ __launch_bounds__(256)
void route_kernel(const int2* __restrict__ sel, int* __restrict__ perm,
                  int* __restrict__ tokpos, int* __restrict__ meta)
{
    __shared__ int cnt[ECNT], off[ECNT], cur[ECNT];
    const int tid = threadIdx.x;
    if (tid < ECNT) cnt[tid] = 0;
    __syncthreads();
    for (int t = tid; t < NTOK; t += 256) {
        atomicAdd(&cnt[sel[t].x], 1);
        atomicAdd(&cnt[sel[t].y], 1);
    }
    __syncthreads();
    if (tid == 0) {
        int run = 0;
        for (int e = 0; e < ECNT; ++e) {
            off[e] = run; cur[e] = 0;
            int pc = (cnt[e] + BM - 1) / BM * BM;
            meta[2 * e] = run; meta[2 * e + 1] = pc;
            run += pc;
        }
    }
    __syncthreads();
    for (int p = tid; p < TOTCAP; p += 256) perm[p] = 0;   // pad slots -> token 0
    __syncthreads();
    for (int t = tid; t < NTOK; t += 256) {
        int2 s = sel[t];
        int p0 = atomicAdd(&cur[s.x], 1); perm[off[s.x] + p0] = t; tokpos[2 * t]     = off[s.x] + p0;
        int p1 = atomicAdd(&cur[s.y], 1); perm[off[s.y] + p1] = t; tokpos[2 * t + 1] = off[s.y] + p1;
    }
}

// ---------------- gather h2 rows into expert order ----------------
__global__ __launch_bounds__(256)
void gather_kernel(const float* __restrict__ h2, const int* __restrict__ perm,
                   float* __restrict__ xg)
{
    int i = blockIdx.x * 256 + threadIdx.x;   // TOTCAP*CDIM
    int c = i % CDIM, p = i / CDIM;
    xg[i] = h2[(size_t)perm[p] * CDIM + c];
}

__global__ __launch_bounds__(256)
void gather_bf16_kernel(const float* __restrict__ h2, const int* __restrict__ perm,
                        unsigned short* __restrict__ xg)
{
    int i = blockIdx.x * 256 + threadIdx.x;   // TOTCAP*CDIM
    int c = i % CDIM, p = i / CDIM;
    xg[i] = f2bf(h2[(size_t)perm[p] * CDIM + c]);
}

// ---------------- combine: x += w0*sum_sk(y[pos0]) + w1*sum_sk(y[pos1]) ----------------
template<int SK>
__global__ __launch_bounds__(256)
void combine_kernel(const float* __restrict__ y, size_t pstride,
                    const int* __restrict__ tokpos,
                    const float2* __restrict__ wts, float* __restrict__ x)
{
    int i = blockIdx.x * 256 + threadIdx.x;   // NTOK*CDIM
    int c = i % CDIM, t = i / CDIM;
    float2 wv = wts[t];
    const size_t r0 = (size_t)tokpos[2 * t] * CDIM + c;
    const size_t r1 = (size_t)tokpos[2 * t + 1] * CDIM + c;
    float a0 = 0.0f, a1 = 0.0f;
    #pragma unroll
    for (int s = 0; s < SK; ++s) {
        a0 += y[s * pstride + r0];
        a1 += y[s * pstride + r1];
    }
    x[i] += wv.x * a0 + wv.y * a1;
}

// ---------------- per-row cross-entropy ----------------
__global__ __launch_bounds__(256)
void loss_row_kernel(const float* __restrict__ logits, const int* __restrict__ tgt,
                     float* __restrict__ lrow)
{
    int row = blockIdx.x;
    const float* lr = logits + (size_t)row * VOC;
    int tid = threadIdx.x, w = tid >> 6, lane = tid & 63;
    __shared__ float red[4];
    float mx = -1e30f;
    for (int i = tid; i < VOC; i += 256) mx = fmaxf(mx, lr[i]);
    mx = wave_max(mx);
    if (lane == 0) red[w] = mx;
    __syncthreads();
    mx = fmaxf(fmaxf(red[0], red[1]), fmaxf(red[2], red[3]));
    __syncthreads();
    float se = 0.0f;
    for (int i = tid; i < VOC; i += 256) se += expf(lr[i] - mx);
    se = wave_sum(se);
    if (lane == 0) red[w] = se;
    __syncthreads();
    if (tid == 0) {
        float lse = mx + logf(red[0] + red[1] + red[2] + red[3]);
        lrow[row] = lse - lr[tgt[row]];
    }
}

__global__ __launch_bounds__(256)
void loss_reduce_kernel(const float* __restrict__ lrow, float* __restrict__ out)
{
    int tid = threadIdx.x, w = tid >> 6, lane = tid & 63;
    float s = 0.0f;
    for (int i = tid; i < NTOK; i += 256) s += lrow[i];
    s = wave_sum(s);
    __shared__ float red[4];
    if (lane == 0) red[w] = s;
    __syncthreads();
    if (tid == 0) out[0] = (red[0] + red[1] + red[2] + red[3]) * (1.0f / NTOK);
}

// ---------------- launch ----------------
extern "C" void kernel_launch(void* const* d_in, const int* in_sizes, int n_in,
                              void* d_out, int out_size, void* d_ws, size_t ws_size,
                              hipStream_t stream)
{
    const int*   idx     = (const int*)d_in[0];
    const int*   targets = (const int*)d_in[1];
    const float* tok_emb = (const float*)d_in[2];
    const float* pos_emb = (const float*)d_in[3];
    const float* ln1_s   = (const float*)d_in[4];
    const float* ln1_b   = (const float*)d_in[5];
    const float* wq      = (const float*)d_in[6];
    const float* wk      = (const float*)d_in[7];
    const float* wv      = (const float*)d_in[8];
    const float* wo      = (const float*)d_in[9];
    const float* bo      = (const float*)d_in[10];
    const float* ln2_s   = (const float*)d_in[11];
    const float* ln2_b   = (const float*)d_in[12];
    const float* gate_w  = (const float*)d_in[13];
    const float* w1      = (const float*)d_in[14];
    const float* b1      = (const float*)d_in[15];
    const float* w2      = (const float*)d_in[16];
    const float* b2      = (const float*)d_in[17];
    const float* lm_w    = (const float*)d_in[18];
    const float* lm_b    = (const float*)d_in[19];
    float* out = (float*)d_out;

    // ws layout
    unsigned short* wph = (unsigned short*)d_ws;                     // 3*L*C*C
    unsigned short* wpl = wph + (size_t)3 * LCNT * CDIM * CDIM;
    unsigned short* woh = wpl + (size_t)3 * LCNT * CDIM * CDIM;      // L*C*C
    unsigned short* wol = woh + (size_t)LCNT * CDIM * CDIM;
    float* x    = (float*)(wol + (size_t)LCNT * CDIM * CDIM);
    float* hbuf = x    + (size_t)NTOK * CDIM;        // LN1 out, attn out
    float* qkv  = hbuf + (size_t)NTOK * CDIM;        // region: qkvh+qkvl bf16 / h2 fp32 / ybuf fp32
    float* xg   = qkv  + (size_t)NTOK * QKVLD;       // TOTCAP*C gathered h2
    float* hid  = xg   + (size_t)TOTCAP * CDIM;      // TOTCAP*FF fp32 (l0); bf16 hid + lm_w_bf (l1/head)
    float* lrow = hid  + (size_t)TOTCAP * FF;        // NTOK
    float2* wts = (float2*)(lrow + NTOK);            // NTOK float2
    int2*  sel  = (int2*)(wts + NTOK);               // NTOK int2
    int*   perm = (int*)(sel + NTOK);                // TOTCAP
    int*  tokpos= perm + TOTCAP;                     // 2*NTOK
    int*   meta = tokpos + 2 * NTOK;                 // 16
    unsigned short* x_bf = (unsigned short*)(meta + 16);  // NTOK*C bf16
    float* part = (float*)(x_bf + (size_t)NTOK * CDIM);   // SKN*TOTCAP*C partials (optional)

    const size_t need_bytes = (size_t)((char*)(part + (size_t)SKN * TOTCAP * CDIM) - (char*)d_ws);
    const bool use_sk = ws_size >= need_bytes;

    unsigned short* qkvh = (unsigned short*)qkv;               // NTOK*QKVLD bf16 hi
    unsigned short* qkvl = qkvh + (size_t)NTOK * QKVLD;        // NTOK*QKVLD bf16 lo (fits: region is fp32-sized)
    unsigned short* xg_bf  = (unsigned short*)xg;
    unsigned short* hid_bf = (unsigned short*)hid;
    unsigned short* lmw_bf = (unsigned short*)hid;

    dim3 blk(256);

    repack_kernel<<<(3 * LCNT * CDIM * CDIM) / 256, blk, 0, stream>>>(wq, wk, wv, wph, wpl);
    splitw_kernel<<<1024, blk, 0, stream>>>(wo, woh, wol, LCNT * CDIM * CDIM / 4);
    embed_kernel<<<(NTOK * CDIM) / 256, blk, 0, stream>>>(idx, tok_emb, pos_emb, x);

    for (int l = 0; l < LCNT; ++l) {
        ln_kernel<<<NTOK, blk, 0, stream>>>(x, ln1_s + (size_t)l * CDIM, ln1_b + (size_t)l * CDIM, hbuf);

        // fused QKV projection -> split hi/lo bf16 output
        gemm_splitpb_kernel<0, true><<<dim3(QKVLD / BN, NTOK / BM), blk, 0, stream>>>(
            CDIM, hbuf, CDIM, wph + (size_t)l * 3 * CDIM * CDIM, wpl + (size_t)l * 3 * CDIM * CDIM,
            CDIM, nullptr, nullptr, qkvh, qkvl, QKVLD);

        attn_mfma_kernel<<<dim3(TT / QBLK, BB * HCNT), blk, 0, stream>>>(qkvh, qkvl, hbuf);

        gemm_splitpb_kernel<1, false><<<dim3(CDIM / BN, NTOK / BM), blk, 0, stream>>>(
            CDIM, hbuf, CDIM, woh + (size_t)l * CDIM * CDIM, wol + (size_t)l * CDIM * CDIM,
            CDIM, bo + (size_t)l * CDIM, x, nullptr, nullptr, CDIM);

        // --- MoE: gate -> route -> gather -> expert GEMMs -> combine ---
        float* h2 = qkv;       // qkv region dead after attn
        float* ybuf = qkv;
        ln_kernel<<<NTOK, blk, 0, stream>>>(x, ln2_s + (size_t)l * CDIM, ln2_b + (size_t)l * CDIM, h2);
        gate_kernel<<<NTOK / 256, blk, 0, stream>>>(h2, gate_w + (size_t)l * ECNT * CDIM, sel, wts);
        route_kernel<<<1, blk, 0, stream>>>(sel, perm, tokpos, meta);

        const float* w1l = w1 + (size_t)l * ECNT * FF * CDIM;
        const float* b1l = b1 + (size_t)l * ECNT * FF;
        const float* w2l = w2 + (size_t)l * ECNT * CDIM * FF;
        const float* b2l = b2 + (size_t)l * ECNT * CDIM;
        if (l == 0) {   // feeds next layer's router -> fp32-grade (split 3-MFMA)
            gather_kernel<<<(TOTCAP * CDIM) / 256, blk, 0, stream>>>(h2, perm, xg);
            gemm_bf16_kernel<2, true><<<dim3(FF / BN, TOTCAP / BM, ECNT), blk, 0, stream>>>(
                CDIM, xg, CDIM, w1l, CDIM, b1l, hid, FF, meta, (size_t)FF * CDIM, FF);
            if (use_sk) {   // split-K w2: 4x blocks, latency-bound shape fix
                gemm_sk_kernel<<<dim3(CDIM / BN, TOTCAP / BM, ECNT * SKN), blk, 0, stream>>>(
                    FF / SKN, hid, FF, w2l, FF, b2l, part, CDIM, (size_t)TOTCAP * CDIM,
                    meta, (size_t)CDIM * FF, CDIM);
                combine_kernel<SKN><<<(NTOK * CDIM) / 256, blk, 0, stream>>>(
                    part, (size_t)TOTCAP * CDIM, tokpos, wts, x);
            } else {
                gemm_bf16_kernel<0, true><<<dim3(CDIM / BN, TOTCAP / BM, ECNT), blk, 0, stream>>>(
                    FF, hid, FF, w2l, FF, b2l, ybuf, CDIM, meta, (size_t)CDIM * FF, CDIM);
                combine_kernel<1><<<(NTOK * CDIM) / 256, blk, 0, stream>>>(
                    ybuf, 0, tokpos, wts, x);
            }
        } else {        // feeds only logits -> fast 1-MFMA, bf16 activations
            gather_bf16_kernel<<<(TOTCAP * CDIM) / 256, blk, 0, stream>>>(h2, perm, xg_bf);
            gemm_fastw_kernel<2, false, true, false><<<dim3(FF / BN, TOTCAP / BM, ECNT), blk, 0, stream>>>(
                CDIM, xg_bf, CDIM, w1l, CDIM, b1l, hid_bf, FF, meta, (size_t)FF * CDIM, FF);
            gemm_fastw_kernel<0, false, false, false><<<dim3(CDIM / BN, TOTCAP / BM, ECNT), blk, 0, stream>>>(
                FF, hid_bf, FF, w2l, FF, b2l, ybuf, CDIM, meta, (size_t)CDIM * FF, CDIM);
            combine_kernel<1><<<(NTOK * CDIM) / 256, blk, 0, stream>>>(
                ybuf, 0, tokpos, wts, x);
        }
    }

    // pre-convert LM head operands to bf16 (hid region is dead now)
    cvt_bf16_kernel<<<2048, blk, 0, stream>>>(lm_w, lmw_bf, VOC * CDIM / 4);
    cvt_bf16_kernel<<<512, blk, 0, stream>>>(x, x_bf, NTOK * CDIM / 4);

    // LM head: bf16 x bf16 via global_load_lds staging, XCD-aware m-fastest swizzle
    gemm_lds_kernel<true><<<dim3(VOC / BN, NTOK / BM), blk, 0, stream>>>(
        CDIM, x_bf, CDIM, lmw_bf, CDIM, lm_b, out, VOC);

    loss_row_kernel<<<NTOK, blk, 0, stream>>>(out, targets, lrow);
    loss_reduce_kernel<<<1, blk, 0, stream>>>(lrow, out + (size_t)NTOK * VOC);
}

// Round 11
// 1328.544 us; speedup vs baseline: 9.6282x; 1.0324x over previous
//
#include <hip/hip_runtime.h>
#include <hip/hip_bf16.h>

// Problem constants (from reference)
#define LCNT 2
#define HCNT 12
#define CDIM 768
#define HSD  64
#define ECNT 8
#define VOC  32000
#define BB   2
#define TT   1024
#define NTOK 2048   // B*T
#define FF   3072   // 4*C
#define QKVLD 2304  // 3*C
#define TOTCAP 5120 // 2*NTOK + 8*128 padding capacity
#define SKN  4      // split-K factor for l0 w2

typedef __attribute__((ext_vector_type(8))) short bf16x8;
typedef __attribute__((ext_vector_type(4))) float f32x4;

// ---------------- helpers ----------------
__device__ __forceinline__ float wave_sum(float v) {
    #pragma unroll
    for (int off = 32; off; off >>= 1) v += __shfl_xor(v, off);
    return v;
}
__device__ __forceinline__ float wave_max(float v) {
    #pragma unroll
    for (int off = 32; off; off >>= 1) v = fmaxf(v, __shfl_xor(v, off));
    return v;
}
__device__ __forceinline__ unsigned short f2bf(float f) {
    unsigned int u = __float_as_uint(f);
    unsigned int r = (u + 0x7FFFu + ((u >> 16) & 1u)) >> 16;
    return (unsigned short)r;
}
__device__ __forceinline__ float bf2f(unsigned short h) {
    return __uint_as_float((unsigned int)h << 16);
}
__device__ __forceinline__ void split2(float a, unsigned short& h, unsigned short& l) {
    h = f2bf(a);
    l = f2bf(a - bf2f(h));
}
__device__ __forceinline__ ushort4 cvt4(float4 v) {
    ushort4 r;
    r.x = f2bf(v.x); r.y = f2bf(v.y); r.z = f2bf(v.z); r.w = f2bf(v.w);
    return r;
}
// async 16B global->LDS (dest = wave-uniform base + lane*16)
__device__ __forceinline__ void gload16(const void* g, void* l) {
    __builtin_amdgcn_global_load_lds(
        (const __attribute__((address_space(1))) unsigned int*)g,
        (__attribute__((address_space(3))) unsigned int*)l,
        16, 0, 0);
}

// ---------------- fp32 -> bf16 bulk convert ----------------
__global__ __launch_bounds__(256)
void cvt_bf16_kernel(const float* __restrict__ in, unsigned short* __restrict__ out, int n4)
{
    for (int i = blockIdx.x * 256 + threadIdx.x; i < n4; i += gridDim.x * 256) {
        float4 v = reinterpret_cast<const float4*>(in)[i];
        reinterpret_cast<ushort4*>(out)[i] = cvt4(v);
    }
}

// ---------------- fp32 -> split hi/lo bf16 bulk ----------------
__global__ __launch_bounds__(256)
void splitw_kernel(const float* __restrict__ in, unsigned short* __restrict__ oh,
                   unsigned short* __restrict__ ol, int n4)
{
    for (int i = blockIdx.x * 256 + threadIdx.x; i < n4; i += gridDim.x * 256) {
        float4 v = reinterpret_cast<const float4*>(in)[i];
        ushort4 h, l;
        split2(v.x, h.x, l.x); split2(v.y, h.y, l.y);
        split2(v.z, h.z, l.z); split2(v.w, h.w, l.w);
        reinterpret_cast<ushort4*>(oh)[i] = h;
        reinterpret_cast<ushort4*>(ol)[i] = l;
    }
}

// ---------------- embedding ----------------
__global__ __launch_bounds__(256)
void embed_kernel(const int* __restrict__ idx, const float* __restrict__ tok,
                  const float* __restrict__ pos, float* __restrict__ x)
{
    int i = blockIdx.x * 256 + threadIdx.x;      // N*C total
    int c = i % CDIM;
    int n = i / CDIM;
    int t = n % TT;
    x[i] = tok[(size_t)idx[n] * CDIM + c] + pos[(size_t)t * CDIM + c];
}

// ---------------- repack wq/wk/wv [L,H,C,HS] -> split hi/lo [l][w3*C + n][k] (fused B^T) ----------------
__global__ __launch_bounds__(256)
void repack_kernel(const float* __restrict__ wq, const float* __restrict__ wk,
                   const float* __restrict__ wv, unsigned short* __restrict__ wph,
                   unsigned short* __restrict__ wpl)
{
    int i = blockIdx.x * 256 + threadIdx.x;      // 3*L*C*C
    int kk = i % CDIM;
    int n  = (i / CDIM) % CDIM;
    int w3 = (i / (CDIM * CDIM)) % 3;
    int l  = i / (CDIM * CDIM * 3);
    const float* src = (w3 == 0) ? wq : (w3 == 1) ? wk : wv;
    int h = n / HSD, d = n % HSD;
    float v = src[((((size_t)l * HCNT + h) * CDIM) + kk) * HSD + d];
    unsigned short hh, ll;
    split2(v, hh, ll);
    size_t o = (((size_t)l * 3 + w3) * CDIM + n) * CDIM + kk;
    wph[o] = hh;
    wpl[o] = ll;
}

// ---------------- layernorm; emits split hi/lo (+ optional fp32) ----------------
template<bool WF32>
__global__ __launch_bounds__(256)
void ln_kernel(const float* __restrict__ x, const float* __restrict__ sc,
               const float* __restrict__ bs, float* __restrict__ out,
               unsigned short* __restrict__ oh, unsigned short* __restrict__ ol)
{
    int row = blockIdx.x;
    const float* xr = x + (size_t)row * CDIM;
    int tid = threadIdx.x;
    float v0 = xr[tid], v1 = xr[tid + 256], v2 = xr[tid + 512];
    float s1 = v0 + v1 + v2;
    float s2 = v0 * v0 + v1 * v1 + v2 * v2;
    s1 = wave_sum(s1);
    s2 = wave_sum(s2);
    __shared__ float r1[4], r2[4];
    int w = tid >> 6, lane = tid & 63;
    if (lane == 0) { r1[w] = s1; r2[w] = s2; }
    __syncthreads();
    float t1 = r1[0] + r1[1] + r1[2] + r1[3];
    float t2 = r2[0] + r2[1] + r2[2] + r2[3];
    float mu = t1 * (1.0f / CDIM);
    float var = t2 * (1.0f / CDIM) - mu * mu;
    float rstd = rsqrtf(var + 1e-5f);
    float o0 = (v0 - mu) * rstd * sc[tid]       + bs[tid];
    float o1 = (v1 - mu) * rstd * sc[tid + 256] + bs[tid + 256];
    float o2 = (v2 - mu) * rstd * sc[tid + 512] + bs[tid + 512];
    if constexpr (WF32) {
        float* orow = out + (size_t)row * CDIM;
        orow[tid] = o0; orow[tid + 256] = o1; orow[tid + 512] = o2;
    }
    unsigned short h, l;
    unsigned short* ohr = oh + (size_t)row * CDIM;
    unsigned short* olr = ol + (size_t)row * CDIM;
    split2(o0, h, l); ohr[tid]       = h; olr[tid]       = l;
    split2(o1, h, l); ohr[tid + 256] = h; olr[tid + 256] = l;
    split2(o2, h, l); ohr[tid + 512] = h; olr[tid + 512] = l;
}

#define BM 128
#define BN 128
#define BK 32
#define PADK 40   // bf16 stride per row (80 B)

// ---------------- split GEMM, BOTH operands pre-split hi/lo bf16 (pure-copy staging) ----------------
// MODE 0: store fp32 (or OUTSPLIT hi/lo) ; MODE 1: accumulate fp32
template<int MODE, bool OUTSPLIT>
__global__ __launch_bounds__(256)
void gemm_ps_kernel(int Kd,
                    const unsigned short* __restrict__ Ahg,
                    const unsigned short* __restrict__ Alg, int lda,
                    const unsigned short* __restrict__ Bhg,
                    const unsigned short* __restrict__ Blg, int ldb,
                    const float* __restrict__ bias,
                    float* __restrict__ out,
                    unsigned short* __restrict__ outh,
                    unsigned short* __restrict__ outl, int ldo)
{
    __shared__ short Ah[BM * PADK];
    __shared__ short Al[BM * PADK];
    __shared__ short Bh[BN * PADK];
    __shared__ short Bl[BN * PADK];

    const int tid = threadIdx.x;
    const int m0 = blockIdx.y * BM;
    const int n0 = blockIdx.x * BN;
    const int w = tid >> 6, lane = tid & 63;
    const int wr = w >> 1, wc = w & 1;
    const int lrow = lane & 15, lkg = lane >> 4;
    const int srow = tid >> 3, skg = (tid & 7) * 4;

    const unsigned short* Ahb = Ahg + (size_t)m0 * lda;
    const unsigned short* Alb = Alg + (size_t)m0 * lda;
    const unsigned short* Bhb = Bhg + (size_t)n0 * ldb;
    const unsigned short* Blb = Blg + (size_t)n0 * ldb;

    ushort4 pah[4], pal[4], pbh[4], pbl[4];
    #pragma unroll
    for (int p = 0; p < 4; ++p) {
        pah[p] = *(const ushort4*)(Ahb + (size_t)(p * 32 + srow) * lda + skg);
        pal[p] = *(const ushort4*)(Alb + (size_t)(p * 32 + srow) * lda + skg);
        pbh[p] = *(const ushort4*)(Bhb + (size_t)(p * 32 + srow) * ldb + skg);
        pbl[p] = *(const ushort4*)(Blb + (size_t)(p * 32 + srow) * ldb + skg);
    }

    f32x4 acc[4][4] = {};
    const int nk = Kd / BK;

    for (int t = 0; t < nk; ++t) {
        __syncthreads();
        #pragma unroll
        for (int p = 0; p < 4; ++p) {
            *(ushort4*)(&Ah[(p * 32 + srow) * PADK + skg]) = pah[p];
            *(ushort4*)(&Al[(p * 32 + srow) * PADK + skg]) = pal[p];
            *(ushort4*)(&Bh[(p * 32 + srow) * PADK + skg]) = pbh[p];
            *(ushort4*)(&Bl[(p * 32 + srow) * PADK + skg]) = pbl[p];
        }
        __syncthreads();
        if (t + 1 < nk) {
            const int kb = (t + 1) * BK + skg;
            #pragma unroll
            for (int p = 0; p < 4; ++p) {
                pah[p] = *(const ushort4*)(Ahb + (size_t)(p * 32 + srow) * lda + kb);
                pal[p] = *(const ushort4*)(Alb + (size_t)(p * 32 + srow) * lda + kb);
                pbh[p] = *(const ushort4*)(Bhb + (size_t)(p * 32 + srow) * ldb + kb);
                pbl[p] = *(const ushort4*)(Blb + (size_t)(p * 32 + srow) * ldb + kb);
            }
        }
        bf16x8 afh[4], afl[4];
        #pragma unroll
        for (int i = 0; i < 4; ++i) {
            afh[i] = *(const bf16x8*)(&Ah[(wr * 64 + i * 16 + lrow) * PADK + lkg * 8]);
            afl[i] = *(const bf16x8*)(&Al[(wr * 64 + i * 16 + lrow) * PADK + lkg * 8]);
        }
        #pragma unroll
        for (int j = 0; j < 4; ++j) {
            const bf16x8 bh = *(const bf16x8*)(&Bh[(wc * 64 + j * 16 + lrow) * PADK + lkg * 8]);
            const bf16x8 bl = *(const bf16x8*)(&Bl[(wc * 64 + j * 16 + lrow) * PADK + lkg * 8]);
            #pragma unroll
            for (int i = 0; i < 4; ++i) {
                acc[i][j] = __builtin_amdgcn_mfma_f32_16x16x32_bf16(afh[i], bh, acc[i][j], 0, 0, 0);
                acc[i][j] = __builtin_amdgcn_mfma_f32_16x16x32_bf16(afl[i], bh, acc[i][j], 0, 0, 0);
                acc[i][j] = __builtin_amdgcn_mfma_f32_16x16x32_bf16(afh[i], bl, acc[i][j], 0, 0, 0);
            }
        }
    }

    #pragma unroll
    for (int i = 0; i < 4; ++i) {
        #pragma unroll
        for (int r = 0; r < 4; ++r) {
            const int row = m0 + wr * 64 + i * 16 + lkg * 4 + r;
            #pragma unroll
            for (int j = 0; j < 4; ++j) {
                const int col = n0 + wc * 64 + j * 16 + lrow;
                const float bj = bias ? bias[col] : 0.0f;
                const float vres = acc[i][j][r] + bj;
                if constexpr (OUTSPLIT) {
                    unsigned short h, l;
                    split2(vres, h, l);
                    outh[(size_t)row * ldo + col] = h;
                    outl[(size_t)row * ldo + col] = l;
                } else {
                    float* op = out + (size_t)row * ldo + col;
                    if (MODE == 0) *op = vres;
                    else *op = *op + vres;
                }
            }
        }
    }
}

// ---------------- expert split GEMM: A pre-split (pure copy), B fp32 inline-split ----------------
// epilogue: relu + split hi/lo store (l0 w1)
__global__ __launch_bounds__(256)
void gemm_pse_kernel(int Kd,
                     const unsigned short* __restrict__ Ahg,
                     const unsigned short* __restrict__ Alg, int lda,
                     const float* __restrict__ B, int ldb,
                     const float* __restrict__ bias,
                     unsigned short* __restrict__ outh,
                     unsigned short* __restrict__ outl, int ldo,
                     const int* __restrict__ rowmeta,
                     size_t bstride, int biasstride)
{
    __shared__ short Ah[BM * PADK];
    __shared__ short Al[BM * PADK];
    __shared__ short Bh[BN * PADK];
    __shared__ short Bl[BN * PADK];

    const int ee = blockIdx.z;
    const int rcnt = rowmeta[2 * ee + 1];
    if ((int)(blockIdx.y * BM) >= rcnt) return;
    const int roff = rowmeta[2 * ee];
    B += (size_t)ee * bstride;
    bias += (size_t)ee * biasstride;

    const int tid = threadIdx.x;
    const int m0 = roff + blockIdx.y * BM;
    const int n0 = blockIdx.x * BN;
    const int w = tid >> 6, lane = tid & 63;
    const int wr = w >> 1, wc = w & 1;
    const int lrow = lane & 15, lkg = lane >> 4;
    const int srow = tid >> 3, skg = (tid & 7) * 4;

    const unsigned short* Ahb = Ahg + (size_t)m0 * lda;
    const unsigned short* Alb = Alg + (size_t)m0 * lda;
    const float* Bblk = B + (size_t)n0 * ldb;

    ushort4 pah[4], pal[4];
    float4 pb[4];
    #pragma unroll
    for (int p = 0; p < 4; ++p) {
        pah[p] = *(const ushort4*)(Ahb + (size_t)(p * 32 + srow) * lda + skg);
        pal[p] = *(const ushort4*)(Alb + (size_t)(p * 32 + srow) * lda + skg);
        pb[p]  = *(const float4*)(Bblk + (size_t)(p * 32 + srow) * ldb + skg);
    }

    f32x4 acc[4][4] = {};
    const int nk = Kd / BK;

    for (int t = 0; t < nk; ++t) {
        __syncthreads();
        #pragma unroll
        for (int p = 0; p < 4; ++p) {
            *(ushort4*)(&Ah[(p * 32 + srow) * PADK + skg]) = pah[p];
            *(ushort4*)(&Al[(p * 32 + srow) * PADK + skg]) = pal[p];
            ushort4 h, l;
            split2(pb[p].x, h.x, l.x); split2(pb[p].y, h.y, l.y);
            split2(pb[p].z, h.z, l.z); split2(pb[p].w, h.w, l.w);
            *(ushort4*)(&Bh[(p * 32 + srow) * PADK + skg]) = h;
            *(ushort4*)(&Bl[(p * 32 + srow) * PADK + skg]) = l;
        }
        __syncthreads();
        if (t + 1 < nk) {
            const int kb = (t + 1) * BK + skg;
            #pragma unroll
            for (int p = 0; p < 4; ++p) {
                pah[p] = *(const ushort4*)(Ahb + (size_t)(p * 32 + srow) * lda + kb);
                pal[p] = *(const ushort4*)(Alb + (size_t)(p * 32 + srow) * lda + kb);
                pb[p]  = *(const float4*)(Bblk + (size_t)(p * 32 + srow) * ldb + kb);
            }
        }
        bf16x8 afh[4], afl[4];
        #pragma unroll
        for (int i = 0; i < 4; ++i) {
            afh[i] = *(const bf16x8*)(&Ah[(wr * 64 + i * 16 + lrow) * PADK + lkg * 8]);
            afl[i] = *(const bf16x8*)(&Al[(wr * 64 + i * 16 + lrow) * PADK + lkg * 8]);
        }
        #pragma unroll
        for (int j = 0; j < 4; ++j) {
            const bf16x8 bh = *(const bf16x8*)(&Bh[(wc * 64 + j * 16 + lrow) * PADK + lkg * 8]);
            const bf16x8 bl = *(const bf16x8*)(&Bl[(wc * 64 + j * 16 + lrow) * PADK + lkg * 8]);
            #pragma unroll
            for (int i = 0; i < 4; ++i) {
                acc[i][j] = __builtin_amdgcn_mfma_f32_16x16x32_bf16(afh[i], bh, acc[i][j], 0, 0, 0);
                acc[i][j] = __builtin_amdgcn_mfma_f32_16x16x32_bf16(afl[i], bh, acc[i][j], 0, 0, 0);
                acc[i][j] = __builtin_amdgcn_mfma_f32_16x16x32_bf16(afh[i], bl, acc[i][j], 0, 0, 0);
            }
        }
    }

    #pragma unroll
    for (int i = 0; i < 4; ++i) {
        #pragma unroll
        for (int r = 0; r < 4; ++r) {
            const int row = m0 + wr * 64 + i * 16 + lkg * 4 + r;
            #pragma unroll
            for (int j = 0; j < 4; ++j) {
                const int col = n0 + wc * 64 + j * 16 + lrow;
                const float vres = fmaxf(acc[i][j][r] + bias[col], 0.0f);
                unsigned short h, l;
                split2(vres, h, l);
                outh[(size_t)row * ldo + col] = h;
                outl[(size_t)row * ldo + col] = l;
            }
        }
    }
}

// ---------------- split-K expert GEMM: A pre-split (pure copy), B fp32 inline-split ----------------
// blockIdx.z = ee*SK + kz; partial outputs; bias only at kz==0.
template<int SK>
__global__ __launch_bounds__(256)
void gemm_pssk_kernel(int Kc,
                      const unsigned short* __restrict__ Ahg,
                      const unsigned short* __restrict__ Alg, int lda,
                      const float* __restrict__ B, int ldb,
                      const float* __restrict__ bias,
                      float* __restrict__ part, int ldo, size_t pstride,
                      const int* __restrict__ rowmeta,
                      size_t bstride, int biasstride)
{
    __shared__ short Ah[BM * PADK];
    __shared__ short Al[BM * PADK];
    __shared__ short Bh[BN * PADK];
    __shared__ short Bl[BN * PADK];

    const int zz = blockIdx.z;
    const int ee = zz / SK, kz = zz % SK;
    const int rcnt = rowmeta[2 * ee + 1];
    if ((int)(blockIdx.y * BM) >= rcnt) return;
    const int roff = rowmeta[2 * ee];
    const float* Bp = B + (size_t)ee * bstride + (size_t)kz * Kc;
    const unsigned short* Ahp = Ahg + (size_t)kz * Kc;
    const unsigned short* Alp = Alg + (size_t)kz * Kc;
    const float* biasp = (kz == 0) ? bias + (size_t)ee * biasstride : nullptr;
    float* out = part + (size_t)kz * pstride;

    const int tid = threadIdx.x;
    const int m0 = roff + blockIdx.y * BM;
    const int n0 = blockIdx.x * BN;
    const int w = tid >> 6, lane = tid & 63;
    const int wr = w >> 1, wc = w & 1;
    const int lrow = lane & 15, lkg = lane >> 4;
    const int srow = tid >> 3, skg = (tid & 7) * 4;

    const unsigned short* Ahb = Ahp + (size_t)m0 * lda;
    const unsigned short* Alb = Alp + (size_t)m0 * lda;
    const float* Bblk = Bp + (size_t)n0 * ldb;

    ushort4 pah[4], pal[4];
    float4 pb[4];
    #pragma unroll
    for (int p = 0; p < 4; ++p) {
        pah[p] = *(const ushort4*)(Ahb + (size_t)(p * 32 + srow) * lda + skg);
        pal[p] = *(const ushort4*)(Alb + (size_t)(p * 32 + srow) * lda + skg);
        pb[p]  = *(const float4*)(Bblk + (size_t)(p * 32 + srow) * ldb + skg);
    }

    f32x4 acc[4][4] = {};
    const int nk = Kc / BK;

    for (int t = 0; t < nk; ++t) {
        __syncthreads();
        #pragma unroll
        for (int p = 0; p < 4; ++p) {
            *(ushort4*)(&Ah[(p * 32 + srow) * PADK + skg]) = pah[p];
            *(ushort4*)(&Al[(p * 32 + srow) * PADK + skg]) = pal[p];
            ushort4 h, l;
            split2(pb[p].x, h.x, l.x); split2(pb[p].y, h.y, l.y);
            split2(pb[p].z, h.z, l.z); split2(pb[p].w, h.w, l.w);
            *(ushort4*)(&Bh[(p * 32 + srow) * PADK + skg]) = h;
            *(ushort4*)(&Bl[(p * 32 + srow) * PADK + skg]) = l;
        }
        __syncthreads();
        if (t + 1 < nk) {
            const int kb = (t + 1) * BK + skg;
            #pragma unroll
            for (int p = 0; p < 4; ++p) {
                pah[p] = *(const ushort4*)(Ahb + (size_t)(p * 32 + srow) * lda + kb);
                pal[p] = *(const ushort4*)(Alb + (size_t)(p * 32 + srow) * lda + kb);
                pb[p]  = *(const float4*)(Bblk + (size_t)(p * 32 + srow) * ldb + kb);
            }
        }
        bf16x8 afh[4], afl[4];
        #pragma unroll
        for (int i = 0; i < 4; ++i) {
            afh[i] = *(const bf16x8*)(&Ah[(wr * 64 + i * 16 + lrow) * PADK + lkg * 8]);
            afl[i] = *(const bf16x8*)(&Al[(wr * 64 + i * 16 + lrow) * PADK + lkg * 8]);
        }
        #pragma unroll
        for (int j = 0; j < 4; ++j) {
            const bf16x8 bh = *(const bf16x8*)(&Bh[(wc * 64 + j * 16 + lrow) * PADK + lkg * 8]);
            const bf16x8 bl = *(const bf16x8*)(&Bl[(wc * 64 + j * 16 + lrow) * PADK + lkg * 8]);
            #pragma unroll
            for (int i = 0; i < 4; ++i) {
                acc[i][j] = __builtin_amdgcn_mfma_f32_16x16x32_bf16(afh[i], bh, acc[i][j], 0, 0, 0);
                acc[i][j] = __builtin_amdgcn_mfma_f32_16x16x32_bf16(afl[i], bh, acc[i][j], 0, 0, 0);
                acc[i][j] = __builtin_amdgcn_mfma_f32_16x16x32_bf16(afh[i], bl, acc[i][j], 0, 0, 0);
            }
        }
    }

    #pragma unroll
    for (int i = 0; i < 4; ++i) {
        #pragma unroll
        for (int r = 0; r < 4; ++r) {
            const int row = m0 + wr * 64 + i * 16 + lkg * 4 + r;
            #pragma unroll
            for (int j = 0; j < 4; ++j) {
                const int col = n0 + wc * 64 + j * 16 + lrow;
                const float bj = biasp ? biasp[col] : 0.0f;
                out[(size_t)row * ldo + col] = acc[i][j][r] + bj;
            }
        }
    }
}

// ---------------- fast bf16 GEMM, pre-converted A (B fp32 inline or bf16), reg-staged ----------------
template<int MODE, bool SWZ, bool OUTBF, bool BBF>
__global__ __launch_bounds__(256)
void gemm_fastw_kernel(int Kd,
                       const unsigned short* __restrict__ A, int lda,
                       const void* __restrict__ Bv, int ldb,
                       const float* __restrict__ bias,
                       void* __restrict__ outv, int ldo,
                       const int* __restrict__ rowmeta,
                       size_t bstride, int biasstride)
{
    __shared__ short Ah[BM * PADK];
    __shared__ short Bh[BN * PADK];

    int bx = blockIdx.x, by = blockIdx.y;
    if constexpr (SWZ) {
        const int nwg = gridDim.x * gridDim.y;
        const int chunk = nwg >> 3;
        const int flat = by * gridDim.x + bx;
        const int newid = (flat & 7) * chunk + (flat >> 3);
        by = newid % gridDim.y;
        bx = newid / gridDim.y;
    }

    const float* Bf = (const float*)Bv;
    const unsigned short* Bb = (const unsigned short*)Bv;
    float* outf = (float*)outv;
    unsigned short* outb = (unsigned short*)outv;

    int roff = 0;
    if (rowmeta) {
        const int ee = blockIdx.z;
        const int rcnt = rowmeta[2 * ee + 1];
        if ((int)(by * BM) >= rcnt) return;
        roff = rowmeta[2 * ee];
        if (BBF) Bb += (size_t)ee * bstride; else Bf += (size_t)ee * bstride;
        if (bias) bias += (size_t)ee * biasstride;
    }

    const int tid = threadIdx.x;
    const int m0 = roff + by * BM;
    const int n0 = bx * BN;
    const int w = tid >> 6, lane = tid & 63;
    const int wr = w >> 1, wc = w & 1;
    const int lrow = lane & 15, lkg = lane >> 4;
    const int srow = tid >> 3, skg = (tid & 7) * 4;

    const unsigned short* Ablk = A + (size_t)m0 * lda;
    const float* Bfblk = Bf + (size_t)n0 * ldb;
    const unsigned short* Bbblk = Bb + (size_t)n0 * ldb;

    ushort4 pa[4];
    ushort4 pbb[4];
    float4  pbf[4];
    #pragma unroll
    for (int p = 0; p < 4; ++p) {
        pa[p] = *(const ushort4*)(Ablk + (size_t)(p * 32 + srow) * lda + skg);
        if constexpr (BBF) pbb[p] = *(const ushort4*)(Bbblk + (size_t)(p * 32 + srow) * ldb + skg);
        else               pbf[p] = *(const float4*)(Bfblk + (size_t)(p * 32 + srow) * ldb + skg);
    }

    f32x4 acc[4][4] = {};
    const int nk = Kd / BK;

    for (int t = 0; t < nk; ++t) {
        __syncthreads();
        #pragma unroll
        for (int p = 0; p < 4; ++p) {
            *(ushort4*)(&Ah[(p * 32 + srow) * PADK + skg]) = pa[p];
            *(ushort4*)(&Bh[(p * 32 + srow) * PADK + skg]) = BBF ? pbb[p] : cvt4(pbf[p]);
        }
        __syncthreads();
        if (t + 1 < nk) {
            const int kb = (t + 1) * BK + skg;
            #pragma unroll
            for (int p = 0; p < 4; ++p) {
                pa[p] = *(const ushort4*)(Ablk + (size_t)(p * 32 + srow) * lda + kb);
                if constexpr (BBF) pbb[p] = *(const ushort4*)(Bbblk + (size_t)(p * 32 + srow) * ldb + kb);
                else               pbf[p] = *(const float4*)(Bfblk + (size_t)(p * 32 + srow) * ldb + kb);
            }
        }
        bf16x8 af[4];
        #pragma unroll
        for (int i = 0; i < 4; ++i)
            af[i] = *(const bf16x8*)(&Ah[(wr * 64 + i * 16 + lrow) * PADK + lkg * 8]);
        #pragma unroll
        for (int j = 0; j < 4; ++j) {
            const bf16x8 bh = *(const bf16x8*)(&Bh[(wc * 64 + j * 16 + lrow) * PADK + lkg * 8]);
            #pragma unroll
            for (int i = 0; i < 4; ++i)
                acc[i][j] = __builtin_amdgcn_mfma_f32_16x16x32_bf16(af[i], bh, acc[i][j], 0, 0, 0);
        }
    }

    #pragma unroll
    for (int i = 0; i < 4; ++i) {
        #pragma unroll
        for (int r = 0; r < 4; ++r) {
            const int row = m0 + wr * 64 + i * 16 + lkg * 4 + r;
            #pragma unroll
            for (int j = 0; j < 4; ++j) {
                const int col = n0 + wc * 64 + j * 16 + lrow;
                const float bj = bias ? bias[col] : 0.0f;
                float vres = acc[i][j][r] + bj;
                if (MODE == 2) vres = fmaxf(vres, 0.0f);
                if constexpr (OUTBF) outb[(size_t)row * ldo + col] = f2bf(vres);
                else                 outf[(size_t)row * ldo + col] = vres;
            }
        }
    }
}

// ---------------- fast bf16 GEMM with global_load_lds staging (m97 structure) ----------------
template<bool SWZ>
__global__ __launch_bounds__(256)
void gemm_lds_kernel(int Kd,
                     const unsigned short* __restrict__ A, int lda,
                     const unsigned short* __restrict__ B, int ldb,
                     const float* __restrict__ bias,
                     float* __restrict__ out, int ldo)
{
    __shared__ unsigned short Asl[BM * BK];   // 8 KB
    __shared__ unsigned short Bsl[BN * BK];   // 8 KB

    int bx = blockIdx.x, by = blockIdx.y;
    if constexpr (SWZ) {
        const int nwg = gridDim.x * gridDim.y;
        const int chunk = nwg >> 3;
        const int flat = by * gridDim.x + bx;
        const int newid = (flat & 7) * chunk + (flat >> 3);
        by = newid % gridDim.y;
        bx = newid / gridDim.y;
    }

    const int tid = threadIdx.x;
    const int m0 = by * BM;
    const int n0 = bx * BN;
    const int w = tid >> 6, lane = tid & 63;
    const int wr = w >> 1, wc = w & 1;
    const int lrow = lane & 15, lkg = lane >> 4;
    const int grow = lane >> 2, gcol = (lane & 3) * 8;

    const unsigned short* Ablk = A + (size_t)m0 * lda;
    const unsigned short* Bblk = B + (size_t)n0 * ldb;

    f32x4 acc[4][4] = {};
    const int nk = Kd / BK;

    for (int t = 0; t < nk; ++t) {
        const int k0 = t * BK;
        __syncthreads();
        #pragma unroll
        for (int j = 0; j < 2; ++j) {
            const int rbase = w * 32 + j * 16;
            gload16(Ablk + (size_t)(rbase + grow) * lda + k0 + gcol, Asl + rbase * BK);
            gload16(Bblk + (size_t)(rbase + grow) * ldb + k0 + gcol, Bsl + rbase * BK);
        }
        __syncthreads();

        bf16x8 af[4];
        #pragma unroll
        for (int i = 0; i < 4; ++i)
            af[i] = *(const bf16x8*)(Asl + (wr * 64 + i * 16 + lrow) * BK + lkg * 8);
        #pragma unroll
        for (int j = 0; j < 4; ++j) {
            const bf16x8 bh = *(const bf16x8*)(Bsl + (wc * 64 + j * 16 + lrow) * BK + lkg * 8);
            #pragma unroll
            for (int i = 0; i < 4; ++i)
                acc[i][j] = __builtin_amdgcn_mfma_f32_16x16x32_bf16(af[i], bh, acc[i][j], 0, 0, 0);
        }
    }

    #pragma unroll
    for (int i = 0; i < 4; ++i) {
        #pragma unroll
        for (int r = 0; r < 4; ++r) {
            const int row = m0 + wr * 64 + i * 16 + lkg * 4 + r;
            #pragma unroll
            for (int j = 0; j < 4; ++j) {
                const int col = n0 + wc * 64 + j * 16 + lrow;
                const float bj = bias ? bias[col] : 0.0f;
                out[(size_t)row * ldo + col] = acc[i][j][r] + bj;
            }
        }
    }
}

// ---------------- MFMA flash attention, pre-split hi/lo qkv input; split hi/lo output ----------------
#define QBLK 64
#define KVBLK 64

__global__ __launch_bounds__(256)
void attn_mfma_kernel(const unsigned short* __restrict__ qh_g,
                      const unsigned short* __restrict__ ql_g,
                      unsigned short* __restrict__ oh_g,
                      unsigned short* __restrict__ ol_g)
{
    __shared__ short Kh[2][KVBLK][PADK];
    __shared__ short Kl[2][KVBLK][PADK];
    __shared__ short Vh[2][HSD][PADK];
    __shared__ short Vl[2][HSD][PADK];
    __shared__ short Ph[4][2][16][PADK];
    __shared__ short Pl[4][2][16][PADK];

    const int t0 = blockIdx.x * QBLK;
    const int bh = blockIdx.y;
    const int b = bh / HCNT, hh = bh % HCNT;
    const size_t baseq = (size_t)b * TT * QKVLD + (size_t)hh * HSD;
    const size_t obase = (size_t)b * TT * CDIM + (size_t)hh * HSD;
    const unsigned short* kh_g = qh_g + baseq + CDIM;
    const unsigned short* kl_g = ql_g + baseq + CDIM;
    const unsigned short* vh_g = qh_g + baseq + 2 * CDIM;
    const unsigned short* vl_g = ql_g + baseq + 2 * CDIM;
    const int tid = threadIdx.x;
    const int w = tid >> 6, lane = tid & 63;
    const int lrow = lane & 15, lkg = lane >> 4;
    const float sscale = rsqrtf((float)CDIM);

    bf16x8 qh[2], ql[2];
    {
        const size_t qroff = baseq + (size_t)(t0 + w * 16 + lrow) * QKVLD;
        #pragma unroll
        for (int ks = 0; ks < 2; ++ks) {
            qh[ks] = *(const bf16x8*)(qh_g + qroff + ks * 32 + lkg * 8);
            ql[ks] = *(const bf16x8*)(ql_g + qroff + ks * 32 + lkg * 8);
        }
    }

    f32x4 oacc[4] = {};
    float m_[4], l_[4];
    #pragma unroll
    for (int rr = 0; rr < 4; ++rr) { m_[rr] = -1e30f; l_[rr] = 0.0f; }

    for (int s0 = 0; s0 <= t0 + QBLK - 1; s0 += KVBLK) {
        __syncthreads();
        {   // stage K (pure copies)
            const int srow = tid >> 3, skg = (tid & 7) * 4;
            #pragma unroll
            for (int p = 0; p < 2; ++p) {
                const size_t kroff = (size_t)(s0 + p * 32 + srow) * QKVLD;
                #pragma unroll
                for (int ks = 0; ks < 2; ++ks) {
                    *(ushort4*)(&Kh[ks][p * 32 + srow][skg]) = *(const ushort4*)(kh_g + kroff + ks * 32 + skg);
                    *(ushort4*)(&Kl[ks][p * 32 + srow][skg]) = *(const ushort4*)(kl_g + kroff + ks * 32 + skg);
                }
            }
            // stage V transposed (pure copies)
            const int key = tid & 63, dg = (tid >> 6) * 16;
            const size_t vroff = (size_t)(s0 + key) * QKVLD + dg;
            const int kst = key >> 5, ko = key & 31;
            #pragma unroll
            for (int dd = 0; dd < 16; dd += 4) {
                ushort4 hv = *(const ushort4*)(vh_g + vroff + dd);
                ushort4 lv = *(const ushort4*)(vl_g + vroff + dd);
                Vh[kst][dg + dd + 0][ko] = hv.x; Vl[kst][dg + dd + 0][ko] = lv.x;
                Vh[kst][dg + dd + 1][ko] = hv.y; Vl[kst][dg + dd + 1][ko] = lv.y;
                Vh[kst][dg + dd + 2][ko] = hv.z; Vl[kst][dg + dd + 2][ko] = lv.z;
                Vh[kst][dg + dd + 3][ko] = hv.w; Vl[kst][dg + dd + 3][ko] = lv.w;
            }
        }
        __syncthreads();

        f32x4 sacc[4] = {};
        #pragma unroll
        for (int j = 0; j < 4; ++j) {
            #pragma unroll
            for (int ks = 0; ks < 2; ++ks) {
                const bf16x8 bh = *(const bf16x8*)(&Kh[ks][j * 16 + lrow][lkg * 8]);
                const bf16x8 bl = *(const bf16x8*)(&Kl[ks][j * 16 + lrow][lkg * 8]);
                sacc[j] = __builtin_amdgcn_mfma_f32_16x16x32_bf16(qh[ks], bh, sacc[j], 0, 0, 0);
                sacc[j] = __builtin_amdgcn_mfma_f32_16x16x32_bf16(ql[ks], bh, sacc[j], 0, 0, 0);
                sacc[j] = __builtin_amdgcn_mfma_f32_16x16x32_bf16(qh[ks], bl, sacc[j], 0, 0, 0);
            }
        }

        #pragma unroll
        for (int rr = 0; rr < 4; ++rr) {
            const int qi = t0 + w * 16 + lkg * 4 + rr;
            float pv[4];
            float mx = -1e30f;
            #pragma unroll
            for (int j = 0; j < 4; ++j) {
                float s = sacc[j][rr] * sscale;
                if (s0 + j * 16 + lrow > qi) s = -1e30f;
                pv[j] = s;
                mx = fmaxf(mx, s);
            }
            #pragma unroll
            for (int off = 1; off < 16; off <<= 1) mx = fmaxf(mx, __shfl_xor(mx, off));
            const float mnew = fmaxf(m_[rr], mx);
            const float corr = __expf(m_[rr] - mnew);
            float ps = 0.0f;
            #pragma unroll
            for (int j = 0; j < 4; ++j) { pv[j] = __expf(pv[j] - mnew); ps += pv[j]; }
            #pragma unroll
            for (int off = 1; off < 16; off <<= 1) ps += __shfl_xor(ps, off);
            l_[rr] = l_[rr] * corr + ps;
            m_[rr] = mnew;
            #pragma unroll
            for (int jd = 0; jd < 4; ++jd) oacc[jd][rr] *= corr;
            #pragma unroll
            for (int j = 0; j < 4; ++j) {
                unsigned short h, l;
                split2(pv[j], h, l);
                const int key = j * 16 + lrow;
                Ph[w][key >> 5][lkg * 4 + rr][key & 31] = h;
                Pl[w][key >> 5][lkg * 4 + rr][key & 31] = l;
            }
        }

        #pragma unroll
        for (int ks = 0; ks < 2; ++ks) {
            const bf16x8 ah = *(const bf16x8*)(&Ph[w][ks][lrow][lkg * 8]);
            const bf16x8 al = *(const bf16x8*)(&Pl[w][ks][lrow][lkg * 8]);
            #pragma unroll
            for (int jd = 0; jd < 4; ++jd) {
                const bf16x8 bh = *(const bf16x8*)(&Vh[ks][jd * 16 + lrow][lkg * 8]);
                const bf16x8 bl = *(const bf16x8*)(&Vl[ks][jd * 16 + lrow][lkg * 8]);
                oacc[jd] = __builtin_amdgcn_mfma_f32_16x16x32_bf16(ah, bh, oacc[jd], 0, 0, 0);
                oacc[jd] = __builtin_amdgcn_mfma_f32_16x16x32_bf16(al, bh, oacc[jd], 0, 0, 0);
                oacc[jd] = __builtin_amdgcn_mfma_f32_16x16x32_bf16(ah, bl, oacc[jd], 0, 0, 0);
            }
        }
    }

    #pragma unroll
    for (int rr = 0; rr < 4; ++rr) {
        const int qi = t0 + w * 16 + lkg * 4 + rr;
        const float invl = 1.0f / l_[rr];
        const size_t orow = obase + (size_t)qi * CDIM;
        #pragma unroll
        for (int jd = 0; jd < 4; ++jd) {
            unsigned short h, l;
            split2(oacc[jd][rr] * invl, h, l);
            oh_g[orow + jd * 16 + lrow] = h;
            ol_g[orow + jd * 16 + lrow] = l;
        }
    }
}

// ---------------- gate: logits + top-2 + softmax -> sel[N], wts[N] (reads fp32 h2) ----------------
__global__ __launch_bounds__(256)
void gate_kernel(const float* __restrict__ h2, const float* __restrict__ gw,
                 int2* __restrict__ sel, float2* __restrict__ wts)
{
    __shared__ float gws[ECNT * CDIM];
    int tid = threadIdx.x;
    for (int i = tid; i < ECNT * CDIM; i += 256) gws[i] = gw[i];
    __syncthreads();
    int t = blockIdx.x * 256 + tid;
    const float* hr = h2 + (size_t)t * CDIM;
    float g[ECNT] = {};
    for (int c = 0; c < CDIM; ++c) {
        float hv = hr[c];
        #pragma unroll
        for (int e = 0; e < ECNT; ++e) g[e] = fmaf(hv, gws[e * CDIM + c], g[e]);
    }
    int e0 = 0; float g0 = g[0];
    #pragma unroll
    for (int e = 1; e < ECNT; ++e) if (g[e] > g0) { g0 = g[e]; e0 = e; }
    int e1 = -1; float g1 = -1e30f;
    #pragma unroll
    for (int e = 0; e < ECNT; ++e) if (e != e0 && g[e] > g1) { g1 = g[e]; e1 = e; }
    float z = __expf(g1 - g0);          // <= 1
    float w0 = 1.0f / (1.0f + z);
    sel[t] = make_int2(e0, e1);
    wts[t] = make_float2(w0, 1.0f - w0);
}

// ---------------- routing: build expert-grouped permutation (single block) ----------------
__global__ __launch_bounds__(256)
void route_kernel(const int2* __restrict__ sel, int* __restrict__ perm,
                  int* __restrict__ tokpos, int* __restrict__ meta)
{
    __shared__ int cnt[ECNT], off[ECNT], cur[ECNT];
    const int tid = threadIdx.x;
    if (tid < ECNT) cnt[tid] = 0;
    __syncthreads();
    for (int t = tid; t < NTOK; t += 256) {
        atomicAdd(&cnt[sel[t].x], 1);
        atomicAdd(&cnt[sel[t].y], 1);
    }
    __syncthreads();
    if (tid == 0) {
        int run = 0;
        for (int e = 0; e < ECNT; ++e) {
            off[e] = run; cur[e] = 0;
            int pc = (cnt[e] + BM - 1) / BM * BM;
            meta[2 * e] = run; meta[2 * e + 1] = pc;
            run += pc;
        }
    }
    __syncthreads();
    for (int p = tid; p < TOTCAP; p += 256) perm[p] = 0;   // pad slots -> token 0
    __syncthreads();
    for (int t = tid; t < NTOK; t += 256) {
        int2 s = sel[t];
        int p0 = atomicAdd(&cur[s.x], 1); perm[off[s.x] + p0] = t; tokpos[2 * t]     = off[s.x] + p0;
        int p1 = atomicAdd(&cur[s.y], 1); perm[off[s.y] + p1] = t; tokpos[2 * t + 1] = off[s.y] + p1;
    }
}

// ---------------- gather pre-split h2 rows into expert order (pure copy) ----------------
__global__ __launch_bounds__(256)
void gather_ps_kernel(const unsigned short* __restrict__ h2h,
                      const unsigned short* __restrict__ h2l,
                      const int* __restrict__ perm,
                      unsigned short* __restrict__ xgh,
                      unsigned short* __restrict__ xgl)
{
    int i = blockIdx.x * 256 + threadIdx.x;   // TOTCAP*CDIM
    int c = i % CDIM, p = i / CDIM;
    const size_t s = (size_t)perm[p] * CDIM + c;
    xgh[i] = h2h[s];
    xgl[i] = h2l[s];
}

// ---------------- gather hi-part rows (= f2bf(h2)) for l1 fast path ----------------
__global__ __launch_bounds__(256)
void gather_cp_kernel(const unsigned short* __restrict__ h2h, const int* __restrict__ perm,
                      unsigned short* __restrict__ xg)
{
    int i = blockIdx.x * 256 + threadIdx.x;   // TOTCAP*CDIM
    int c = i % CDIM, p = i / CDIM;
    xg[i] = h2h[(size_t)perm[p] * CDIM + c];
}

// ---------------- combine: x += w0*sum_sk(y[pos0]) + w1*sum_sk(y[pos1]) ----------------
template<int SK>
__global__ __launch_bounds__(256)
void combine_kernel(const float* __restrict__ y, size_t pstride,
                    const int* __restrict__ tokpos,
                    const float2* __restrict__ wts, float* __restrict__ x)
{
    int i = blockIdx.x * 256 + threadIdx.x;   // NTOK*CDIM
    int c = i % CDIM, t = i / CDIM;
    float2 wv = wts[t];
    const size_t r0 = (size_t)tokpos[2 * t] * CDIM + c;
    const size_t r1 = (size_t)tokpos[2 * t + 1] * CDIM + c;
    float a0 = 0.0f, a1 = 0.0f;
    #pragma unroll
    for (int s = 0; s < SK; ++s) {
        a0 += y[s * pstride + r0];
        a1 += y[s * pstride + r1];
    }
    x[i] += wv.x * a0 + wv.y * a1;
}

// ---------------- per-row cross-entropy (float4 loads) ----------------
__global__ __launch_bounds__(256)
void loss_row_kernel(const float* __restrict__ logits, const int* __restrict__ tgt,
                     float* __restrict__ lrow)
{
    int row = blockIdx.x;
    const float4* lr4 = (const float4*)(logits + (size_t)row * VOC);
    int tid = threadIdx.x, w = tid >> 6, lane = tid & 63;
    __shared__ float red[4];
    float mx = -1e30f;
    for (int i = tid; i < VOC / 4; i += 256) {
        float4 v = lr4[i];
        mx = fmaxf(mx, fmaxf(fmaxf(v.x, v.y), fmaxf(v.z, v.w)));
    }
    mx = wave_max(mx);
    if (lane == 0) red[w] = mx;
    __syncthreads();
    mx = fmaxf(fmaxf(red[0], red[1]), fmaxf(red[2], red[3]));
    __syncthreads();
    float se = 0.0f;
    for (int i = tid; i < VOC / 4; i += 256) {
        float4 v = lr4[i];
        se += expf(v.x - mx) + expf(v.y - mx) + expf(v.z - mx) + expf(v.w - mx);
    }
    se = wave_sum(se);
    if (lane == 0) red[w] = se;
    __syncthreads();
    if (tid == 0) {
        float lse = mx + logf(red[0] + red[1] + red[2] + red[3]);
        lrow[row] = lse - logits[(size_t)row * VOC + tgt[row]];
    }
}

__global__ __launch_bounds__(256)
void loss_reduce_kernel(const float* __restrict__ lrow, float* __restrict__ out)
{
    int tid = threadIdx.x, w = tid >> 6, lane = tid & 63;
    float s = 0.0f;
    for (int i = tid; i < NTOK; i += 256) s += lrow[i];
    s = wave_sum(s);
    __shared__ float red[4];
    if (lane == 0) red[w] = s;
    __syncthreads();
    if (tid == 0) out[0] = (red[0] + red[1] + red[2] + red[3]) * (1.0f / NTOK);
}

// ---------------- launch ----------------
extern "C" void kernel_launch(void* const* d_in, const int* in_sizes, int n_in,
                              void* d_out, int out_size, void* d_ws, size_t ws_size,
                              hipStream_t stream)
{
    const int*   idx     = (const int*)d_in[0];
    const int*   targets = (const int*)d_in[1];
    const float* tok_emb = (const float*)d_in[2];
    const float* pos_emb = (const float*)d_in[3];
    const float* ln1_s   = (const float*)d_in[4];
    const float* ln1_b   = (const float*)d_in[5];
    const float* wq      = (const float*)d_in[6];
    const float* wk      = (const float*)d_in[7];
    const float* wv      = (const float*)d_in[8];
    const float* wo      = (const float*)d_in[9];
    const float* bo      = (const float*)d_in[10];
    const float* ln2_s   = (const float*)d_in[11];
    const float* ln2_b   = (const float*)d_in[12];
    const float* gate_w  = (const float*)d_in[13];
    const float* w1      = (const float*)d_in[14];
    const float* b1      = (const float*)d_in[15];
    const float* w2      = (const float*)d_in[16];
    const float* b2      = (const float*)d_in[17];
    const float* lm_w    = (const float*)d_in[18];
    const float* lm_b    = (const float*)d_in[19];
    float* out = (float*)d_out;

    // ws layout
    unsigned short* wph = (unsigned short*)d_ws;                     // 3*L*C*C
    unsigned short* wpl = wph + (size_t)3 * LCNT * CDIM * CDIM;
    unsigned short* woh = wpl + (size_t)3 * LCNT * CDIM * CDIM;      // L*C*C
    unsigned short* wol = woh + (size_t)LCNT * CDIM * CDIM;
    float* x    = (float*)(wol + (size_t)LCNT * CDIM * CDIM);
    float* hbuf = x    + (size_t)NTOK * CDIM;        // LN1-split / attn-out-split (2x bf16)
    float* qkv  = hbuf + (size_t)NTOK * CDIM;        // qkvh+qkvl bf16 / h2 fp32 + h2h + h2l / ybuf
    float* xg   = qkv  + (size_t)NTOK * QKVLD;       // TOTCAP*C: xgh+xgl bf16 (l0) / xg_bf (l1)
    float* hid  = xg   + (size_t)TOTCAP * CDIM;      // TOTCAP*FF: hidh+hidl bf16 (l0) / hid_bf + lmw_bf
    float* lrow = hid  + (size_t)TOTCAP * FF;        // NTOK
    float2* wts = (float2*)(lrow + NTOK);            // NTOK float2
    int2*  sel  = (int2*)(wts + NTOK);               // NTOK int2
    int*   perm = (int*)(sel + NTOK);                // TOTCAP
    int*  tokpos= perm + TOTCAP;                     // 2*NTOK
    int*   meta = tokpos + 2 * NTOK;                 // 16
    unsigned short* x_bf = (unsigned short*)(meta + 16);  // NTOK*C bf16
    float* part = (float*)(x_bf + (size_t)NTOK * CDIM);   // SKN*TOTCAP*C partials (optional)

    const size_t need_bytes = (size_t)((char*)(part + (size_t)SKN * TOTCAP * CDIM) - (char*)d_ws);
    const bool use_sk = ws_size >= need_bytes;

    unsigned short* hbufh = (unsigned short*)hbuf;             // NTOK*C
    unsigned short* hbufl = hbufh + (size_t)NTOK * CDIM;
    unsigned short* qkvh = (unsigned short*)qkv;               // NTOK*QKVLD
    unsigned short* qkvl = qkvh + (size_t)NTOK * QKVLD;
    float*          h2   = qkv;                                // NTOK*C fp32 (gate)
    unsigned short* h2h  = (unsigned short*)(qkv + (size_t)NTOK * CDIM);
    unsigned short* h2l  = h2h + (size_t)NTOK * CDIM;
    float*          ybuf = qkv;                                // NTOK*C fp32 (after gather)
    unsigned short* xgh  = (unsigned short*)xg;                // TOTCAP*C
    unsigned short* xgl  = xgh + (size_t)TOTCAP * CDIM;
    unsigned short* xg_bf = (unsigned short*)xg;
    unsigned short* hidh = (unsigned short*)hid;               // TOTCAP*FF
    unsigned short* hidl = hidh + (size_t)TOTCAP * FF;
    unsigned short* hid_bf = (unsigned short*)hid;
    unsigned short* lmw_bf = (unsigned short*)hid;

    dim3 blk(256);

    repack_kernel<<<(3 * LCNT * CDIM * CDIM) / 256, blk, 0, stream>>>(wq, wk, wv, wph, wpl);
    splitw_kernel<<<1024, blk, 0, stream>>>(wo, woh, wol, LCNT * CDIM * CDIM / 4);
    embed_kernel<<<(NTOK * CDIM) / 256, blk, 0, stream>>>(idx, tok_emb, pos_emb, x);

    for (int l = 0; l < LCNT; ++l) {
        // LN1 -> split hi/lo only
        ln_kernel<false><<<NTOK, blk, 0, stream>>>(
            x, ln1_s + (size_t)l * CDIM, ln1_b + (size_t)l * CDIM, nullptr, hbufh, hbufl);

        // fused QKV projection (pre-split A and B) -> split hi/lo output
        gemm_ps_kernel<0, true><<<dim3(QKVLD / BN, NTOK / BM), blk, 0, stream>>>(
            CDIM, hbufh, hbufl, CDIM,
            wph + (size_t)l * 3 * CDIM * CDIM, wpl + (size_t)l * 3 * CDIM * CDIM, CDIM,
            nullptr, nullptr, qkvh, qkvl, QKVLD);

        attn_mfma_kernel<<<dim3(TT / QBLK, BB * HCNT), blk, 0, stream>>>(qkvh, qkvl, hbufh, hbufl);

        // wo projection (pre-split A and B) -> accumulate into x
        gemm_ps_kernel<1, false><<<dim3(CDIM / BN, NTOK / BM), blk, 0, stream>>>(
            CDIM, hbufh, hbufl, CDIM,
            woh + (size_t)l * CDIM * CDIM, wol + (size_t)l * CDIM * CDIM, CDIM,
            bo + (size_t)l * CDIM, x, nullptr, nullptr, CDIM);

        // --- MoE ---
        // LN2 -> fp32 (gate, bit-identical routing) + split hi/lo (experts)
        ln_kernel<true><<<NTOK, blk, 0, stream>>>(
            x, ln2_s + (size_t)l * CDIM, ln2_b + (size_t)l * CDIM, h2, h2h, h2l);
        gate_kernel<<<NTOK / 256, blk, 0, stream>>>(h2, gate_w + (size_t)l * ECNT * CDIM, sel, wts);
        route_kernel<<<1, blk, 0, stream>>>(sel, perm, tokpos, meta);

        const float* w1l = w1 + (size_t)l * ECNT * FF * CDIM;
        const float* b1l = b1 + (size_t)l * ECNT * FF;
        const float* w2l = w2 + (size_t)l * ECNT * CDIM * FF;
        const float* b2l = b2 + (size_t)l * ECNT * CDIM;
        if (l == 0) {   // feeds next layer's router -> fp32-grade (split 3-MFMA)
            gather_ps_kernel<<<(TOTCAP * CDIM) / 256, blk, 0, stream>>>(h2h, h2l, perm, xgh, xgl);
            gemm_pse_kernel<<<dim3(FF / BN, TOTCAP / BM, ECNT), blk, 0, stream>>>(
                CDIM, xgh, xgl, CDIM, w1l, CDIM, b1l, hidh, hidl, FF,
                meta, (size_t)FF * CDIM, FF);
            if (use_sk) {
                gemm_pssk_kernel<SKN><<<dim3(CDIM / BN, TOTCAP / BM, ECNT * SKN), blk, 0, stream>>>(
                    FF / SKN, hidh, hidl, FF, w2l, FF, b2l, part, CDIM, (size_t)TOTCAP * CDIM,
                    meta, (size_t)CDIM * FF, CDIM);
                combine_kernel<SKN><<<(NTOK * CDIM) / 256, blk, 0, stream>>>(
                    part, (size_t)TOTCAP * CDIM, tokpos, wts, x);
            } else {
                gemm_pssk_kernel<1><<<dim3(CDIM / BN, TOTCAP / BM, ECNT), blk, 0, stream>>>(
                    FF, hidh, hidl, FF, w2l, FF, b2l, ybuf, CDIM, 0,
                    meta, (size_t)CDIM * FF, CDIM);
                combine_kernel<1><<<(NTOK * CDIM) / 256, blk, 0, stream>>>(
                    ybuf, 0, tokpos, wts, x);
            }
        } else {        // feeds only logits -> fast 1-MFMA, bf16 activations
            gather_cp_kernel<<<(TOTCAP * CDIM) / 256, blk, 0, stream>>>(h2h, perm, xg_bf);
            gemm_fastw_kernel<2, false, true, false><<<dim3(FF / BN, TOTCAP / BM, ECNT), blk, 0, stream>>>(
                CDIM, xg_bf, CDIM, w1l, CDIM, b1l, hid_bf, FF, meta, (size_t)FF * CDIM, FF);
            gemm_fastw_kernel<0, false, false, false><<<dim3(CDIM / BN, TOTCAP / BM, ECNT), blk, 0, stream>>>(
                FF, hid_bf, FF, w2l, FF, b2l, ybuf, CDIM, meta, (size_t)CDIM * FF, CDIM);
            combine_kernel<1><<<(NTOK * CDIM) / 256, blk, 0, stream>>>(
                ybuf, 0, tokpos, wts, x);
        }
    }

    // pre-convert LM head operands to bf16 (hid region is dead now)
    cvt_bf16_kernel<<<2048, blk, 0, stream>>>(lm_w, lmw_bf, VOC * CDIM / 4);
    cvt_bf16_kernel<<<512, blk, 0, stream>>>(x, x_bf, NTOK * CDIM / 4);

    // LM head: bf16 x bf16 via global_load_lds staging, XCD-aware m-fastest swizzle
    gemm_lds_kernel<true><<<dim3(VOC / BN, NTOK / BM), blk, 0, stream>>>(
        CDIM, x_bf, CDIM, lmw_bf, CDIM, lm_b, out, VOC);

    loss_row_kernel<<<NTOK, blk, 0, stream>>>(out, targets, lrow);
    loss_reduce_kernel<<<1, blk, 0, stream>>>(lrow, out + (size_t)NTOK * VOC);
}

// Round 12
// 1318.504 us; speedup vs baseline: 9.7015x; 1.0076x over previous
//
#include <hip/hip_runtime.h>
#include <hip/hip_bf16.h>

// Problem constants (from reference)
#define LCNT 2
#define HCNT 12
#define CDIM 768
#define HSD  64
#define ECNT 8
#define VOC  32000
#define BB   2
#define TT   1024
#define NTOK 2048   // B*T
#define FF   3072   // 4*C
#define QKVLD 2304  // 3*C
#define TOTCAP 5120 // 2*NTOK + 8*128 padding capacity
#define SKN  4      // split-K factor for l0 w2

typedef __attribute__((ext_vector_type(8))) short bf16x8;
typedef __attribute__((ext_vector_type(4))) float f32x4;

// ---------------- helpers ----------------
__device__ __forceinline__ float wave_sum(float v) {
    #pragma unroll
    for (int off = 32; off; off >>= 1) v += __shfl_xor(v, off);
    return v;
}
__device__ __forceinline__ float wave_max(float v) {
    #pragma unroll
    for (int off = 32; off; off >>= 1) v = fmaxf(v, __shfl_xor(v, off));
    return v;
}
__device__ __forceinline__ unsigned short f2bf(float f) {
    unsigned int u = __float_as_uint(f);
    unsigned int r = (u + 0x7FFFu + ((u >> 16) & 1u)) >> 16;
    return (unsigned short)r;
}
__device__ __forceinline__ float bf2f(unsigned short h) {
    return __uint_as_float((unsigned int)h << 16);
}
__device__ __forceinline__ void split2(float a, unsigned short& h, unsigned short& l) {
    h = f2bf(a);
    l = f2bf(a - bf2f(h));
}
__device__ __forceinline__ ushort4 cvt4(float4 v) {
    ushort4 r;
    r.x = f2bf(v.x); r.y = f2bf(v.y); r.z = f2bf(v.z); r.w = f2bf(v.w);
    return r;
}
// async 16B global->LDS (dest = wave-uniform base + lane*16)
__device__ __forceinline__ void gload16(const void* g, void* l) {
    __builtin_amdgcn_global_load_lds(
        (const __attribute__((address_space(1))) unsigned int*)g,
        (__attribute__((address_space(3))) unsigned int*)l,
        16, 0, 0);
}

// ---------------- fp32 -> bf16 bulk convert ----------------
__global__ __launch_bounds__(256)
void cvt_bf16_kernel(const float* __restrict__ in, unsigned short* __restrict__ out, int n4)
{
    for (int i = blockIdx.x * 256 + threadIdx.x; i < n4; i += gridDim.x * 256) {
        float4 v = reinterpret_cast<const float4*>(in)[i];
        reinterpret_cast<ushort4*>(out)[i] = cvt4(v);
    }
}

// ---------------- fp32 -> split hi/lo bf16 bulk ----------------
__global__ __launch_bounds__(256)
void splitw_kernel(const float* __restrict__ in, unsigned short* __restrict__ oh,
                   unsigned short* __restrict__ ol, int n4)
{
    for (int i = blockIdx.x * 256 + threadIdx.x; i < n4; i += gridDim.x * 256) {
        float4 v = reinterpret_cast<const float4*>(in)[i];
        ushort4 h, l;
        split2(v.x, h.x, l.x); split2(v.y, h.y, l.y);
        split2(v.z, h.z, l.z); split2(v.w, h.w, l.w);
        reinterpret_cast<ushort4*>(oh)[i] = h;
        reinterpret_cast<ushort4*>(ol)[i] = l;
    }
}

// ---------------- embedding ----------------
__global__ __launch_bounds__(256)
void embed_kernel(const int* __restrict__ idx, const float* __restrict__ tok,
                  const float* __restrict__ pos, float* __restrict__ x)
{
    int i = blockIdx.x * 256 + threadIdx.x;      // N*C total
    int c = i % CDIM;
    int n = i / CDIM;
    int t = n % TT;
    x[i] = tok[(size_t)idx[n] * CDIM + c] + pos[(size_t)t * CDIM + c];
}

// ---------------- repack wq/wk/wv [L,H,C,HS] -> split hi/lo [l][w3*C + n][k] (fused B^T) ----------------
__global__ __launch_bounds__(256)
void repack_kernel(const float* __restrict__ wq, const float* __restrict__ wk,
                   const float* __restrict__ wv, unsigned short* __restrict__ wph,
                   unsigned short* __restrict__ wpl)
{
    int i = blockIdx.x * 256 + threadIdx.x;      // 3*L*C*C
    int kk = i % CDIM;
    int n  = (i / CDIM) % CDIM;
    int w3 = (i / (CDIM * CDIM)) % 3;
    int l  = i / (CDIM * CDIM * 3);
    const float* src = (w3 == 0) ? wq : (w3 == 1) ? wk : wv;
    int h = n / HSD, d = n % HSD;
    float v = src[((((size_t)l * HCNT + h) * CDIM) + kk) * HSD + d];
    unsigned short hh, ll;
    split2(v, hh, ll);
    size_t o = (((size_t)l * 3 + w3) * CDIM + n) * CDIM + kk;
    wph[o] = hh;
    wpl[o] = ll;
}

// ---------------- layernorm; emits split hi/lo (+ optional fp32) ----------------
template<bool WF32>
__global__ __launch_bounds__(256)
void ln_kernel(const float* __restrict__ x, const float* __restrict__ sc,
               const float* __restrict__ bs, float* __restrict__ out,
               unsigned short* __restrict__ oh, unsigned short* __restrict__ ol)
{
    int row = blockIdx.x;
    const float* xr = x + (size_t)row * CDIM;
    int tid = threadIdx.x;
    float v0 = xr[tid], v1 = xr[tid + 256], v2 = xr[tid + 512];
    float s1 = v0 + v1 + v2;
    float s2 = v0 * v0 + v1 * v1 + v2 * v2;
    s1 = wave_sum(s1);
    s2 = wave_sum(s2);
    __shared__ float r1[4], r2[4];
    int w = tid >> 6, lane = tid & 63;
    if (lane == 0) { r1[w] = s1; r2[w] = s2; }
    __syncthreads();
    float t1 = r1[0] + r1[1] + r1[2] + r1[3];
    float t2 = r2[0] + r2[1] + r2[2] + r2[3];
    float mu = t1 * (1.0f / CDIM);
    float var = t2 * (1.0f / CDIM) - mu * mu;
    float rstd = rsqrtf(var + 1e-5f);
    float o0 = (v0 - mu) * rstd * sc[tid]       + bs[tid];
    float o1 = (v1 - mu) * rstd * sc[tid + 256] + bs[tid + 256];
    float o2 = (v2 - mu) * rstd * sc[tid + 512] + bs[tid + 512];
    if constexpr (WF32) {
        float* orow = out + (size_t)row * CDIM;
        orow[tid] = o0; orow[tid + 256] = o1; orow[tid + 512] = o2;
    }
    unsigned short h, l;
    unsigned short* ohr = oh + (size_t)row * CDIM;
    unsigned short* olr = ol + (size_t)row * CDIM;
    split2(o0, h, l); ohr[tid]       = h; olr[tid]       = l;
    split2(o1, h, l); ohr[tid + 256] = h; olr[tid + 256] = l;
    split2(o2, h, l); ohr[tid + 512] = h; olr[tid + 512] = l;
}

#define BM 128
#define BN 128
#define BK 32
#define PADK 40   // bf16 stride per row (80 B)

// ---------------- split GEMM, BOTH operands pre-split hi/lo bf16 (pure-copy staging) ----------------
// MODE 0: store fp32 (or OUTSPLIT hi/lo) ; MODE 1: accumulate fp32
template<int MODE, bool OUTSPLIT>
__global__ __launch_bounds__(256)
void gemm_ps_kernel(int Kd,
                    const unsigned short* __restrict__ Ahg,
                    const unsigned short* __restrict__ Alg, int lda,
                    const unsigned short* __restrict__ Bhg,
                    const unsigned short* __restrict__ Blg, int ldb,
                    const float* __restrict__ bias,
                    float* __restrict__ out,
                    unsigned short* __restrict__ outh,
                    unsigned short* __restrict__ outl, int ldo)
{
    __shared__ short Ah[BM * PADK];
    __shared__ short Al[BM * PADK];
    __shared__ short Bh[BN * PADK];
    __shared__ short Bl[BN * PADK];

    const int tid = threadIdx.x;
    const int m0 = blockIdx.y * BM;
    const int n0 = blockIdx.x * BN;
    const int w = tid >> 6, lane = tid & 63;
    const int wr = w >> 1, wc = w & 1;
    const int lrow = lane & 15, lkg = lane >> 4;
    const int srow = tid >> 3, skg = (tid & 7) * 4;

    const unsigned short* Ahb = Ahg + (size_t)m0 * lda;
    const unsigned short* Alb = Alg + (size_t)m0 * lda;
    const unsigned short* Bhb = Bhg + (size_t)n0 * ldb;
    const unsigned short* Blb = Blg + (size_t)n0 * ldb;

    ushort4 pah[4], pal[4], pbh[4], pbl[4];
    #pragma unroll
    for (int p = 0; p < 4; ++p) {
        pah[p] = *(const ushort4*)(Ahb + (size_t)(p * 32 + srow) * lda + skg);
        pal[p] = *(const ushort4*)(Alb + (size_t)(p * 32 + srow) * lda + skg);
        pbh[p] = *(const ushort4*)(Bhb + (size_t)(p * 32 + srow) * ldb + skg);
        pbl[p] = *(const ushort4*)(Blb + (size_t)(p * 32 + srow) * ldb + skg);
    }

    f32x4 acc[4][4] = {};
    const int nk = Kd / BK;

    for (int t = 0; t < nk; ++t) {
        __syncthreads();
        #pragma unroll
        for (int p = 0; p < 4; ++p) {
            *(ushort4*)(&Ah[(p * 32 + srow) * PADK + skg]) = pah[p];
            *(ushort4*)(&Al[(p * 32 + srow) * PADK + skg]) = pal[p];
            *(ushort4*)(&Bh[(p * 32 + srow) * PADK + skg]) = pbh[p];
            *(ushort4*)(&Bl[(p * 32 + srow) * PADK + skg]) = pbl[p];
        }
        __syncthreads();
        if (t + 1 < nk) {
            const int kb = (t + 1) * BK + skg;
            #pragma unroll
            for (int p = 0; p < 4; ++p) {
                pah[p] = *(const ushort4*)(Ahb + (size_t)(p * 32 + srow) * lda + kb);
                pal[p] = *(const ushort4*)(Alb + (size_t)(p * 32 + srow) * lda + kb);
                pbh[p] = *(const ushort4*)(Bhb + (size_t)(p * 32 + srow) * ldb + kb);
                pbl[p] = *(const ushort4*)(Blb + (size_t)(p * 32 + srow) * ldb + kb);
            }
        }
        bf16x8 afh[4], afl[4];
        #pragma unroll
        for (int i = 0; i < 4; ++i) {
            afh[i] = *(const bf16x8*)(&Ah[(wr * 64 + i * 16 + lrow) * PADK + lkg * 8]);
            afl[i] = *(const bf16x8*)(&Al[(wr * 64 + i * 16 + lrow) * PADK + lkg * 8]);
        }
        #pragma unroll
        for (int j = 0; j < 4; ++j) {
            const bf16x8 bh = *(const bf16x8*)(&Bh[(wc * 64 + j * 16 + lrow) * PADK + lkg * 8]);
            const bf16x8 bl = *(const bf16x8*)(&Bl[(wc * 64 + j * 16 + lrow) * PADK + lkg * 8]);
            #pragma unroll
            for (int i = 0; i < 4; ++i) {
                acc[i][j] = __builtin_amdgcn_mfma_f32_16x16x32_bf16(afh[i], bh, acc[i][j], 0, 0, 0);
                acc[i][j] = __builtin_amdgcn_mfma_f32_16x16x32_bf16(afl[i], bh, acc[i][j], 0, 0, 0);
                acc[i][j] = __builtin_amdgcn_mfma_f32_16x16x32_bf16(afh[i], bl, acc[i][j], 0, 0, 0);
            }
        }
    }

    #pragma unroll
    for (int i = 0; i < 4; ++i) {
        #pragma unroll
        for (int r = 0; r < 4; ++r) {
            const int row = m0 + wr * 64 + i * 16 + lkg * 4 + r;
            #pragma unroll
            for (int j = 0; j < 4; ++j) {
                const int col = n0 + wc * 64 + j * 16 + lrow;
                const float bj = bias ? bias[col] : 0.0f;
                const float vres = acc[i][j][r] + bj;
                if constexpr (OUTSPLIT) {
                    unsigned short h, l;
                    split2(vres, h, l);
                    outh[(size_t)row * ldo + col] = h;
                    outl[(size_t)row * ldo + col] = l;
                } else {
                    float* op = out + (size_t)row * ldo + col;
                    if (MODE == 0) *op = vres;
                    else *op = *op + vres;
                }
            }
        }
    }
}

// ---------------- expert split GEMM: A pre-split (pure copy), B fp32 inline-split ----------------
// epilogue: relu + split hi/lo store (l0 w1)
__global__ __launch_bounds__(256)
void gemm_pse_kernel(int Kd,
                     const unsigned short* __restrict__ Ahg,
                     const unsigned short* __restrict__ Alg, int lda,
                     const float* __restrict__ B, int ldb,
                     const float* __restrict__ bias,
                     unsigned short* __restrict__ outh,
                     unsigned short* __restrict__ outl, int ldo,
                     const int* __restrict__ rowmeta,
                     size_t bstride, int biasstride)
{
    __shared__ short Ah[BM * PADK];
    __shared__ short Al[BM * PADK];
    __shared__ short Bh[BN * PADK];
    __shared__ short Bl[BN * PADK];

    const int ee = blockIdx.z;
    const int rcnt = rowmeta[2 * ee + 1];
    if ((int)(blockIdx.y * BM) >= rcnt) return;
    const int roff = rowmeta[2 * ee];
    B += (size_t)ee * bstride;
    bias += (size_t)ee * biasstride;

    const int tid = threadIdx.x;
    const int m0 = roff + blockIdx.y * BM;
    const int n0 = blockIdx.x * BN;
    const int w = tid >> 6, lane = tid & 63;
    const int wr = w >> 1, wc = w & 1;
    const int lrow = lane & 15, lkg = lane >> 4;
    const int srow = tid >> 3, skg = (tid & 7) * 4;

    const unsigned short* Ahb = Ahg + (size_t)m0 * lda;
    const unsigned short* Alb = Alg + (size_t)m0 * lda;
    const float* Bblk = B + (size_t)n0 * ldb;

    ushort4 pah[4], pal[4];
    float4 pb[4];
    #pragma unroll
    for (int p = 0; p < 4; ++p) {
        pah[p] = *(const ushort4*)(Ahb + (size_t)(p * 32 + srow) * lda + skg);
        pal[p] = *(const ushort4*)(Alb + (size_t)(p * 32 + srow) * lda + skg);
        pb[p]  = *(const float4*)(Bblk + (size_t)(p * 32 + srow) * ldb + skg);
    }

    f32x4 acc[4][4] = {};
    const int nk = Kd / BK;

    for (int t = 0; t < nk; ++t) {
        __syncthreads();
        #pragma unroll
        for (int p = 0; p < 4; ++p) {
            *(ushort4*)(&Ah[(p * 32 + srow) * PADK + skg]) = pah[p];
            *(ushort4*)(&Al[(p * 32 + srow) * PADK + skg]) = pal[p];
            ushort4 h, l;
            split2(pb[p].x, h.x, l.x); split2(pb[p].y, h.y, l.y);
            split2(pb[p].z, h.z, l.z); split2(pb[p].w, h.w, l.w);
            *(ushort4*)(&Bh[(p * 32 + srow) * PADK + skg]) = h;
            *(ushort4*)(&Bl[(p * 32 + srow) * PADK + skg]) = l;
        }
        __syncthreads();
        if (t + 1 < nk) {
            const int kb = (t + 1) * BK + skg;
            #pragma unroll
            for (int p = 0; p < 4; ++p) {
                pah[p] = *(const ushort4*)(Ahb + (size_t)(p * 32 + srow) * lda + kb);
                pal[p] = *(const ushort4*)(Alb + (size_t)(p * 32 + srow) * lda + kb);
                pb[p]  = *(const float4*)(Bblk + (size_t)(p * 32 + srow) * ldb + kb);
            }
        }
        bf16x8 afh[4], afl[4];
        #pragma unroll
        for (int i = 0; i < 4; ++i) {
            afh[i] = *(const bf16x8*)(&Ah[(wr * 64 + i * 16 + lrow) * PADK + lkg * 8]);
            afl[i] = *(const bf16x8*)(&Al[(wr * 64 + i * 16 + lrow) * PADK + lkg * 8]);
        }
        #pragma unroll
        for (int j = 0; j < 4; ++j) {
            const bf16x8 bh = *(const bf16x8*)(&Bh[(wc * 64 + j * 16 + lrow) * PADK + lkg * 8]);
            const bf16x8 bl = *(const bf16x8*)(&Bl[(wc * 64 + j * 16 + lrow) * PADK + lkg * 8]);
            #pragma unroll
            for (int i = 0; i < 4; ++i) {
                acc[i][j] = __builtin_amdgcn_mfma_f32_16x16x32_bf16(afh[i], bh, acc[i][j], 0, 0, 0);
                acc[i][j] = __builtin_amdgcn_mfma_f32_16x16x32_bf16(afl[i], bh, acc[i][j], 0, 0, 0);
                acc[i][j] = __builtin_amdgcn_mfma_f32_16x16x32_bf16(afh[i], bl, acc[i][j], 0, 0, 0);
            }
        }
    }

    #pragma unroll
    for (int i = 0; i < 4; ++i) {
        #pragma unroll
        for (int r = 0; r < 4; ++r) {
            const int row = m0 + wr * 64 + i * 16 + lkg * 4 + r;
            #pragma unroll
            for (int j = 0; j < 4; ++j) {
                const int col = n0 + wc * 64 + j * 16 + lrow;
                const float vres = fmaxf(acc[i][j][r] + bias[col], 0.0f);
                unsigned short h, l;
                split2(vres, h, l);
                outh[(size_t)row * ldo + col] = h;
                outl[(size_t)row * ldo + col] = l;
            }
        }
    }
}

// ---------------- split-K expert GEMM: A pre-split (pure copy), B fp32 inline-split ----------------
// blockIdx.z = ee*SK + kz; partial outputs; bias only at kz==0.
template<int SK>
__global__ __launch_bounds__(256)
void gemm_pssk_kernel(int Kc,
                      const unsigned short* __restrict__ Ahg,
                      const unsigned short* __restrict__ Alg, int lda,
                      const float* __restrict__ B, int ldb,
                      const float* __restrict__ bias,
                      float* __restrict__ part, int ldo, size_t pstride,
                      const int* __restrict__ rowmeta,
                      size_t bstride, int biasstride)
{
    __shared__ short Ah[BM * PADK];
    __shared__ short Al[BM * PADK];
    __shared__ short Bh[BN * PADK];
    __shared__ short Bl[BN * PADK];

    const int zz = blockIdx.z;
    const int ee = zz / SK, kz = zz % SK;
    const int rcnt = rowmeta[2 * ee + 1];
    if ((int)(blockIdx.y * BM) >= rcnt) return;
    const int roff = rowmeta[2 * ee];
    const float* Bp = B + (size_t)ee * bstride + (size_t)kz * Kc;
    const unsigned short* Ahp = Ahg + (size_t)kz * Kc;
    const unsigned short* Alp = Alg + (size_t)kz * Kc;
    const float* biasp = (kz == 0) ? bias + (size_t)ee * biasstride : nullptr;
    float* out = part + (size_t)kz * pstride;

    const int tid = threadIdx.x;
    const int m0 = roff + blockIdx.y * BM;
    const int n0 = blockIdx.x * BN;
    const int w = tid >> 6, lane = tid & 63;
    const int wr = w >> 1, wc = w & 1;
    const int lrow = lane & 15, lkg = lane >> 4;
    const int srow = tid >> 3, skg = (tid & 7) * 4;

    const unsigned short* Ahb = Ahp + (size_t)m0 * lda;
    const unsigned short* Alb = Alp + (size_t)m0 * lda;
    const float* Bblk = Bp + (size_t)n0 * ldb;

    ushort4 pah[4], pal[4];
    float4 pb[4];
    #pragma unroll
    for (int p = 0; p < 4; ++p) {
        pah[p] = *(const ushort4*)(Ahb + (size_t)(p * 32 + srow) * lda + skg);
        pal[p] = *(const ushort4*)(Alb + (size_t)(p * 32 + srow) * lda + skg);
        pb[p]  = *(const float4*)(Bblk + (size_t)(p * 32 + srow) * ldb + skg);
    }

    f32x4 acc[4][4] = {};
    const int nk = Kc / BK;

    for (int t = 0; t < nk; ++t) {
        __syncthreads();
        #pragma unroll
        for (int p = 0; p < 4; ++p) {
            *(ushort4*)(&Ah[(p * 32 + srow) * PADK + skg]) = pah[p];
            *(ushort4*)(&Al[(p * 32 + srow) * PADK + skg]) = pal[p];
            ushort4 h, l;
            split2(pb[p].x, h.x, l.x); split2(pb[p].y, h.y, l.y);
            split2(pb[p].z, h.z, l.z); split2(pb[p].w, h.w, l.w);
            *(ushort4*)(&Bh[(p * 32 + srow) * PADK + skg]) = h;
            *(ushort4*)(&Bl[(p * 32 + srow) * PADK + skg]) = l;
        }
        __syncthreads();
        if (t + 1 < nk) {
            const int kb = (t + 1) * BK + skg;
            #pragma unroll
            for (int p = 0; p < 4; ++p) {
                pah[p] = *(const ushort4*)(Ahb + (size_t)(p * 32 + srow) * lda + kb);
                pal[p] = *(const ushort4*)(Alb + (size_t)(p * 32 + srow) * lda + kb);
                pb[p]  = *(const float4*)(Bblk + (size_t)(p * 32 + srow) * ldb + kb);
            }
        }
        bf16x8 afh[4], afl[4];
        #pragma unroll
        for (int i = 0; i < 4; ++i) {
            afh[i] = *(const bf16x8*)(&Ah[(wr * 64 + i * 16 + lrow) * PADK + lkg * 8]);
            afl[i] = *(const bf16x8*)(&Al[(wr * 64 + i * 16 + lrow) * PADK + lkg * 8]);
        }
        #pragma unroll
        for (int j = 0; j < 4; ++j) {
            const bf16x8 bh = *(const bf16x8*)(&Bh[(wc * 64 + j * 16 + lrow) * PADK + lkg * 8]);
            const bf16x8 bl = *(const bf16x8*)(&Bl[(wc * 64 + j * 16 + lrow) * PADK + lkg * 8]);
            #pragma unroll
            for (int i = 0; i < 4; ++i) {
                acc[i][j] = __builtin_amdgcn_mfma_f32_16x16x32_bf16(afh[i], bh, acc[i][j], 0, 0, 0);
                acc[i][j] = __builtin_amdgcn_mfma_f32_16x16x32_bf16(afl[i], bh, acc[i][j], 0, 0, 0);
                acc[i][j] = __builtin_amdgcn_mfma_f32_16x16x32_bf16(afh[i], bl, acc[i][j], 0, 0, 0);
            }
        }
    }

    #pragma unroll
    for (int i = 0; i < 4; ++i) {
        #pragma unroll
        for (int r = 0; r < 4; ++r) {
            const int row = m0 + wr * 64 + i * 16 + lkg * 4 + r;
            #pragma unroll
            for (int j = 0; j < 4; ++j) {
                const int col = n0 + wc * 64 + j * 16 + lrow;
                const float bj = biasp ? biasp[col] : 0.0f;
                out[(size_t)row * ldo + col] = acc[i][j][r] + bj;
            }
        }
    }
}

// ---------------- fast bf16 GEMM, pre-converted A (B fp32 inline or bf16), reg-staged ----------------
template<int MODE, bool SWZ, bool OUTBF, bool BBF>
__global__ __launch_bounds__(256)
void gemm_fastw_kernel(int Kd,
                       const unsigned short* __restrict__ A, int lda,
                       const void* __restrict__ Bv, int ldb,
                       const float* __restrict__ bias,
                       void* __restrict__ outv, int ldo,
                       const int* __restrict__ rowmeta,
                       size_t bstride, int biasstride)
{
    __shared__ short Ah[BM * PADK];
    __shared__ short Bh[BN * PADK];

    int bx = blockIdx.x, by = blockIdx.y;
    if constexpr (SWZ) {
        const int nwg = gridDim.x * gridDim.y;
        const int chunk = nwg >> 3;
        const int flat = by * gridDim.x + bx;
        const int newid = (flat & 7) * chunk + (flat >> 3);
        by = newid % gridDim.y;
        bx = newid / gridDim.y;
    }

    const float* Bf = (const float*)Bv;
    const unsigned short* Bb = (const unsigned short*)Bv;
    float* outf = (float*)outv;
    unsigned short* outb = (unsigned short*)outv;

    int roff = 0;
    if (rowmeta) {
        const int ee = blockIdx.z;
        const int rcnt = rowmeta[2 * ee + 1];
        if ((int)(by * BM) >= rcnt) return;
        roff = rowmeta[2 * ee];
        if (BBF) Bb += (size_t)ee * bstride; else Bf += (size_t)ee * bstride;
        if (bias) bias += (size_t)ee * biasstride;
    }

    const int tid = threadIdx.x;
    const int m0 = roff + by * BM;
    const int n0 = bx * BN;
    const int w = tid >> 6, lane = tid & 63;
    const int wr = w >> 1, wc = w & 1;
    const int lrow = lane & 15, lkg = lane >> 4;
    const int srow = tid >> 3, skg = (tid & 7) * 4;

    const unsigned short* Ablk = A + (size_t)m0 * lda;
    const float* Bfblk = Bf + (size_t)n0 * ldb;
    const unsigned short* Bbblk = Bb + (size_t)n0 * ldb;

    ushort4 pa[4];
    ushort4 pbb[4];
    float4  pbf[4];
    #pragma unroll
    for (int p = 0; p < 4; ++p) {
        pa[p] = *(const ushort4*)(Ablk + (size_t)(p * 32 + srow) * lda + skg);
        if constexpr (BBF) pbb[p] = *(const ushort4*)(Bbblk + (size_t)(p * 32 + srow) * ldb + skg);
        else               pbf[p] = *(const float4*)(Bfblk + (size_t)(p * 32 + srow) * ldb + skg);
    }

    f32x4 acc[4][4] = {};
    const int nk = Kd / BK;

    for (int t = 0; t < nk; ++t) {
        __syncthreads();
        #pragma unroll
        for (int p = 0; p < 4; ++p) {
            *(ushort4*)(&Ah[(p * 32 + srow) * PADK + skg]) = pa[p];
            *(ushort4*)(&Bh[(p * 32 + srow) * PADK + skg]) = BBF ? pbb[p] : cvt4(pbf[p]);
        }
        __syncthreads();
        if (t + 1 < nk) {
            const int kb = (t + 1) * BK + skg;
            #pragma unroll
            for (int p = 0; p < 4; ++p) {
                pa[p] = *(const ushort4*)(Ablk + (size_t)(p * 32 + srow) * lda + kb);
                if constexpr (BBF) pbb[p] = *(const ushort4*)(Bbblk + (size_t)(p * 32 + srow) * ldb + kb);
                else               pbf[p] = *(const float4*)(Bfblk + (size_t)(p * 32 + srow) * ldb + kb);
            }
        }
        bf16x8 af[4];
        #pragma unroll
        for (int i = 0; i < 4; ++i)
            af[i] = *(const bf16x8*)(&Ah[(wr * 64 + i * 16 + lrow) * PADK + lkg * 8]);
        #pragma unroll
        for (int j = 0; j < 4; ++j) {
            const bf16x8 bh = *(const bf16x8*)(&Bh[(wc * 64 + j * 16 + lrow) * PADK + lkg * 8]);
            #pragma unroll
            for (int i = 0; i < 4; ++i)
                acc[i][j] = __builtin_amdgcn_mfma_f32_16x16x32_bf16(af[i], bh, acc[i][j], 0, 0, 0);
        }
    }

    #pragma unroll
    for (int i = 0; i < 4; ++i) {
        #pragma unroll
        for (int r = 0; r < 4; ++r) {
            const int row = m0 + wr * 64 + i * 16 + lkg * 4 + r;
            #pragma unroll
            for (int j = 0; j < 4; ++j) {
                const int col = n0 + wc * 64 + j * 16 + lrow;
                const float bj = bias ? bias[col] : 0.0f;
                float vres = acc[i][j][r] + bj;
                if (MODE == 2) vres = fmaxf(vres, 0.0f);
                if constexpr (OUTBF) outb[(size_t)row * ldo + col] = f2bf(vres);
                else                 outf[(size_t)row * ldo + col] = vres;
            }
        }
    }
}

// ---------------- fast bf16 GEMM, global_load_lds staging, DOUBLE-BUFFERED (T3-min 2-phase) ----------------
// per K-step: issue gloads for tile t+1 into buf^1, ds_read+MFMA from buf, one drain-barrier.
template<bool SWZ>
__global__ __launch_bounds__(256)
void gemm_lds2_kernel(int Kd,
                      const unsigned short* __restrict__ A, int lda,
                      const unsigned short* __restrict__ B, int ldb,
                      const float* __restrict__ bias,
                      float* __restrict__ out, int ldo)
{
    __shared__ unsigned short Asl[2][BM * BK];   // 2 x 8 KB
    __shared__ unsigned short Bsl[2][BN * BK];   // 2 x 8 KB

    int bx = blockIdx.x, by = blockIdx.y;
    if constexpr (SWZ) {
        const int nwg = gridDim.x * gridDim.y;
        const int chunk = nwg >> 3;
        const int flat = by * gridDim.x + bx;
        const int newid = (flat & 7) * chunk + (flat >> 3);
        by = newid % gridDim.y;
        bx = newid / gridDim.y;
    }

    const int tid = threadIdx.x;
    const int m0 = by * BM;
    const int n0 = bx * BN;
    const int w = tid >> 6, lane = tid & 63;
    const int wr = w >> 1, wc = w & 1;
    const int lrow = lane & 15, lkg = lane >> 4;
    const int grow = lane >> 2, gcol = (lane & 3) * 8;

    const unsigned short* Ablk = A + (size_t)m0 * lda;
    const unsigned short* Bblk = B + (size_t)n0 * ldb;

    f32x4 acc[4][4] = {};
    const int nk = Kd / BK;

    // prologue: stage tile 0 into buf 0; __syncthreads drains vmcnt(0)
    #pragma unroll
    for (int j = 0; j < 2; ++j) {
        const int rbase = w * 32 + j * 16;
        gload16(Ablk + (size_t)(rbase + grow) * lda + gcol, &Asl[0][rbase * BK]);
        gload16(Bblk + (size_t)(rbase + grow) * ldb + gcol, &Bsl[0][rbase * BK]);
    }
    __syncthreads();

    int cur = 0;
    for (int t = 0; t < nk; ++t) {
        if (t + 1 < nk) {   // issue next-tile loads into the other buffer (overlap with MFMA below)
            const int k0 = (t + 1) * BK;
            #pragma unroll
            for (int j = 0; j < 2; ++j) {
                const int rbase = w * 32 + j * 16;
                gload16(Ablk + (size_t)(rbase + grow) * lda + k0 + gcol, &Asl[cur ^ 1][rbase * BK]);
                gload16(Bblk + (size_t)(rbase + grow) * ldb + k0 + gcol, &Bsl[cur ^ 1][rbase * BK]);
            }
        }
        bf16x8 af[4];
        #pragma unroll
        for (int i = 0; i < 4; ++i)
            af[i] = *(const bf16x8*)(&Asl[cur][(wr * 64 + i * 16 + lrow) * BK + lkg * 8]);
        #pragma unroll
        for (int j = 0; j < 4; ++j) {
            const bf16x8 bh = *(const bf16x8*)(&Bsl[cur][(wc * 64 + j * 16 + lrow) * BK + lkg * 8]);
            #pragma unroll
            for (int i = 0; i < 4; ++i)
                acc[i][j] = __builtin_amdgcn_mfma_f32_16x16x32_bf16(af[i], bh, acc[i][j], 0, 0, 0);
        }
        __syncthreads();   // drains this wave's gloads (vmcnt 0) + syncs: buf^1 ready for next iter
        cur ^= 1;
    }

    #pragma unroll
    for (int i = 0; i < 4; ++i) {
        #pragma unroll
        for (int r = 0; r < 4; ++r) {
            const int row = m0 + wr * 64 + i * 16 + lkg * 4 + r;
            #pragma unroll
            for (int j = 0; j < 4; ++j) {
                const int col = n0 + wc * 64 + j * 16 + lrow;
                const float bj = bias ? bias[col] : 0.0f;
                out[(size_t)row * ldo + col] = acc[i][j][r] + bj;
            }
        }
    }
}

// ---------------- MFMA flash attention, pre-split hi/lo qkv input; split hi/lo output ----------------
#define QBLK 64
#define KVBLK 64

__global__ __launch_bounds__(256)
void attn_mfma_kernel(const unsigned short* __restrict__ qh_g,
                      const unsigned short* __restrict__ ql_g,
                      unsigned short* __restrict__ oh_g,
                      unsigned short* __restrict__ ol_g)
{
    __shared__ short Kh[2][KVBLK][PADK];
    __shared__ short Kl[2][KVBLK][PADK];
    __shared__ short Vh[2][HSD][PADK];
    __shared__ short Vl[2][HSD][PADK];
    __shared__ short Ph[4][2][16][PADK];
    __shared__ short Pl[4][2][16][PADK];

    const int t0 = blockIdx.x * QBLK;
    const int bh = blockIdx.y;
    const int b = bh / HCNT, hh = bh % HCNT;
    const size_t baseq = (size_t)b * TT * QKVLD + (size_t)hh * HSD;
    const size_t obase = (size_t)b * TT * CDIM + (size_t)hh * HSD;
    const unsigned short* kh_g = qh_g + baseq + CDIM;
    const unsigned short* kl_g = ql_g + baseq + CDIM;
    const unsigned short* vh_g = qh_g + baseq + 2 * CDIM;
    const unsigned short* vl_g = ql_g + baseq + 2 * CDIM;
    const int tid = threadIdx.x;
    const int w = tid >> 6, lane = tid & 63;
    const int lrow = lane & 15, lkg = lane >> 4;
    const float sscale = rsqrtf((float)CDIM);

    bf16x8 qh[2], ql[2];
    {
        const size_t qroff = baseq + (size_t)(t0 + w * 16 + lrow) * QKVLD;
        #pragma unroll
        for (int ks = 0; ks < 2; ++ks) {
            qh[ks] = *(const bf16x8*)(qh_g + qroff + ks * 32 + lkg * 8);
            ql[ks] = *(const bf16x8*)(ql_g + qroff + ks * 32 + lkg * 8);
        }
    }

    f32x4 oacc[4] = {};
    float m_[4], l_[4];
    #pragma unroll
    for (int rr = 0; rr < 4; ++rr) { m_[rr] = -1e30f; l_[rr] = 0.0f; }

    for (int s0 = 0; s0 <= t0 + QBLK - 1; s0 += KVBLK) {
        __syncthreads();
        {   // stage K (pure copies)
            const int srow = tid >> 3, skg = (tid & 7) * 4;
            #pragma unroll
            for (int p = 0; p < 2; ++p) {
                const size_t kroff = (size_t)(s0 + p * 32 + srow) * QKVLD;
                #pragma unroll
                for (int ks = 0; ks < 2; ++ks) {
                    *(ushort4*)(&Kh[ks][p * 32 + srow][skg]) = *(const ushort4*)(kh_g + kroff + ks * 32 + skg);
                    *(ushort4*)(&Kl[ks][p * 32 + srow][skg]) = *(const ushort4*)(kl_g + kroff + ks * 32 + skg);
                }
            }
            // stage V transposed (pure copies)
            const int key = tid & 63, dg = (tid >> 6) * 16;
            const size_t vroff = (size_t)(s0 + key) * QKVLD + dg;
            const int kst = key >> 5, ko = key & 31;
            #pragma unroll
            for (int dd = 0; dd < 16; dd += 4) {
                ushort4 hv = *(const ushort4*)(vh_g + vroff + dd);
                ushort4 lv = *(const ushort4*)(vl_g + vroff + dd);
                Vh[kst][dg + dd + 0][ko] = hv.x; Vl[kst][dg + dd + 0][ko] = lv.x;
                Vh[kst][dg + dd + 1][ko] = hv.y; Vl[kst][dg + dd + 1][ko] = lv.y;
                Vh[kst][dg + dd + 2][ko] = hv.z; Vl[kst][dg + dd + 2][ko] = lv.z;
                Vh[kst][dg + dd + 3][ko] = hv.w; Vl[kst][dg + dd + 3][ko] = lv.w;
            }
        }
        __syncthreads();

        f32x4 sacc[4] = {};
        #pragma unroll
        for (int j = 0; j < 4; ++j) {
            #pragma unroll
            for (int ks = 0; ks < 2; ++ks) {
                const bf16x8 bh = *(const bf16x8*)(&Kh[ks][j * 16 + lrow][lkg * 8]);
                const bf16x8 bl = *(const bf16x8*)(&Kl[ks][j * 16 + lrow][lkg * 8]);
                sacc[j] = __builtin_amdgcn_mfma_f32_16x16x32_bf16(qh[ks], bh, sacc[j], 0, 0, 0);
                sacc[j] = __builtin_amdgcn_mfma_f32_16x16x32_bf16(ql[ks], bh, sacc[j], 0, 0, 0);
                sacc[j] = __builtin_amdgcn_mfma_f32_16x16x32_bf16(qh[ks], bl, sacc[j], 0, 0, 0);
            }
        }

        #pragma unroll
        for (int rr = 0; rr < 4; ++rr) {
            const int qi = t0 + w * 16 + lkg * 4 + rr;
            float pv[4];
            float mx = -1e30f;
            #pragma unroll
            for (int j = 0; j < 4; ++j) {
                float s = sacc[j][rr] * sscale;
                if (s0 + j * 16 + lrow > qi) s = -1e30f;
                pv[j] = s;
                mx = fmaxf(mx, s);
            }
            #pragma unroll
            for (int off = 1; off < 16; off <<= 1) mx = fmaxf(mx, __shfl_xor(mx, off));
            const float mnew = fmaxf(m_[rr], mx);
            const float corr = __expf(m_[rr] - mnew);
            float ps = 0.0f;
            #pragma unroll
            for (int j = 0; j < 4; ++j) { pv[j] = __expf(pv[j] - mnew); ps += pv[j]; }
            #pragma unroll
            for (int off = 1; off < 16; off <<= 1) ps += __shfl_xor(ps, off);
            l_[rr] = l_[rr] * corr + ps;
            m_[rr] = mnew;
            #pragma unroll
            for (int jd = 0; jd < 4; ++jd) oacc[jd][rr] *= corr;
            #pragma unroll
            for (int j = 0; j < 4; ++j) {
                unsigned short h, l;
                split2(pv[j], h, l);
                const int key = j * 16 + lrow;
                Ph[w][key >> 5][lkg * 4 + rr][key & 31] = h;
                Pl[w][key >> 5][lkg * 4 + rr][key & 31] = l;
            }
        }

        #pragma unroll
        for (int ks = 0; ks < 2; ++ks) {
            const bf16x8 ah = *(const bf16x8*)(&Ph[w][ks][lrow][lkg * 8]);
            const bf16x8 al = *(const bf16x8*)(&Pl[w][ks][lrow][lkg * 8]);
            #pragma unroll
            for (int jd = 0; jd < 4; ++jd) {
                const bf16x8 bh = *(const bf16x8*)(&Vh[ks][jd * 16 + lrow][lkg * 8]);
                const bf16x8 bl = *(const bf16x8*)(&Vl[ks][jd * 16 + lrow][lkg * 8]);
                oacc[jd] = __builtin_amdgcn_mfma_f32_16x16x32_bf16(ah, bh, oacc[jd], 0, 0, 0);
                oacc[jd] = __builtin_amdgcn_mfma_f32_16x16x32_bf16(al, bh, oacc[jd], 0, 0, 0);
                oacc[jd] = __builtin_amdgcn_mfma_f32_16x16x32_bf16(ah, bl, oacc[jd], 0, 0, 0);
            }
        }
    }

    #pragma unroll
    for (int rr = 0; rr < 4; ++rr) {
        const int qi = t0 + w * 16 + lkg * 4 + rr;
        const float invl = 1.0f / l_[rr];
        const size_t orow = obase + (size_t)qi * CDIM;
        #pragma unroll
        for (int jd = 0; jd < 4; ++jd) {
            unsigned short h, l;
            split2(oacc[jd][rr] * invl, h, l);
            oh_g[orow + jd * 16 + lrow] = h;
            ol_g[orow + jd * 16 + lrow] = l;
        }
    }
}

// ---------------- gate: logits + top-2 + softmax -> sel[N], wts[N] (reads fp32 h2) ----------------
__global__ __launch_bounds__(256)
void gate_kernel(const float* __restrict__ h2, const float* __restrict__ gw,
                 int2* __restrict__ sel, float2* __restrict__ wts)
{
    __shared__ float gws[ECNT * CDIM];
    int tid = threadIdx.x;
    for (int i = tid; i < ECNT * CDIM; i += 256) gws[i] = gw[i];
    __syncthreads();
    int t = blockIdx.x * 256 + tid;
    const float* hr = h2 + (size_t)t * CDIM;
    float g[ECNT] = {};
    for (int c = 0; c < CDIM; ++c) {
        float hv = hr[c];
        #pragma unroll
        for (int e = 0; e < ECNT; ++e) g[e] = fmaf(hv, gws[e * CDIM + c], g[e]);
    }
    int e0 = 0; float g0 = g[0];
    #pragma unroll
    for (int e = 1; e < ECNT; ++e) if (g[e] > g0) { g0 = g[e]; e0 = e; }
    int e1 = -1; float g1 = -1e30f;
    #pragma unroll
    for (int e = 0; e < ECNT; ++e) if (e != e0 && g[e] > g1) { g1 = g[e]; e1 = e; }
    float z = __expf(g1 - g0);          // <= 1
    float w0 = 1.0f / (1.0f + z);
    sel[t] = make_int2(e0, e1);
    wts[t] = make_float2(w0, 1.0f - w0);
}

// ---------------- routing: build expert-grouped permutation (single block) ----------------
__global__ __launch_bounds__(256)
void route_kernel(const int2* __restrict__ sel, int* __restrict__ perm,
                  int* __restrict__ tokpos, int* __restrict__ meta)
{
    __shared__ int cnt[ECNT], off[ECNT], cur[ECNT];
    const int tid = threadIdx.x;
    if (tid < ECNT) cnt[tid] = 0;
    __syncthreads();
    for (int t = tid; t < NTOK; t += 256) {
        atomicAdd(&cnt[sel[t].x], 1);
        atomicAdd(&cnt[sel[t].y], 1);
    }
    __syncthreads();
    if (tid == 0) {
        int run = 0;
        for (int e = 0; e < ECNT; ++e) {
            off[e] = run; cur[e] = 0;
            int pc = (cnt[e] + BM - 1) / BM * BM;
            meta[2 * e] = run; meta[2 * e + 1] = pc;
            run += pc;
        }
    }
    __syncthreads();
    for (int p = tid; p < TOTCAP; p += 256) perm[p] = 0;   // pad slots -> token 0
    __syncthreads();
    for (int t = tid; t < NTOK; t += 256) {
        int2 s = sel[t];
        int p0 = atomicAdd(&cur[s.x], 1); perm[off[s.x] + p0] = t; tokpos[2 * t]     = off[s.x] + p0;
        int p1 = atomicAdd(&cur[s.y], 1); perm[off[s.y] + p1] = t; tokpos[2 * t + 1] = off[s.y] + p1;
    }
}

// ---------------- gather pre-split h2 rows into expert order (pure copy) ----------------
__global__ __launch_bounds__(256)
void gather_ps_kernel(const unsigned short* __restrict__ h2h,
                      const unsigned short* __restrict__ h2l,
                      const int* __restrict__ perm,
                      unsigned short* __restrict__ xgh,
                      unsigned short* __restrict__ xgl)
{
    int i = blockIdx.x * 256 + threadIdx.x;   // TOTCAP*CDIM
    int c = i % CDIM, p = i / CDIM;
    const size_t s = (size_t)perm[p] * CDIM + c;
    xgh[i] = h2h[s];
    xgl[i] = h2l[s];
}

// ---------------- gather hi-part rows (= f2bf(h2)) for l1 fast path ----------------
__global__ __launch_bounds__(256)
void gather_cp_kernel(const unsigned short* __restrict__ h2h, const int* __restrict__ perm,
                      unsigned short* __restrict__ xg)
{
    int i = blockIdx.x * 256 + threadIdx.x;   // TOTCAP*CDIM
    int c = i % CDIM, p = i / CDIM;
    xg[i] = h2h[(size_t)perm[p] * CDIM + c];
}

// ---------------- combine: x += w0*sum_sk(y[pos0]) + w1*sum_sk(y[pos1]) ----------------
template<int SK>
__global__ __launch_bounds__(256)
void combine_kernel(const float* __restrict__ y, size_t pstride,
                    const int* __restrict__ tokpos,
                    const float2* __restrict__ wts, float* __restrict__ x)
{
    int i = blockIdx.x * 256 + threadIdx.x;   // NTOK*CDIM
    int c = i % CDIM, t = i / CDIM;
    float2 wv = wts[t];
    const size_t r0 = (size_t)tokpos[2 * t] * CDIM + c;
    const size_t r1 = (size_t)tokpos[2 * t + 1] * CDIM + c;
    float a0 = 0.0f, a1 = 0.0f;
    #pragma unroll
    for (int s = 0; s < SK; ++s) {
        a0 += y[s * pstride + r0];
        a1 += y[s * pstride + r1];
    }
    x[i] += wv.x * a0 + wv.y * a1;
}

// ---------------- per-row cross-entropy (float4 loads) ----------------
__global__ __launch_bounds__(256)
void loss_row_kernel(const float* __restrict__ logits, const int* __restrict__ tgt,
                     float* __restrict__ lrow)
{
    int row = blockIdx.x;
    const float4* lr4 = (const float4*)(logits + (size_t)row * VOC);
    int tid = threadIdx.x, w = tid >> 6, lane = tid & 63;
    __shared__ float red[4];
    float mx = -1e30f;
    for (int i = tid; i < VOC / 4; i += 256) {
        float4 v = lr4[i];
        mx = fmaxf(mx, fmaxf(fmaxf(v.x, v.y), fmaxf(v.z, v.w)));
    }
    mx = wave_max(mx);
    if (lane == 0) red[w] = mx;
    __syncthreads();
    mx = fmaxf(fmaxf(red[0], red[1]), fmaxf(red[2], red[3]));
    __syncthreads();
    float se = 0.0f;
    for (int i = tid; i < VOC / 4; i += 256) {
        float4 v = lr4[i];
        se += expf(v.x - mx) + expf(v.y - mx) + expf(v.z - mx) + expf(v.w - mx);
    }
    se = wave_sum(se);
    if (lane == 0) red[w] = se;
    __syncthreads();
    if (tid == 0) {
        float lse = mx + logf(red[0] + red[1] + red[2] + red[3]);
        lrow[row] = lse - logits[(size_t)row * VOC + tgt[row]];
    }
}

__global__ __launch_bounds__(256)
void loss_reduce_kernel(const float* __restrict__ lrow, float* __restrict__ out)
{
    int tid = threadIdx.x, w = tid >> 6, lane = tid & 63;
    float s = 0.0f;
    for (int i = tid; i < NTOK; i += 256) s += lrow[i];
    s = wave_sum(s);
    __shared__ float red[4];
    if (lane == 0) red[w] = s;
    __syncthreads();
    if (tid == 0) out[0] = (red[0] + red[1] + red[2] + red[3]) * (1.0f / NTOK);
}

// ---------------- launch ----------------
extern "C" void kernel_launch(void* const* d_in, const int* in_sizes, int n_in,
                              void* d_out, int out_size, void* d_ws, size_t ws_size,
                              hipStream_t stream)
{
    const int*   idx     = (const int*)d_in[0];
    const int*   targets = (const int*)d_in[1];
    const float* tok_emb = (const float*)d_in[2];
    const float* pos_emb = (const float*)d_in[3];
    const float* ln1_s   = (const float*)d_in[4];
    const float* ln1_b   = (const float*)d_in[5];
    const float* wq      = (const float*)d_in[6];
    const float* wk      = (const float*)d_in[7];
    const float* wv      = (const float*)d_in[8];
    const float* wo      = (const float*)d_in[9];
    const float* bo      = (const float*)d_in[10];
    const float* ln2_s   = (const float*)d_in[11];
    const float* ln2_b   = (const float*)d_in[12];
    const float* gate_w  = (const float*)d_in[13];
    const float* w1      = (const float*)d_in[14];
    const float* b1      = (const float*)d_in[15];
    const float* w2      = (const float*)d_in[16];
    const float* b2      = (const float*)d_in[17];
    const float* lm_w    = (const float*)d_in[18];
    const float* lm_b    = (const float*)d_in[19];
    float* out = (float*)d_out;

    // ws layout
    unsigned short* wph = (unsigned short*)d_ws;                     // 3*L*C*C
    unsigned short* wpl = wph + (size_t)3 * LCNT * CDIM * CDIM;
    unsigned short* woh = wpl + (size_t)3 * LCNT * CDIM * CDIM;      // L*C*C
    unsigned short* wol = woh + (size_t)LCNT * CDIM * CDIM;
    float* x    = (float*)(wol + (size_t)LCNT * CDIM * CDIM);
    float* hbuf = x    + (size_t)NTOK * CDIM;        // LN1-split / attn-out-split (2x bf16)
    float* qkv  = hbuf + (size_t)NTOK * CDIM;        // qkvh+qkvl bf16 / h2 fp32 + h2h + h2l / ybuf
    float* xg   = qkv  + (size_t)NTOK * QKVLD;       // TOTCAP*C: xgh+xgl bf16 (l0) / xg_bf (l1)
    float* hid  = xg   + (size_t)TOTCAP * CDIM;      // TOTCAP*FF: hidh+hidl bf16 (l0) / hid_bf + lmw_bf
    float* lrow = hid  + (size_t)TOTCAP * FF;        // NTOK
    float2* wts = (float2*)(lrow + NTOK);            // NTOK float2
    int2*  sel  = (int2*)(wts + NTOK);               // NTOK int2
    int*   perm = (int*)(sel + NTOK);                // TOTCAP
    int*  tokpos= perm + TOTCAP;                     // 2*NTOK
    int*   meta = tokpos + 2 * NTOK;                 // 16
    unsigned short* x_bf = (unsigned short*)(meta + 16);  // NTOK*C bf16
    float* part = (float*)(x_bf + (size_t)NTOK * CDIM);   // SKN*TOTCAP*C partials (optional)

    const size_t need_bytes = (size_t)((char*)(part + (size_t)SKN * TOTCAP * CDIM) - (char*)d_ws);
    const bool use_sk = ws_size >= need_bytes;

    unsigned short* hbufh = (unsigned short*)hbuf;             // NTOK*C
    unsigned short* hbufl = hbufh + (size_t)NTOK * CDIM;
    unsigned short* qkvh = (unsigned short*)qkv;               // NTOK*QKVLD
    unsigned short* qkvl = qkvh + (size_t)NTOK * QKVLD;
    float*          h2   = qkv;                                // NTOK*C fp32 (gate)
    unsigned short* h2h  = (unsigned short*)(qkv + (size_t)NTOK * CDIM);
    unsigned short* h2l  = h2h + (size_t)NTOK * CDIM;
    float*          ybuf = qkv;                                // NTOK*C fp32 (after gather)
    unsigned short* xgh  = (unsigned short*)xg;                // TOTCAP*C
    unsigned short* xgl  = xgh + (size_t)TOTCAP * CDIM;
    unsigned short* xg_bf = (unsigned short*)xg;
    unsigned short* hidh = (unsigned short*)hid;               // TOTCAP*FF
    unsigned short* hidl = hidh + (size_t)TOTCAP * FF;
    unsigned short* hid_bf = (unsigned short*)hid;
    unsigned short* lmw_bf = (unsigned short*)hid;

    dim3 blk(256);

    repack_kernel<<<(3 * LCNT * CDIM * CDIM) / 256, blk, 0, stream>>>(wq, wk, wv, wph, wpl);
    splitw_kernel<<<1024, blk, 0, stream>>>(wo, woh, wol, LCNT * CDIM * CDIM / 4);
    embed_kernel<<<(NTOK * CDIM) / 256, blk, 0, stream>>>(idx, tok_emb, pos_emb, x);

    for (int l = 0; l < LCNT; ++l) {
        // LN1 -> split hi/lo only
        ln_kernel<false><<<NTOK, blk, 0, stream>>>(
            x, ln1_s + (size_t)l * CDIM, ln1_b + (size_t)l * CDIM, nullptr, hbufh, hbufl);

        // fused QKV projection (pre-split A and B) -> split hi/lo output
        gemm_ps_kernel<0, true><<<dim3(QKVLD / BN, NTOK / BM), blk, 0, stream>>>(
            CDIM, hbufh, hbufl, CDIM,
            wph + (size_t)l * 3 * CDIM * CDIM, wpl + (size_t)l * 3 * CDIM * CDIM, CDIM,
            nullptr, nullptr, qkvh, qkvl, QKVLD);

        attn_mfma_kernel<<<dim3(TT / QBLK, BB * HCNT), blk, 0, stream>>>(qkvh, qkvl, hbufh, hbufl);

        // wo projection (pre-split A and B) -> accumulate into x
        gemm_ps_kernel<1, false><<<dim3(CDIM / BN, NTOK / BM), blk, 0, stream>>>(
            CDIM, hbufh, hbufl, CDIM,
            woh + (size_t)l * CDIM * CDIM, wol + (size_t)l * CDIM * CDIM, CDIM,
            bo + (size_t)l * CDIM, x, nullptr, nullptr, CDIM);

        // --- MoE ---
        // LN2 -> fp32 (gate, bit-identical routing) + split hi/lo (experts)
        ln_kernel<true><<<NTOK, blk, 0, stream>>>(
            x, ln2_s + (size_t)l * CDIM, ln2_b + (size_t)l * CDIM, h2, h2h, h2l);
        gate_kernel<<<NTOK / 256, blk, 0, stream>>>(h2, gate_w + (size_t)l * ECNT * CDIM, sel, wts);
        route_kernel<<<1, blk, 0, stream>>>(sel, perm, tokpos, meta);

        const float* w1l = w1 + (size_t)l * ECNT * FF * CDIM;
        const float* b1l = b1 + (size_t)l * ECNT * FF;
        const float* w2l = w2 + (size_t)l * ECNT * CDIM * FF;
        const float* b2l = b2 + (size_t)l * ECNT * CDIM;
        if (l == 0) {   // feeds next layer's router -> fp32-grade (split 3-MFMA)
            gather_ps_kernel<<<(TOTCAP * CDIM) / 256, blk, 0, stream>>>(h2h, h2l, perm, xgh, xgl);
            gemm_pse_kernel<<<dim3(FF / BN, TOTCAP / BM, ECNT), blk, 0, stream>>>(
                CDIM, xgh, xgl, CDIM, w1l, CDIM, b1l, hidh, hidl, FF,
                meta, (size_t)FF * CDIM, FF);
            if (use_sk) {
                gemm_pssk_kernel<SKN><<<dim3(CDIM / BN, TOTCAP / BM, ECNT * SKN), blk, 0, stream>>>(
                    FF / SKN, hidh, hidl, FF, w2l, FF, b2l, part, CDIM, (size_t)TOTCAP * CDIM,
                    meta, (size_t)CDIM * FF, CDIM);
                combine_kernel<SKN><<<(NTOK * CDIM) / 256, blk, 0, stream>>>(
                    part, (size_t)TOTCAP * CDIM, tokpos, wts, x);
            } else {
                gemm_pssk_kernel<1><<<dim3(CDIM / BN, TOTCAP / BM, ECNT), blk, 0, stream>>>(
                    FF, hidh, hidl, FF, w2l, FF, b2l, ybuf, CDIM, 0,
                    meta, (size_t)CDIM * FF, CDIM);
                combine_kernel<1><<<(NTOK * CDIM) / 256, blk, 0, stream>>>(
                    ybuf, 0, tokpos, wts, x);
            }
        } else {        // feeds only logits -> fast 1-MFMA, bf16 activations
            gather_cp_kernel<<<(TOTCAP * CDIM) / 256, blk, 0, stream>>>(h2h, perm, xg_bf);
            gemm_fastw_kernel<2, false, true, false><<<dim3(FF / BN, TOTCAP / BM, ECNT), blk, 0, stream>>>(
                CDIM, xg_bf, CDIM, w1l, CDIM, b1l, hid_bf, FF, meta, (size_t)FF * CDIM, FF);
            gemm_fastw_kernel<0, false, false, false><<<dim3(CDIM / BN, TOTCAP / BM, ECNT), blk, 0, stream>>>(
                FF, hid_bf, FF, w2l, FF, b2l, ybuf, CDIM, meta, (size_t)CDIM * FF, CDIM);
            combine_kernel<1><<<(NTOK * CDIM) / 256, blk, 0, stream>>>(
                ybuf, 0, tokpos, wts, x);
        }
    }

    // pre-convert LM head operands to bf16 (hid region is dead now)
    cvt_bf16_kernel<<<2048, blk, 0, stream>>>(lm_w, lmw_bf, VOC * CDIM / 4);
    cvt_bf16_kernel<<<512, blk, 0, stream>>>(x, x_bf, NTOK * CDIM / 4);

    // LM head: bf16 x bf16, double-buffered global_load_lds (T3-min), XCD-aware swizzle
    gemm_lds2_kernel<true><<<dim3(VOC / BN, NTOK / BM), blk, 0, stream>>>(
        CDIM, x_bf, CDIM, lmw_bf, CDIM, lm_b, out, VOC);

    loss_row_kernel<<<NTOK, blk, 0, stream>>>(out, targets, lrow);
    loss_reduce_kernel<<<1, blk, 0, stream>>>(lrow, out + (size_t)NTOK * VOC);
}